// Round 7
// baseline (887.388 us; speedup 1.0000x reference)
//
#include <hip/hip_runtime.h>
#include <hip/hip_fp16.h>
#include <math.h>

// ---------------- sizes ----------------
#define B32   32
#define OCLS  102
#define NCAPS 2592

// ---------------- ws map (floats) ----------------
// phase 1 (conv/pc): FEAT2 C1WB PCWQ PCP(16 slices) U2
// phase 2 (routing): WQ2 overlays FEAT2; WQ overlays PCP-low (both dead)
// phase 3 (recon):   FC3P overlays U2+CT
#define OFF_FEAT   0u               // feat2[b][h][co][w36]: 10,027,008
#define OFF_WQ2    0u               // fp8 W pack [o][n][d][i]: 33,867,776 B
#define OFF_C1WT   10027008u        // bf16 conv1 pack: 3*256*128 ush
#define OFF_PCWQ   10119936u        // fp8 pc pack [ci][co][104]B: 6,815,744 B
#define OFF_PCP    15428352u        // 16*32*81*256 = 10,616,832 -> ends 26,045,184
#define OFF_WQ     15428352u        // fp8 W pack [o][n][i][d] (overlays PCP after squash)
#define OFF_U2     26045184u        // 663,552
#define OFF_CT     26708736u        // fp16 c[o][n][b]: 8,460,288 halfs -> ends 30,938,880
#define OFF_FC3P   26045184u        // fc3 partials (overlay U2+CT after routing)
#define OFF_S      30938880u
#define OFF_V0     30991104u
#define OFF_V1     31043328u
#define OFF_VSQ    31095552u        // fp8 vsum x1024: 52,224 B
#define OFF_H1     31108608u
#define OFF_H2T    31124992u        // end 31,157,760 (<31.4M proven)

typedef __attribute__((ext_vector_type(8))) short short8;
typedef __attribute__((ext_vector_type(4))) float f32x4;
typedef long long i64;

__device__ __forceinline__ unsigned short f2b(float f) {
  union { float f; unsigned u; } v; v.f = f;
  unsigned r = v.u + 0x7fffu + ((v.u >> 16) & 1u);
  return (unsigned short)(r >> 16);
}

// float -> OCP e4m3fn (RNE, flush<2^-6, clamp) -- software fallback
__device__ __forceinline__ unsigned f2q_fast(float x) {
  union { float f; unsigned u; } v; v.f = x;
  unsigned s = (v.u >> 24) & 0x80u;
  unsigned au = v.u & 0x7fffffffu;
  if (au < 0x3c800000u) return s;
  if (au >= 0x43e00000u) return s | 0x7eu;
  unsigned r = au + 0x7ffffu + ((au >> 20) & 1u);
  unsigned e = (r >> 23) - 120u;
  unsigned m = (r >> 20) & 7u;
  return s | (e << 3) | m;
}

// two floats -> packed fp8 pair in low 16 bits (HW cvt when available)
__device__ __forceinline__ unsigned fp8pair(float a, float b) {
#if __has_builtin(__builtin_amdgcn_cvt_pk_fp8_f32)
  return (unsigned)__builtin_amdgcn_cvt_pk_fp8_f32(a, b, 0, false) & 0xffffu;
#else
  return f2q_fast(a) | (f2q_fast(b) << 8);
#endif
}

// ---------------- conv1_w -> bf16 [ci][co][128] ----------------
__global__ void k_mkC1B(const float* __restrict__ conv1_w,
                        unsigned short* __restrict__ C1WB) {
  int co = blockIdx.x;
  int t = threadIdx.x;  // 128
#pragma unroll
  for (int ci = 0; ci < 3; ++ci) {
    float v = (t < 121) ? conv1_w[co * 363 + ci * 121 + t] : 0.f;
    C1WB[(ci * 256 + co) * 128 + t] = f2b(v);
  }
}

// ---------------- pc_w -> fp8 x64 [ci][co][104]B ----------------
__global__ void k_mkBq(const float* __restrict__ pc_w, unsigned char* __restrict__ PCWQ) {
  int co = blockIdx.x;
  for (int e = threadIdx.x; e < 20736; e += 256) {
    int ci = e / 81, tap = e - ci * 81;
    PCWQ[(size_t)ci * 26624 + co * 104 + tap] =
        (unsigned char)f2q_fast(pc_w[(size_t)co * 20736 + e] * 64.f);
  }
  int ci = threadIdx.x;
  for (int tap = 81; tap < 104; ++tap)
    PCWQ[(size_t)ci * 26624 + co * 104 + tap] = 0;
}

// ---------------- W -> fp8 x64: Wq2[o][n][d][i] and Wq[o][n][i][d] ----------------
__global__ void k_mkW(const float* __restrict__ W, unsigned char* __restrict__ Wq2,
                      unsigned char* __restrict__ Wq) {
  int on = blockIdx.x * 256 + threadIdx.x;
  if (on >= 102 * 2592) return;
  const float4* src = (const float4*)(W + (size_t)on * 128);
  unsigned w2[32], wq[32];
#pragma unroll
  for (int j = 0; j < 32; ++j) wq[j] = 0;
#pragma unroll
  for (int d = 0; d < 16; ++d) {
    float4 a = src[d * 2], b = src[d * 2 + 1];
    w2[d * 2]     = fp8pair(a.x * 64.f, a.y * 64.f) | (fp8pair(a.z * 64.f, a.w * 64.f) << 16);
    w2[d * 2 + 1] = fp8pair(b.x * 64.f, b.y * 64.f) | (fp8pair(b.z * 64.f, b.w * 64.f) << 16);
    float vals[8] = {a.x, a.y, a.z, a.w, b.x, b.y, b.z, b.w};
#pragma unroll
    for (int i = 0; i < 8; ++i)
      wq[i * 4 + (d >> 2)] |= f2q_fast(vals[i] * 64.f) << ((d & 3) * 8);
  }
  uint4* d2 = (uint4*)(Wq2 + (size_t)on * 128);
  uint4* dq = (uint4*)(Wq + (size_t)on * 128);
#pragma unroll
  for (int k = 0; k < 8; ++k) {
    d2[k] = make_uint4(w2[4 * k], w2[4 * k + 1], w2[4 * k + 2], w2[4 * k + 3]);
    dq[k] = make_uint4(wq[4 * k], wq[4 * k + 1], wq[4 * k + 2], wq[4 * k + 3]);
  }
}

// ---------------- conv1 via bf16 MFMA implicit-im2col ----------------
__global__ __launch_bounds__(256) void k_c1m(const float* __restrict__ x,
                                             const unsigned short* __restrict__ C1WB,
                                             const float* __restrict__ bias,
                                             float* __restrict__ feat2) {
  __shared__ unsigned short sh[48 * 128 + 256 * 128];
  unsigned short* lA = sh;
  unsigned short* lB = sh + 48 * 128;
  float* obuf = (float*)(sh + 48 * 128);

  int bx = blockIdx.x;
  int b = bx / 34, ho = bx % 34;
  int t = threadIdx.x;
  int lane = t & 63, wv = t >> 6;
  int l15 = lane & 15, lh = lane >> 4;
  int rx = l15 & 7;

  {
    uint4 zz = make_uint4(0, 0, 0, 0);
    uint4* z = (uint4*)lA;
    for (int i = t; i < 48 * 128 / 8; i += 256) z[i] = zz;
  }
  __syncthreads();

  f32x4 acc[3][4];
#pragma unroll
  for (int mf = 0; mf < 3; ++mf)
#pragma unroll
    for (int nf = 0; nf < 4; ++nf) acc[mf][nf] = (f32x4){0.f, 0.f, 0.f, 0.f};

#pragma unroll 1
  for (int ci = 0; ci < 3; ++ci) {
    {
      const uint4* Bsrc = (const uint4*)(C1WB + ci * 32768);
#pragma unroll
      for (int i = 0; i < 16; ++i) {
        int f = i * 256 + t;
        int row = f >> 4, cu = f & 15;
        ((uint4*)lB)[row * 16 + (cu ^ (row & 7))] = Bsrc[f];
      }
    }
    for (int tk = t; tk < 374; tk += 256) {
      int kh = tk / 34, wo = tk - kh * 34;
      const float* src = x + ((size_t)(b * 3 + ci) * 112 + ho * 3 + kh) * 112 + wo * 3;
#pragma unroll
      for (int j = 0; j < 11; ++j) {
        int tap = kh * 11 + j;
        int cu = tap >> 3;
        lA[wo * 128 + (((cu ^ (wo & 7)) << 3) | (tap & 7))] = f2b(src[j]);
      }
    }
    __syncthreads();

#pragma unroll
    for (int s = 0; s < 4; ++s) {
      int cub = ((s * 4 + lh) ^ rx) << 3;
      short8 a0 = *(const short8*)(lA + (0 + l15) * 128 + cub);
      short8 a1 = *(const short8*)(lA + (16 + l15) * 128 + cub);
      short8 a2 = *(const short8*)(lA + (32 + l15) * 128 + cub);
      short8 b0 = *(const short8*)(lB + (wv * 64 + 0 + l15) * 128 + cub);
      short8 b1 = *(const short8*)(lB + (wv * 64 + 16 + l15) * 128 + cub);
      short8 b2 = *(const short8*)(lB + (wv * 64 + 32 + l15) * 128 + cub);
      short8 b3 = *(const short8*)(lB + (wv * 64 + 48 + l15) * 128 + cub);
      acc[0][0] = __builtin_amdgcn_mfma_f32_16x16x32_bf16(a0, b0, acc[0][0], 0, 0, 0);
      acc[0][1] = __builtin_amdgcn_mfma_f32_16x16x32_bf16(a0, b1, acc[0][1], 0, 0, 0);
      acc[0][2] = __builtin_amdgcn_mfma_f32_16x16x32_bf16(a0, b2, acc[0][2], 0, 0, 0);
      acc[0][3] = __builtin_amdgcn_mfma_f32_16x16x32_bf16(a0, b3, acc[0][3], 0, 0, 0);
      acc[1][0] = __builtin_amdgcn_mfma_f32_16x16x32_bf16(a1, b0, acc[1][0], 0, 0, 0);
      acc[1][1] = __builtin_amdgcn_mfma_f32_16x16x32_bf16(a1, b1, acc[1][1], 0, 0, 0);
      acc[1][2] = __builtin_amdgcn_mfma_f32_16x16x32_bf16(a1, b2, acc[1][2], 0, 0, 0);
      acc[1][3] = __builtin_amdgcn_mfma_f32_16x16x32_bf16(a1, b3, acc[1][3], 0, 0, 0);
      acc[2][0] = __builtin_amdgcn_mfma_f32_16x16x32_bf16(a2, b0, acc[2][0], 0, 0, 0);
      acc[2][1] = __builtin_amdgcn_mfma_f32_16x16x32_bf16(a2, b1, acc[2][1], 0, 0, 0);
      acc[2][2] = __builtin_amdgcn_mfma_f32_16x16x32_bf16(a2, b2, acc[2][2], 0, 0, 0);
      acc[2][3] = __builtin_amdgcn_mfma_f32_16x16x32_bf16(a2, b3, acc[2][3], 0, 0, 0);
    }
    __syncthreads();
  }

  float bv[4];
#pragma unroll
  for (int nf = 0; nf < 4; ++nf) bv[nf] = bias[wv * 64 + nf * 16 + l15];
#pragma unroll
  for (int mf = 0; mf < 3; ++mf)
#pragma unroll
    for (int nf = 0; nf < 4; ++nf)
#pragma unroll
      for (int r = 0; r < 4; ++r) {
        int wo = mf * 16 + lh * 4 + r;
        if (wo < 36)
          obuf[(wv * 64 + nf * 16 + l15) * 36 + wo] = fmaxf(acc[mf][nf][r] + bv[nf], 0.f);
      }
  __syncthreads();
  float4* dst = (float4*)(feat2 + (size_t)bx * 9216);
  const float4* srcb = (const float4*)obuf;
#pragma unroll
  for (int i = 0; i < 9; ++i) dst[i * 256 + t] = srcb[i * 256 + t];
}

// ---------------- pc conv gather (fp8, HW cvt pairs) ----------------
__device__ __forceinline__ void pc_gather8(const float* __restrict__ feat2,
                                           unsigned char* __restrict__ dstbuf,
                                           int mb, int ci, int t) {
  for (int task = t; task < 576; task += 256) {
    int m = task / 9, kh = task - m * 9;
    int gm = mb * 64 + m;
    if (gm < 2592) {
      int b = gm / 81, p = gm - b * 81;
      int ho = p / 9, wo = p - ho * 9;
      const float* src = feat2 + ((size_t)(b * 34 + ho * 3 + kh) * 256 + ci) * 36 + wo * 3;
      unsigned char* dst = dstbuf + m * 104 + kh * 9;
      unsigned p01 = fp8pair(src[0], src[1]);
      unsigned p23 = fp8pair(src[2], src[3]);
      unsigned p45 = fp8pair(src[4], src[5]);
      unsigned p67 = fp8pair(src[6], src[7]);
      unsigned p8  = fp8pair(src[8], 0.f);
      dst[0] = p01; dst[1] = p01 >> 8;
      dst[2] = p23; dst[3] = p23 >> 8;
      dst[4] = p45; dst[5] = p45 >> 8;
      dst[6] = p67; dst[7] = p67 >> 8;
      dst[8] = p8;
    }
  }
}

// ---------------- primary caps conv: fp8 MFMA, kc=16, B-in-regs, A dbuf ----------------
__global__ __launch_bounds__(256, 3) void k_pc4(const float* __restrict__ feat2,
                                                const unsigned char* __restrict__ PCWQ,
                                                float* __restrict__ pcp) {
  __shared__ unsigned char lA[2][64 * 104];

  int mb = blockIdx.x, kc = blockIdx.y;  // (41, 16)
  int t = threadIdx.x;
  int lane = t & 63, wv = t >> 6;
  int l15 = lane & 15, lh = lane >> 4;

  {
    uint4 zz = make_uint4(0, 0, 0, 0);
    uint4* z = (uint4*)lA;
    for (int i = t; i < 2 * 64 * 104 / 16; i += 256) z[i] = zz;
  }
  __syncthreads();
  pc_gather8(feat2, lA[0], mb, kc * 16, t);
  __syncthreads();

  f32x4 acc[4][4];
#pragma unroll
  for (int mf = 0; mf < 4; ++mf)
#pragma unroll
    for (int nf = 0; nf < 4; ++nf) acc[mf][nf] = (f32x4){0.f, 0.f, 0.f, 0.f};

#pragma unroll 1
  for (int cil = 0; cil < 16; ++cil) {
    int ci = kc * 16 + cil;
    int cur = cil & 1;

    i64 bfr[4][3];
    const unsigned char* Bbase = PCWQ + (size_t)ci * 26624 + (wv * 64 + l15) * 104 + lh * 8;
#pragma unroll
    for (int nf = 0; nf < 4; ++nf)
#pragma unroll
      for (int s = 0; s < 3; ++s)
        bfr[nf][s] = *(const i64*)(Bbase + nf * 16 * 104 + s * 32);

    if (cil < 15) pc_gather8(feat2, lA[cur ^ 1], mb, ci + 1, t);

    const unsigned char* arow = lA[cur] + l15 * 104 + lh * 8;
#pragma unroll
    for (int s = 0; s < 3; ++s) {
      i64 a0 = *(const i64*)(arow + s * 32);
      i64 a1 = *(const i64*)(arow + 16 * 104 + s * 32);
      i64 a2 = *(const i64*)(arow + 32 * 104 + s * 32);
      i64 a3 = *(const i64*)(arow + 48 * 104 + s * 32);
      acc[0][0] = __builtin_amdgcn_mfma_f32_16x16x32_fp8_fp8(a0, bfr[0][s], acc[0][0], 0, 0, 0);
      acc[0][1] = __builtin_amdgcn_mfma_f32_16x16x32_fp8_fp8(a0, bfr[1][s], acc[0][1], 0, 0, 0);
      acc[0][2] = __builtin_amdgcn_mfma_f32_16x16x32_fp8_fp8(a0, bfr[2][s], acc[0][2], 0, 0, 0);
      acc[0][3] = __builtin_amdgcn_mfma_f32_16x16x32_fp8_fp8(a0, bfr[3][s], acc[0][3], 0, 0, 0);
      acc[1][0] = __builtin_amdgcn_mfma_f32_16x16x32_fp8_fp8(a1, bfr[0][s], acc[1][0], 0, 0, 0);
      acc[1][1] = __builtin_amdgcn_mfma_f32_16x16x32_fp8_fp8(a1, bfr[1][s], acc[1][1], 0, 0, 0);
      acc[1][2] = __builtin_amdgcn_mfma_f32_16x16x32_fp8_fp8(a1, bfr[2][s], acc[1][2], 0, 0, 0);
      acc[1][3] = __builtin_amdgcn_mfma_f32_16x16x32_fp8_fp8(a1, bfr[3][s], acc[1][3], 0, 0, 0);
      acc[2][0] = __builtin_amdgcn_mfma_f32_16x16x32_fp8_fp8(a2, bfr[0][s], acc[2][0], 0, 0, 0);
      acc[2][1] = __builtin_amdgcn_mfma_f32_16x16x32_fp8_fp8(a2, bfr[1][s], acc[2][1], 0, 0, 0);
      acc[2][2] = __builtin_amdgcn_mfma_f32_16x16x32_fp8_fp8(a2, bfr[2][s], acc[2][2], 0, 0, 0);
      acc[2][3] = __builtin_amdgcn_mfma_f32_16x16x32_fp8_fp8(a2, bfr[3][s], acc[2][3], 0, 0, 0);
      acc[3][0] = __builtin_amdgcn_mfma_f32_16x16x32_fp8_fp8(a3, bfr[0][s], acc[3][0], 0, 0, 0);
      acc[3][1] = __builtin_amdgcn_mfma_f32_16x16x32_fp8_fp8(a3, bfr[1][s], acc[3][1], 0, 0, 0);
      acc[3][2] = __builtin_amdgcn_mfma_f32_16x16x32_fp8_fp8(a3, bfr[2][s], acc[3][2], 0, 0, 0);
      acc[3][3] = __builtin_amdgcn_mfma_f32_16x16x32_fp8_fp8(a3, bfr[3][s], acc[3][3], 0, 0, 0);
    }
    __syncthreads();
  }

#pragma unroll
  for (int mf = 0; mf < 4; ++mf) {
    int gm = mb * 64 + mf * 16 + lh * 4;
    if (gm < 2592) {
      float* dst = pcp + (size_t)kc * 663552 + (size_t)gm * 256 + wv * 64 + l15;
#pragma unroll
      for (int nf = 0; nf < 4; ++nf)
#pragma unroll
        for (int r = 0; r < 4; ++r)
          dst[(size_t)r * 256 + nf * 16] = acc[mf][nf][r];
    }
  }
}

// ---------------- fused: sum 16 partials + /64 + bias + squash -> u2 ----------------
__global__ void k_squash2(const float* __restrict__ pcp, const float* __restrict__ pcb,
                          float* __restrict__ u2) {
  int t = blockIdx.x * 256 + threadIdx.x;  // < 82944
  int b = t / 2592, n = t - b * 2592;
  float v[8];
  float sq = 0.f;
#pragma unroll
  for (int i = 0; i < 8; ++i) {
    int f = n * 8 + i;
    int co = f / 81, p = f - co * 81;
    const float* base = pcp + (size_t)(b * 81 + p) * 256 + co;
    float s = 0.f;
#pragma unroll
    for (int c = 0; c < 16; ++c) s += base[(size_t)c * 663552];
    s = pcb[co] + s * 0.015625f;  // /64 (W x64 scale)
    v[i] = s;
    sq += s * s;
  }
  float sc = (sq / (1.f + sq)) / sqrtf(sq + 1e-8f);
#pragma unroll
  for (int i = 0; i < 8; ++i) u2[t * 8 + i] = v[i] * sc;
}

// ---------------- routing kernel A (fp8 MFMA): logits + softmax -> cT ----------------
__global__ __launch_bounds__(128) void k_A2(const unsigned char* __restrict__ Wq,
                                            const float* __restrict__ u2,
                                            const unsigned char* __restrict__ vq,
                                            __half* __restrict__ cT) {
  __shared__ __half Eld[102 * 2 * 2 * 32];
  int nb = blockIdx.x;  // 648
  int t = threadIdx.x, wv = t >> 6, lane = t & 63;
  int l15 = lane & 15, g = lane >> 4;
  int n0 = nb * 4 + 2 * wv;
  int nl = g >> 1, ih = (g & 1) * 4;

  float4 u0 = *(const float4*)(u2 + (((size_t)l15 * 2592 + n0 + nl) * 8 + ih));
  float4 u1 = *(const float4*)(u2 + (((size_t)(l15 + 16) * 2592 + n0 + nl) * 8 + ih));

  int nlA = l15 >> 3, iA = l15 & 7;
  const unsigned char* Ap = Wq + (((size_t)(n0 + nlA)) * 8 + iA) * 16 + (g & 1) * 8;
  const unsigned char* B0p = vq + (size_t)l15 * 16 + (g & 1) * 8;
  bool act = (g < 2);

  float den0 = 0.f, den1 = 0.f;
#pragma unroll 2
  for (int o = 0; o < 102; ++o) {
    i64 a = 0, b0 = 0, b1 = 0;
    if (act) {
      a  = *(const i64*)(Ap + (size_t)o * 331776);
      b0 = *(const i64*)(B0p + (size_t)o * 512);
      b1 = *(const i64*)(B0p + (size_t)o * 512 + 256);
    }
    f32x4 d0 = {0.f, 0.f, 0.f, 0.f}, d1 = {0.f, 0.f, 0.f, 0.f};
    d0 = __builtin_amdgcn_mfma_f32_16x16x32_fp8_fp8(a, b0, d0, 0, 0, 0);
    d1 = __builtin_amdgcn_mfma_f32_16x16x32_fp8_fp8(a, b1, d1, 0, 0, 0);
    float p0 = d0[0] * u0.x + d0[1] * u0.y + d0[2] * u0.z + d0[3] * u0.w;
    float p1 = d1[0] * u1.x + d1[1] * u1.y + d1[2] * u1.z + d1[3] * u1.w;
    p0 += __shfl_xor(p0, 16);
    p1 += __shfl_xor(p1, 16);
    p0 *= 1.52587890625e-05f;  // / (64 * 1024)
    p1 *= 1.52587890625e-05f;
    float e0 = __expf(p0), e1 = __expf(p1);
    den0 += e0; den1 += e1;
    if ((g & 1) == 0) {
      int base = (o * 2 + wv) * 64 + (g >> 1) * 16 + l15;
      Eld[base] = __float2half(e0);
      Eld[base + 32] = __float2half(e1);
    }
  }
  float r0 = 1.0f / den0, r1 = 1.0f / den1;
  if ((g & 1) == 0) {
    for (int o = 0; o < 102; ++o) {
      int base = (o * 2 + wv) * 64 + (g >> 1) * 16 + l15;
      float c0 = __half2float(Eld[base]) * r0;
      float c1 = __half2float(Eld[base + 32]) * r1;
      __half* dst = cT + ((size_t)o * 2592 + n0 + (g >> 1)) * 32 + l15;
      dst[0] = __float2half(c0);
      dst[16] = __float2half(c1);
    }
  }
}

// ---------------- routing kernel B (fp8 MFMA): s = sum c*xhat ----------------
__device__ __forceinline__ i64 cu_pack8(float c, float4 a, float4 b) {
  union { unsigned u[2]; i64 v; } r;
  r.u[0] = fp8pair(c * a.x, c * a.y) | (fp8pair(c * a.z, c * a.w) << 16);
  r.u[1] = fp8pair(c * b.x, c * b.y) | (fp8pair(c * b.z, c * b.w) << 16);
  return r.v;
}

template <bool HASC>
__global__ __launch_bounds__(256) void k_B3(const unsigned char* __restrict__ Wq2,
                                            const float* __restrict__ u2,
                                            const __half* __restrict__ cT,
                                            float* __restrict__ s) {
  int o = blockIdx.x, kc = blockIdx.y;
  int t = threadIdx.x, lane = t & 63, wv = t >> 6;
  int l15 = lane & 15, h = lane >> 4;

  f32x4 acc0 = {0.f, 0.f, 0.f, 0.f}, acc1 = {0.f, 0.f, 0.f, 0.f};

#pragma unroll 1
  for (int st = wv; st < 81; st += 4) {
    int n = kc * 324 + st * 4 + h;
    i64 aq = *(const i64*)(Wq2 + (((size_t)o * 2592 + n) * 16 + l15) * 8);

    const float4* u0p = (const float4*)(u2 + ((size_t)l15 * 2592 + n) * 8);
    float4 u0a = u0p[0], u0b = u0p[1];
    const float4* u1p = (const float4*)(u2 + ((size_t)(l15 + 16) * 2592 + n) * 8);
    float4 u1a = u1p[0], u1b = u1p[1];

    float c0 = 16.0f, c1 = 16.0f;
    if (HASC) {
      const __half* cp = cT + ((size_t)o * 2592 + n) * 32;
      c0 = 16.0f * __half2float(cp[l15]);
      c1 = 16.0f * __half2float(cp[l15 + 16]);
    }
    i64 b0 = cu_pack8(c0, u0a, u0b);
    i64 b1 = cu_pack8(c1, u1a, u1b);

    acc0 = __builtin_amdgcn_mfma_f32_16x16x32_fp8_fp8(aq, b0, acc0, 0, 0, 0);
    acc1 = __builtin_amdgcn_mfma_f32_16x16x32_fp8_fp8(aq, b1, acc1, 0, 0, 0);
  }

#pragma unroll
  for (int r = 0; r < 4; ++r) {
    atomicAdd(s + ((size_t)l15 * 102 + o) * 16 + h * 4 + r, acc0[r]);
    atomicAdd(s + ((size_t)(l15 + 16) * 102 + o) * 16 + h * 4 + r, acc1[r]);
  }
}

// ---------------- squash v (dim 16); optional fp8 vsum (x1024) ----------------
__global__ void k_R(const float* __restrict__ s, float scale,
                    float* __restrict__ vout, const float* __restrict__ addin,
                    unsigned char* __restrict__ vsq) {
  int t = blockIdx.x * 256 + threadIdx.x;
  if (t >= 3264) return;
  const float* sp = s + t * 16;
  float r[16];
  float sq = 0.f;
#pragma unroll
  for (int d = 0; d < 16; ++d) {
    r[d] = sp[d] * scale;
    sq += r[d] * r[d];
  }
  float sc = (sq / (1.f + sq)) / sqrtf(sq + 1e-8f);
  float vv[16];
#pragma unroll
  for (int d = 0; d < 16; ++d) {
    vv[d] = r[d] * sc;
    vout[t * 16 + d] = vv[d];
  }
  if (vsq) {
    int b = t / 102, o = t - b * 102;
    float w[16];
#pragma unroll
    for (int d = 0; d < 16; ++d)
      w[d] = (addin ? (addin[t * 16 + d] + vv[d]) : vv[d]) * 1024.f;
    unsigned words[4];
#pragma unroll
    for (int q = 0; q < 4; ++q)
      words[q] = fp8pair(w[4 * q], w[4 * q + 1]) | (fp8pair(w[4 * q + 2], w[4 * q + 3]) << 16);
    *(uint4*)(vsq + ((size_t)o * 32 + b) * 16) =
        make_uint4(words[0], words[1], words[2], words[3]);
  }
}

// ---------------- fc chain ----------------
__global__ void k_fc1(const float* __restrict__ v2, const int* __restrict__ tgt,
                      const float* __restrict__ w1, const float* __restrict__ b1,
                      float* __restrict__ h1) {
  int j = blockIdx.x * 128 + threadIdx.x;
  int bq = blockIdx.y;
#pragma unroll
  for (int bi = 0; bi < 4; ++bi) {
    int b = bq * 4 + bi;
    int tb = tgt[b];
    float acc = b1[j];
    const float* vv = v2 + (b * 102 + tb) * 16;
    const float* wr = w1 + (tb * 16) * 512 + j;
#pragma unroll
    for (int d = 0; d < 16; ++d) acc += vv[d] * wr[d * 512];
    h1[b * 512 + j] = fmaxf(acc, 0.f);
  }
}

__global__ void k_fc2(const float* __restrict__ h1, const float* __restrict__ w2,
                      const float* __restrict__ b2, float* __restrict__ h2T) {
  int j = blockIdx.x * 128 + threadIdx.x;
  int bq = blockIdx.y;
  float acc[4];
#pragma unroll
  for (int bi = 0; bi < 4; ++bi) acc[bi] = b2[j];
  for (int k = 0; k < 512; ++k) {
    float wv = w2[k * 1024 + j];
#pragma unroll
    for (int bi = 0; bi < 4; ++bi) acc[bi] += h1[(bq * 4 + bi) * 512 + k] * wv;
  }
  float4 o;
  o.x = fmaxf(acc[0], 0.f); o.y = fmaxf(acc[1], 0.f);
  o.z = fmaxf(acc[2], 0.f); o.w = fmaxf(acc[3], 0.f);
  *(float4*)(h2T + j * 32 + bq * 4) = o;
}

__global__ void k_fc3a(const float* __restrict__ h2T, const float* __restrict__ w3,
                       float* __restrict__ p) {
  int j = blockIdx.x * 128 + threadIdx.x;
  int ky = blockIdx.y;
  float acc[32];
#pragma unroll
  for (int i = 0; i < 32; ++i) acc[i] = 0.f;
  int k0 = ky * 256;
  for (int k = k0; k < k0 + 256; ++k) {
    float wv = w3[(size_t)k * 37632 + j];
    const float4* hp = (const float4*)(h2T + k * 32);
#pragma unroll
    for (int q = 0; q < 8; ++q) {
      float4 h = hp[q];
      acc[q * 4 + 0] += h.x * wv; acc[q * 4 + 1] += h.y * wv;
      acc[q * 4 + 2] += h.z * wv; acc[q * 4 + 3] += h.w * wv;
    }
  }
#pragma unroll
  for (int i = 0; i < 32; ++i)
    p[((size_t)ky * 32 + i) * 37632 + j] = acc[i];
}

__global__ void k_fc3b(const float* __restrict__ p, const float* __restrict__ b3,
                       float* __restrict__ out) {
  int j = blockIdx.x * 256 + threadIdx.x;
  float bv = b3[j];
#pragma unroll 1
  for (int b = 0; b < 32; ++b) {
    float s = bv + p[(size_t)b * 37632 + j] + p[(size_t)(32 + b) * 37632 + j] +
              p[(size_t)(64 + b) * 37632 + j] + p[(size_t)(96 + b) * 37632 + j];
    out[52224 + (size_t)b * 37632 + j] = 1.0f / (1.0f + __expf(-s));
  }
}

// ---------------- host ----------------
extern "C" void kernel_launch(void* const* d_in, const int* in_sizes, int n_in,
                              void* d_out, int out_size, void* d_ws, size_t ws_size,
                              hipStream_t stream) {
  const float* x       = (const float*)d_in[0];
  const int*   targets = (const int*)d_in[1];
  const float* conv1_w = (const float*)d_in[2];
  const float* conv1_b = (const float*)d_in[3];
  const float* pc_w    = (const float*)d_in[4];
  const float* pc_b    = (const float*)d_in[5];
  const float* W       = (const float*)d_in[6];
  const float* fc1_w   = (const float*)d_in[7];
  const float* fc1_b   = (const float*)d_in[8];
  const float* fc2_w   = (const float*)d_in[9];
  const float* fc2_b   = (const float*)d_in[10];
  const float* fc3_w   = (const float*)d_in[11];
  const float* fc3_b   = (const float*)d_in[12];
  float* out = (float*)d_out;
  float* ws = (float*)d_ws;

  float* FEAT2 = ws + OFF_FEAT;
  unsigned short* C1WB = (unsigned short*)(ws + OFF_C1WT);
  unsigned char* PCWQ = (unsigned char*)(ws + OFF_PCWQ);
  float* PCP  = ws + OFF_PCP;
  float* U2   = ws + OFF_U2;
  unsigned char* WQ2 = (unsigned char*)(ws + OFF_WQ2);  // overlays FEAT2 after k_pc4
  unsigned char* WQ  = (unsigned char*)(ws + OFF_WQ);   // overlays PCP after squash2
  __half* CT  = (__half*)(ws + OFF_CT);
  float* FC3P = ws + OFF_FC3P;
  float* S    = ws + OFF_S;
  float* V0   = ws + OFF_V0;
  float* V1   = ws + OFF_V1;
  unsigned char* VSQ = (unsigned char*)(ws + OFF_VSQ);
  float* H1   = ws + OFF_H1;
  float* H2T  = ws + OFF_H2T;

  // weight prep (conv phase)
  k_mkC1B<<<dim3(256), 128, 0, stream>>>(conv1_w, C1WB);
  k_mkBq<<<dim3(256), 256, 0, stream>>>(pc_w, PCWQ);

  // conv1 + relu (bf16 MFMA)
  k_c1m<<<dim3(1088), 256, 0, stream>>>(x, C1WB, conv1_b, FEAT2);

  // primary caps conv (fp8 MFMA, 16-way K-split) + fused reduce/bias/squash
  k_pc4<<<dim3(41, 16), 256, 0, stream>>>(FEAT2, PCWQ, PCP);
  k_squash2<<<dim3(324), 256, 0, stream>>>(PCP, pc_b, U2);

  // routing pack: W read once -> two fp8 layouts (x64)
  k_mkW<<<dim3(1033), 256, 0, stream>>>(W, WQ2, WQ);

  // ---- routing ---- (scales: W x64, cu x16 -> /1024; vq x1024 -> logits /65536)
  hipMemsetAsync(S, 0, 52224 * sizeof(float), stream);
  k_B3<false><<<dim3(102, 8), 256, 0, stream>>>(WQ2, U2, nullptr, S);
  k_R<<<dim3(13), 256, 0, stream>>>(S, 1.0f / (102.0f * 1024.0f), V0, nullptr, VSQ);

  k_A2<<<dim3(648), 128, 0, stream>>>(WQ, U2, VSQ, CT);
  hipMemsetAsync(S, 0, 52224 * sizeof(float), stream);
  k_B3<true><<<dim3(102, 8), 256, 0, stream>>>(WQ2, U2, CT, S);
  k_R<<<dim3(13), 256, 0, stream>>>(S, 1.0f / 1024.0f, V1, V0, VSQ);  // vsq = v0+v1

  k_A2<<<dim3(648), 128, 0, stream>>>(WQ, U2, VSQ, CT);
  hipMemsetAsync(S, 0, 52224 * sizeof(float), stream);
  k_B3<true><<<dim3(102, 8), 256, 0, stream>>>(WQ2, U2, CT, S);
  k_R<<<dim3(13), 256, 0, stream>>>(S, 1.0f / 1024.0f, out, nullptr, nullptr);

  // ---- reconstruction ----
  k_fc1<<<dim3(4, 8), 128, 0, stream>>>(out, targets, fc1_w, fc1_b, H1);
  k_fc2<<<dim3(8, 8), 128, 0, stream>>>(H1, fc2_w, fc2_b, H2T);
  k_fc3a<<<dim3(294, 4), 128, 0, stream>>>(H2T, fc3_w, FC3P);
  k_fc3b<<<dim3(147), 256, 0, stream>>>(FC3P, fc3_b, out);
}

// Round 8
// 736.521 us; speedup vs baseline: 1.2048x; 1.2048x over previous
//
#include <hip/hip_runtime.h>
#include <hip/hip_fp16.h>
#include <math.h>

// ---------------- sizes ----------------
#define B32   32
#define OCLS  102
#define NCAPS 2592

// ---------------- ws map (floats) ----------------
#define OFF_FEAT   0u               // feat2[b][h][co][w36]: 10,027,008
#define OFF_WQ2    0u               // fp8 W pack [o][n][d][i]: 33,867,776 B
#define OFF_C1WT   10027008u        // bf16 conv1 pack: 3*256*128 ush
#define OFF_PCWQ   10119936u        // fp8 pc pack [ci][co][104]B
#define OFF_PCP    15428352u        // 16*32*81*256 = 10,616,832 -> ends 26,045,184
#define OFF_WQ     15428352u        // fp8 W pack [o][n][i][d] (overlays PCP after squash)
#define OFF_U2     26045184u
#define OFF_CT     26708736u        // fp16 c[o][n][b]
#define OFF_FC3P   26045184u        // fc3 partials (overlay U2+CT after routing)
#define OFF_S      30938880u
#define OFF_V0     30991104u
#define OFF_V1     31043328u
#define OFF_VSQ    31095552u
#define OFF_H1     31108608u
#define OFF_H2T    31124992u        // end 31,157,760

typedef __attribute__((ext_vector_type(8))) short short8;
typedef __attribute__((ext_vector_type(4))) float f32x4;
typedef long long i64;

__device__ __forceinline__ unsigned short f2b(float f) {
  union { float f; unsigned u; } v; v.f = f;
  unsigned r = v.u + 0x7fffu + ((v.u >> 16) & 1u);
  return (unsigned short)(r >> 16);
}

// float -> OCP e4m3fn (RNE, flush<2^-6, clamp) -- software fallback
__device__ __forceinline__ unsigned f2q_fast(float x) {
  union { float f; unsigned u; } v; v.f = x;
  unsigned s = (v.u >> 24) & 0x80u;
  unsigned au = v.u & 0x7fffffffu;
  if (au < 0x3c800000u) return s;
  if (au >= 0x43e00000u) return s | 0x7eu;
  unsigned r = au + 0x7ffffu + ((au >> 20) & 1u);
  unsigned e = (r >> 23) - 120u;
  unsigned m = (r >> 20) & 7u;
  return s | (e << 3) | m;
}

// two floats -> packed fp8 pair in low 16 bits (HW cvt when available)
__device__ __forceinline__ unsigned fp8pair(float a, float b) {
#if __has_builtin(__builtin_amdgcn_cvt_pk_fp8_f32)
  return (unsigned)__builtin_amdgcn_cvt_pk_fp8_f32(a, b, 0, false) & 0xffffu;
#else
  return f2q_fast(a) | (f2q_fast(b) << 8);
#endif
}

// ---------------- conv1_w -> bf16 [ci][co][128] ----------------
__global__ void k_mkC1B(const float* __restrict__ conv1_w,
                        unsigned short* __restrict__ C1WB) {
  int co = blockIdx.x;
  int t = threadIdx.x;  // 128
#pragma unroll
  for (int ci = 0; ci < 3; ++ci) {
    float v = (t < 121) ? conv1_w[co * 363 + ci * 121 + t] : 0.f;
    C1WB[(ci * 256 + co) * 128 + t] = f2b(v);
  }
}

// ---------------- pc_w -> fp8 x64 [ci][co][104]B ----------------
__global__ void k_mkBq(const float* __restrict__ pc_w, unsigned char* __restrict__ PCWQ) {
  int co = blockIdx.x;
  for (int e = threadIdx.x; e < 20736; e += 256) {
    int ci = e / 81, tap = e - ci * 81;
    PCWQ[(size_t)ci * 26624 + co * 104 + tap] =
        (unsigned char)f2q_fast(pc_w[(size_t)co * 20736 + e] * 64.f);
  }
  int ci = threadIdx.x;
  for (int tap = 81; tap < 104; ++tap)
    PCWQ[(size_t)ci * 26624 + co * 104 + tap] = 0;
}

// ---------------- W -> fp8 x64, coalesced: Wq2[on][d][i] + Wq[on][i][d] ----------------
// block = 32 on-rows. Thread t: 16 consecutive floats (4xfloat4, block reads 16KB
// contiguous). Wq2 = same order, direct uint4 store (4KB contiguous/block).
// Wq = within-row i<->d transpose via 4KB LDS byte-scatter, then linear uint4 store.
__global__ __launch_bounds__(256) void k_mkW2(const float* __restrict__ W,
                                              unsigned char* __restrict__ Wq2,
                                              unsigned char* __restrict__ Wq) {
  __shared__ unsigned char sq[32 * 128];
  int t = threadIdx.x;
  size_t base = (size_t)blockIdx.x * 4096;  // floats / bytes
  const float4* src = (const float4*)(W + base + (size_t)t * 16);
  float4 f0 = src[0], f1 = src[1], f2 = src[2], f3 = src[3];
  float v[16] = {f0.x, f0.y, f0.z, f0.w, f1.x, f1.y, f1.z, f1.w,
                 f2.x, f2.y, f2.z, f2.w, f3.x, f3.y, f3.z, f3.w};
  unsigned words[4];
#pragma unroll
  for (int j = 0; j < 4; ++j)
    words[j] = fp8pair(v[4 * j] * 64.f, v[4 * j + 1] * 64.f) |
               (fp8pair(v[4 * j + 2] * 64.f, v[4 * j + 3] * 64.f) << 16);
  *(uint4*)(Wq2 + base + (size_t)t * 16) =
      make_uint4(words[0], words[1], words[2], words[3]);

  int r = t >> 3, seg = t & 7;
#pragma unroll
  for (int e = 0; e < 16; ++e) {
    unsigned byte = (words[e >> 2] >> ((e & 3) * 8)) & 0xffu;
    int idx = seg * 16 + e, d = idx >> 3, i = idx & 7;
    sq[r * 128 + i * 16 + d] = (unsigned char)byte;
  }
  __syncthreads();
  *(uint4*)(Wq + base + (size_t)t * 16) = ((const uint4*)sq)[t];
}

// ---------------- conv1 via bf16 MFMA implicit-im2col ----------------
__global__ __launch_bounds__(256) void k_c1m(const float* __restrict__ x,
                                             const unsigned short* __restrict__ C1WB,
                                             const float* __restrict__ bias,
                                             float* __restrict__ feat2) {
  __shared__ unsigned short sh[48 * 128 + 256 * 128];
  unsigned short* lA = sh;
  unsigned short* lB = sh + 48 * 128;
  float* obuf = (float*)(sh + 48 * 128);

  int bx = blockIdx.x;
  int b = bx / 34, ho = bx % 34;
  int t = threadIdx.x;
  int lane = t & 63, wv = t >> 6;
  int l15 = lane & 15, lh = lane >> 4;
  int rx = l15 & 7;

  {
    uint4 zz = make_uint4(0, 0, 0, 0);
    uint4* z = (uint4*)lA;
    for (int i = t; i < 48 * 128 / 8; i += 256) z[i] = zz;
  }
  __syncthreads();

  f32x4 acc[3][4];
#pragma unroll
  for (int mf = 0; mf < 3; ++mf)
#pragma unroll
    for (int nf = 0; nf < 4; ++nf) acc[mf][nf] = (f32x4){0.f, 0.f, 0.f, 0.f};

#pragma unroll 1
  for (int ci = 0; ci < 3; ++ci) {
    {
      const uint4* Bsrc = (const uint4*)(C1WB + ci * 32768);
#pragma unroll
      for (int i = 0; i < 16; ++i) {
        int f = i * 256 + t;
        int row = f >> 4, cu = f & 15;
        ((uint4*)lB)[row * 16 + (cu ^ (row & 7))] = Bsrc[f];
      }
    }
    for (int tk = t; tk < 374; tk += 256) {
      int kh = tk / 34, wo = tk - kh * 34;
      const float* src = x + ((size_t)(b * 3 + ci) * 112 + ho * 3 + kh) * 112 + wo * 3;
#pragma unroll
      for (int j = 0; j < 11; ++j) {
        int tap = kh * 11 + j;
        int cu = tap >> 3;
        lA[wo * 128 + (((cu ^ (wo & 7)) << 3) | (tap & 7))] = f2b(src[j]);
      }
    }
    __syncthreads();

#pragma unroll
    for (int s = 0; s < 4; ++s) {
      int cub = ((s * 4 + lh) ^ rx) << 3;
      short8 a0 = *(const short8*)(lA + (0 + l15) * 128 + cub);
      short8 a1 = *(const short8*)(lA + (16 + l15) * 128 + cub);
      short8 a2 = *(const short8*)(lA + (32 + l15) * 128 + cub);
      short8 b0 = *(const short8*)(lB + (wv * 64 + 0 + l15) * 128 + cub);
      short8 b1 = *(const short8*)(lB + (wv * 64 + 16 + l15) * 128 + cub);
      short8 b2 = *(const short8*)(lB + (wv * 64 + 32 + l15) * 128 + cub);
      short8 b3 = *(const short8*)(lB + (wv * 64 + 48 + l15) * 128 + cub);
      acc[0][0] = __builtin_amdgcn_mfma_f32_16x16x32_bf16(a0, b0, acc[0][0], 0, 0, 0);
      acc[0][1] = __builtin_amdgcn_mfma_f32_16x16x32_bf16(a0, b1, acc[0][1], 0, 0, 0);
      acc[0][2] = __builtin_amdgcn_mfma_f32_16x16x32_bf16(a0, b2, acc[0][2], 0, 0, 0);
      acc[0][3] = __builtin_amdgcn_mfma_f32_16x16x32_bf16(a0, b3, acc[0][3], 0, 0, 0);
      acc[1][0] = __builtin_amdgcn_mfma_f32_16x16x32_bf16(a1, b0, acc[1][0], 0, 0, 0);
      acc[1][1] = __builtin_amdgcn_mfma_f32_16x16x32_bf16(a1, b1, acc[1][1], 0, 0, 0);
      acc[1][2] = __builtin_amdgcn_mfma_f32_16x16x32_bf16(a1, b2, acc[1][2], 0, 0, 0);
      acc[1][3] = __builtin_amdgcn_mfma_f32_16x16x32_bf16(a1, b3, acc[1][3], 0, 0, 0);
      acc[2][0] = __builtin_amdgcn_mfma_f32_16x16x32_bf16(a2, b0, acc[2][0], 0, 0, 0);
      acc[2][1] = __builtin_amdgcn_mfma_f32_16x16x32_bf16(a2, b1, acc[2][1], 0, 0, 0);
      acc[2][2] = __builtin_amdgcn_mfma_f32_16x16x32_bf16(a2, b2, acc[2][2], 0, 0, 0);
      acc[2][3] = __builtin_amdgcn_mfma_f32_16x16x32_bf16(a2, b3, acc[2][3], 0, 0, 0);
    }
    __syncthreads();
  }

  float bv[4];
#pragma unroll
  for (int nf = 0; nf < 4; ++nf) bv[nf] = bias[wv * 64 + nf * 16 + l15];
#pragma unroll
  for (int mf = 0; mf < 3; ++mf)
#pragma unroll
    for (int nf = 0; nf < 4; ++nf)
#pragma unroll
      for (int r = 0; r < 4; ++r) {
        int wo = mf * 16 + lh * 4 + r;
        if (wo < 36)
          obuf[(wv * 64 + nf * 16 + l15) * 36 + wo] = fmaxf(acc[mf][nf][r] + bv[nf], 0.f);
      }
  __syncthreads();
  float4* dst = (float4*)(feat2 + (size_t)bx * 9216);
  const float4* srcb = (const float4*)obuf;
#pragma unroll
  for (int i = 0; i < 9; ++i) dst[i * 256 + t] = srcb[i * 256 + t];
}

// ---------------- pc conv gather (fp8, HW cvt pairs) ----------------
__device__ __forceinline__ void pc_gather8(const float* __restrict__ feat2,
                                           unsigned char* __restrict__ dstbuf,
                                           int mb, int ci, int t) {
  for (int task = t; task < 576; task += 256) {
    int m = task / 9, kh = task - m * 9;
    int gm = mb * 64 + m;
    if (gm < 2592) {
      int b = gm / 81, p = gm - b * 81;
      int ho = p / 9, wo = p - ho * 9;
      const float* src = feat2 + ((size_t)(b * 34 + ho * 3 + kh) * 256 + ci) * 36 + wo * 3;
      unsigned char* dst = dstbuf + m * 104 + kh * 9;
      unsigned p01 = fp8pair(src[0], src[1]);
      unsigned p23 = fp8pair(src[2], src[3]);
      unsigned p45 = fp8pair(src[4], src[5]);
      unsigned p67 = fp8pair(src[6], src[7]);
      unsigned p8  = fp8pair(src[8], 0.f);
      dst[0] = p01; dst[1] = p01 >> 8;
      dst[2] = p23; dst[3] = p23 >> 8;
      dst[4] = p45; dst[5] = p45 >> 8;
      dst[6] = p67; dst[7] = p67 >> 8;
      dst[8] = p8;
    }
  }
}

// ---------------- primary caps conv: fp8 MFMA, kc=16, B-in-regs, A dbuf ----------------
__global__ __launch_bounds__(256, 3) void k_pc4(const float* __restrict__ feat2,
                                                const unsigned char* __restrict__ PCWQ,
                                                float* __restrict__ pcp) {
  __shared__ unsigned char lA[2][64 * 104];

  int mb = blockIdx.x, kc = blockIdx.y;  // (41, 16)
  int t = threadIdx.x;
  int lane = t & 63, wv = t >> 6;
  int l15 = lane & 15, lh = lane >> 4;

  {
    uint4 zz = make_uint4(0, 0, 0, 0);
    uint4* z = (uint4*)lA;
    for (int i = t; i < 2 * 64 * 104 / 16; i += 256) z[i] = zz;
  }
  __syncthreads();
  pc_gather8(feat2, lA[0], mb, kc * 16, t);
  __syncthreads();

  f32x4 acc[4][4];
#pragma unroll
  for (int mf = 0; mf < 4; ++mf)
#pragma unroll
    for (int nf = 0; nf < 4; ++nf) acc[mf][nf] = (f32x4){0.f, 0.f, 0.f, 0.f};

#pragma unroll 1
  for (int cil = 0; cil < 16; ++cil) {
    int ci = kc * 16 + cil;
    int cur = cil & 1;

    i64 bfr[4][3];
    const unsigned char* Bbase = PCWQ + (size_t)ci * 26624 + (wv * 64 + l15) * 104 + lh * 8;
#pragma unroll
    for (int nf = 0; nf < 4; ++nf)
#pragma unroll
      for (int s = 0; s < 3; ++s)
        bfr[nf][s] = *(const i64*)(Bbase + nf * 16 * 104 + s * 32);

    if (cil < 15) pc_gather8(feat2, lA[cur ^ 1], mb, ci + 1, t);

    const unsigned char* arow = lA[cur] + l15 * 104 + lh * 8;
#pragma unroll
    for (int s = 0; s < 3; ++s) {
      i64 a0 = *(const i64*)(arow + s * 32);
      i64 a1 = *(const i64*)(arow + 16 * 104 + s * 32);
      i64 a2 = *(const i64*)(arow + 32 * 104 + s * 32);
      i64 a3 = *(const i64*)(arow + 48 * 104 + s * 32);
      acc[0][0] = __builtin_amdgcn_mfma_f32_16x16x32_fp8_fp8(a0, bfr[0][s], acc[0][0], 0, 0, 0);
      acc[0][1] = __builtin_amdgcn_mfma_f32_16x16x32_fp8_fp8(a0, bfr[1][s], acc[0][1], 0, 0, 0);
      acc[0][2] = __builtin_amdgcn_mfma_f32_16x16x32_fp8_fp8(a0, bfr[2][s], acc[0][2], 0, 0, 0);
      acc[0][3] = __builtin_amdgcn_mfma_f32_16x16x32_fp8_fp8(a0, bfr[3][s], acc[0][3], 0, 0, 0);
      acc[1][0] = __builtin_amdgcn_mfma_f32_16x16x32_fp8_fp8(a1, bfr[0][s], acc[1][0], 0, 0, 0);
      acc[1][1] = __builtin_amdgcn_mfma_f32_16x16x32_fp8_fp8(a1, bfr[1][s], acc[1][1], 0, 0, 0);
      acc[1][2] = __builtin_amdgcn_mfma_f32_16x16x32_fp8_fp8(a1, bfr[2][s], acc[1][2], 0, 0, 0);
      acc[1][3] = __builtin_amdgcn_mfma_f32_16x16x32_fp8_fp8(a1, bfr[3][s], acc[1][3], 0, 0, 0);
      acc[2][0] = __builtin_amdgcn_mfma_f32_16x16x32_fp8_fp8(a2, bfr[0][s], acc[2][0], 0, 0, 0);
      acc[2][1] = __builtin_amdgcn_mfma_f32_16x16x32_fp8_fp8(a2, bfr[1][s], acc[2][1], 0, 0, 0);
      acc[2][2] = __builtin_amdgcn_mfma_f32_16x16x32_fp8_fp8(a2, bfr[2][s], acc[2][2], 0, 0, 0);
      acc[2][3] = __builtin_amdgcn_mfma_f32_16x16x32_fp8_fp8(a2, bfr[3][s], acc[2][3], 0, 0, 0);
      acc[3][0] = __builtin_amdgcn_mfma_f32_16x16x32_fp8_fp8(a3, bfr[0][s], acc[3][0], 0, 0, 0);
      acc[3][1] = __builtin_amdgcn_mfma_f32_16x16x32_fp8_fp8(a3, bfr[1][s], acc[3][1], 0, 0, 0);
      acc[3][2] = __builtin_amdgcn_mfma_f32_16x16x32_fp8_fp8(a3, bfr[2][s], acc[3][2], 0, 0, 0);
      acc[3][3] = __builtin_amdgcn_mfma_f32_16x16x32_fp8_fp8(a3, bfr[3][s], acc[3][3], 0, 0, 0);
    }
    __syncthreads();
  }

#pragma unroll
  for (int mf = 0; mf < 4; ++mf) {
    int gm = mb * 64 + mf * 16 + lh * 4;
    if (gm < 2592) {
      float* dst = pcp + (size_t)kc * 663552 + (size_t)gm * 256 + wv * 64 + l15;
#pragma unroll
      for (int nf = 0; nf < 4; ++nf)
#pragma unroll
        for (int r = 0; r < 4; ++r)
          dst[(size_t)r * 256 + nf * 16] = acc[mf][nf][r];
    }
  }
}

// ---------------- fused: sum 16 partials + /64 + bias + squash -> u2 ----------------
__global__ void k_squash2(const float* __restrict__ pcp, const float* __restrict__ pcb,
                          float* __restrict__ u2) {
  int t = blockIdx.x * 256 + threadIdx.x;  // < 82944
  int b = t / 2592, n = t - b * 2592;
  float v[8];
  float sq = 0.f;
#pragma unroll
  for (int i = 0; i < 8; ++i) {
    int f = n * 8 + i;
    int co = f / 81, p = f - co * 81;
    const float* base = pcp + (size_t)(b * 81 + p) * 256 + co;
    float s = 0.f;
#pragma unroll
    for (int c = 0; c < 16; ++c) s += base[(size_t)c * 663552];
    s = pcb[co] + s * 0.015625f;  // /64 (W x64 scale)
    v[i] = s;
    sq += s * s;
  }
  float sc = (sq / (1.f + sq)) / sqrtf(sq + 1e-8f);
#pragma unroll
  for (int i = 0; i < 8; ++i) u2[t * 8 + i] = v[i] * sc;
}

// ---------------- routing kernel A (fp8 MFMA): logits + softmax -> cT ----------------
__global__ __launch_bounds__(128) void k_A2(const unsigned char* __restrict__ Wq,
                                            const float* __restrict__ u2,
                                            const unsigned char* __restrict__ vq,
                                            __half* __restrict__ cT) {
  __shared__ __half Eld[102 * 2 * 2 * 32];
  int nb = blockIdx.x;  // 648
  int t = threadIdx.x, wv = t >> 6, lane = t & 63;
  int l15 = lane & 15, g = lane >> 4;
  int n0 = nb * 4 + 2 * wv;
  int nl = g >> 1, ih = (g & 1) * 4;

  float4 u0 = *(const float4*)(u2 + (((size_t)l15 * 2592 + n0 + nl) * 8 + ih));
  float4 u1 = *(const float4*)(u2 + (((size_t)(l15 + 16) * 2592 + n0 + nl) * 8 + ih));

  int nlA = l15 >> 3, iA = l15 & 7;
  const unsigned char* Ap = Wq + (((size_t)(n0 + nlA)) * 8 + iA) * 16 + (g & 1) * 8;
  const unsigned char* B0p = vq + (size_t)l15 * 16 + (g & 1) * 8;
  bool act = (g < 2);

  float den0 = 0.f, den1 = 0.f;
#pragma unroll 2
  for (int o = 0; o < 102; ++o) {
    i64 a = 0, b0 = 0, b1 = 0;
    if (act) {
      a  = *(const i64*)(Ap + (size_t)o * 331776);
      b0 = *(const i64*)(B0p + (size_t)o * 512);
      b1 = *(const i64*)(B0p + (size_t)o * 512 + 256);
    }
    f32x4 d0 = {0.f, 0.f, 0.f, 0.f}, d1 = {0.f, 0.f, 0.f, 0.f};
    d0 = __builtin_amdgcn_mfma_f32_16x16x32_fp8_fp8(a, b0, d0, 0, 0, 0);
    d1 = __builtin_amdgcn_mfma_f32_16x16x32_fp8_fp8(a, b1, d1, 0, 0, 0);
    float p0 = d0[0] * u0.x + d0[1] * u0.y + d0[2] * u0.z + d0[3] * u0.w;
    float p1 = d1[0] * u1.x + d1[1] * u1.y + d1[2] * u1.z + d1[3] * u1.w;
    p0 += __shfl_xor(p0, 16);
    p1 += __shfl_xor(p1, 16);
    p0 *= 1.52587890625e-05f;  // / (64 * 1024)
    p1 *= 1.52587890625e-05f;
    float e0 = __expf(p0), e1 = __expf(p1);
    den0 += e0; den1 += e1;
    if ((g & 1) == 0) {
      int base = (o * 2 + wv) * 64 + (g >> 1) * 16 + l15;
      Eld[base] = __float2half(e0);
      Eld[base + 32] = __float2half(e1);
    }
  }
  float r0 = 1.0f / den0, r1 = 1.0f / den1;
  if ((g & 1) == 0) {
    for (int o = 0; o < 102; ++o) {
      int base = (o * 2 + wv) * 64 + (g >> 1) * 16 + l15;
      float c0 = __half2float(Eld[base]) * r0;
      float c1 = __half2float(Eld[base + 32]) * r1;
      __half* dst = cT + ((size_t)o * 2592 + n0 + (g >> 1)) * 32 + l15;
      dst[0] = __float2half(c0);
      dst[16] = __float2half(c1);
    }
  }
}

// ---------------- routing kernel B (fp8 MFMA): s = sum c*xhat ----------------
__device__ __forceinline__ i64 cu_pack8(float c, float4 a, float4 b) {
  union { unsigned u[2]; i64 v; } r;
  r.u[0] = fp8pair(c * a.x, c * a.y) | (fp8pair(c * a.z, c * a.w) << 16);
  r.u[1] = fp8pair(c * b.x, c * b.y) | (fp8pair(c * b.z, c * b.w) << 16);
  return r.v;
}

template <bool HASC>
__global__ __launch_bounds__(256) void k_B3(const unsigned char* __restrict__ Wq2,
                                            const float* __restrict__ u2,
                                            const __half* __restrict__ cT,
                                            float* __restrict__ s) {
  int o = blockIdx.x, kc = blockIdx.y;
  int t = threadIdx.x, lane = t & 63, wv = t >> 6;
  int l15 = lane & 15, h = lane >> 4;

  f32x4 acc0 = {0.f, 0.f, 0.f, 0.f}, acc1 = {0.f, 0.f, 0.f, 0.f};

#pragma unroll 1
  for (int st = wv; st < 81; st += 4) {
    int n = kc * 324 + st * 4 + h;
    i64 aq = *(const i64*)(Wq2 + (((size_t)o * 2592 + n) * 16 + l15) * 8);

    const float4* u0p = (const float4*)(u2 + ((size_t)l15 * 2592 + n) * 8);
    float4 u0a = u0p[0], u0b = u0p[1];
    const float4* u1p = (const float4*)(u2 + ((size_t)(l15 + 16) * 2592 + n) * 8);
    float4 u1a = u1p[0], u1b = u1p[1];

    float c0 = 16.0f, c1 = 16.0f;
    if (HASC) {
      const __half* cp = cT + ((size_t)o * 2592 + n) * 32;
      c0 = 16.0f * __half2float(cp[l15]);
      c1 = 16.0f * __half2float(cp[l15 + 16]);
    }
    i64 b0 = cu_pack8(c0, u0a, u0b);
    i64 b1 = cu_pack8(c1, u1a, u1b);

    acc0 = __builtin_amdgcn_mfma_f32_16x16x32_fp8_fp8(aq, b0, acc0, 0, 0, 0);
    acc1 = __builtin_amdgcn_mfma_f32_16x16x32_fp8_fp8(aq, b1, acc1, 0, 0, 0);
  }

#pragma unroll
  for (int r = 0; r < 4; ++r) {
    atomicAdd(s + ((size_t)l15 * 102 + o) * 16 + h * 4 + r, acc0[r]);
    atomicAdd(s + ((size_t)(l15 + 16) * 102 + o) * 16 + h * 4 + r, acc1[r]);
  }
}

// ---------------- squash v (dim 16); optional fp8 vsum (x1024) ----------------
__global__ void k_R(const float* __restrict__ s, float scale,
                    float* __restrict__ vout, const float* __restrict__ addin,
                    unsigned char* __restrict__ vsq) {
  int t = blockIdx.x * 256 + threadIdx.x;
  if (t >= 3264) return;
  const float* sp = s + t * 16;
  float r[16];
  float sq = 0.f;
#pragma unroll
  for (int d = 0; d < 16; ++d) {
    r[d] = sp[d] * scale;
    sq += r[d] * r[d];
  }
  float sc = (sq / (1.f + sq)) / sqrtf(sq + 1e-8f);
  float vv[16];
#pragma unroll
  for (int d = 0; d < 16; ++d) {
    vv[d] = r[d] * sc;
    vout[t * 16 + d] = vv[d];
  }
  if (vsq) {
    int b = t / 102, o = t - b * 102;
    float w[16];
#pragma unroll
    for (int d = 0; d < 16; ++d)
      w[d] = (addin ? (addin[t * 16 + d] + vv[d]) : vv[d]) * 1024.f;
    unsigned words[4];
#pragma unroll
    for (int q = 0; q < 4; ++q)
      words[q] = fp8pair(w[4 * q], w[4 * q + 1]) | (fp8pair(w[4 * q + 2], w[4 * q + 3]) << 16);
    *(uint4*)(vsq + ((size_t)o * 32 + b) * 16) =
        make_uint4(words[0], words[1], words[2], words[3]);
  }
}

// ---------------- fc chain ----------------
__global__ void k_fc1(const float* __restrict__ v2, const int* __restrict__ tgt,
                      const float* __restrict__ w1, const float* __restrict__ b1,
                      float* __restrict__ h1) {
  int j = blockIdx.x * 128 + threadIdx.x;
  int bq = blockIdx.y;
#pragma unroll
  for (int bi = 0; bi < 4; ++bi) {
    int b = bq * 4 + bi;
    int tb = tgt[b];
    float acc = b1[j];
    const float* vv = v2 + (b * 102 + tb) * 16;
    const float* wr = w1 + (tb * 16) * 512 + j;
#pragma unroll
    for (int d = 0; d < 16; ++d) acc += vv[d] * wr[d * 512];
    h1[b * 512 + j] = fmaxf(acc, 0.f);
  }
}

__global__ void k_fc2(const float* __restrict__ h1, const float* __restrict__ w2,
                      const float* __restrict__ b2, float* __restrict__ h2T) {
  int j = blockIdx.x * 128 + threadIdx.x;
  int bq = blockIdx.y;
  float acc[4];
#pragma unroll
  for (int bi = 0; bi < 4; ++bi) acc[bi] = b2[j];
  for (int k = 0; k < 512; ++k) {
    float wv = w2[k * 1024 + j];
#pragma unroll
    for (int bi = 0; bi < 4; ++bi) acc[bi] += h1[(bq * 4 + bi) * 512 + k] * wv;
  }
  float4 o;
  o.x = fmaxf(acc[0], 0.f); o.y = fmaxf(acc[1], 0.f);
  o.z = fmaxf(acc[2], 0.f); o.w = fmaxf(acc[3], 0.f);
  *(float4*)(h2T + j * 32 + bq * 4) = o;
}

__global__ void k_fc3a(const float* __restrict__ h2T, const float* __restrict__ w3,
                       float* __restrict__ p) {
  int j = blockIdx.x * 128 + threadIdx.x;
  int ky = blockIdx.y;
  float acc[32];
#pragma unroll
  for (int i = 0; i < 32; ++i) acc[i] = 0.f;
  int k0 = ky * 256;
  for (int k = k0; k < k0 + 256; ++k) {
    float wv = w3[(size_t)k * 37632 + j];
    const float4* hp = (const float4*)(h2T + k * 32);
#pragma unroll
    for (int q = 0; q < 8; ++q) {
      float4 h = hp[q];
      acc[q * 4 + 0] += h.x * wv; acc[q * 4 + 1] += h.y * wv;
      acc[q * 4 + 2] += h.z * wv; acc[q * 4 + 3] += h.w * wv;
    }
  }
#pragma unroll
  for (int i = 0; i < 32; ++i)
    p[((size_t)ky * 32 + i) * 37632 + j] = acc[i];
}

__global__ void k_fc3b(const float* __restrict__ p, const float* __restrict__ b3,
                       float* __restrict__ out) {
  int j = blockIdx.x * 256 + threadIdx.x;
  float bv = b3[j];
#pragma unroll 1
  for (int b = 0; b < 32; ++b) {
    float s = bv + p[(size_t)b * 37632 + j] + p[(size_t)(32 + b) * 37632 + j] +
              p[(size_t)(64 + b) * 37632 + j] + p[(size_t)(96 + b) * 37632 + j];
    out[52224 + (size_t)b * 37632 + j] = 1.0f / (1.0f + __expf(-s));
  }
}

// ---------------- host ----------------
extern "C" void kernel_launch(void* const* d_in, const int* in_sizes, int n_in,
                              void* d_out, int out_size, void* d_ws, size_t ws_size,
                              hipStream_t stream) {
  const float* x       = (const float*)d_in[0];
  const int*   targets = (const int*)d_in[1];
  const float* conv1_w = (const float*)d_in[2];
  const float* conv1_b = (const float*)d_in[3];
  const float* pc_w    = (const float*)d_in[4];
  const float* pc_b    = (const float*)d_in[5];
  const float* W       = (const float*)d_in[6];
  const float* fc1_w   = (const float*)d_in[7];
  const float* fc1_b   = (const float*)d_in[8];
  const float* fc2_w   = (const float*)d_in[9];
  const float* fc2_b   = (const float*)d_in[10];
  const float* fc3_w   = (const float*)d_in[11];
  const float* fc3_b   = (const float*)d_in[12];
  float* out = (float*)d_out;
  float* ws = (float*)d_ws;

  float* FEAT2 = ws + OFF_FEAT;
  unsigned short* C1WB = (unsigned short*)(ws + OFF_C1WT);
  unsigned char* PCWQ = (unsigned char*)(ws + OFF_PCWQ);
  float* PCP  = ws + OFF_PCP;
  float* U2   = ws + OFF_U2;
  unsigned char* WQ2 = (unsigned char*)(ws + OFF_WQ2);  // overlays FEAT2 after k_pc4
  unsigned char* WQ  = (unsigned char*)(ws + OFF_WQ);   // overlays PCP after squash2
  __half* CT  = (__half*)(ws + OFF_CT);
  float* FC3P = ws + OFF_FC3P;
  float* S    = ws + OFF_S;
  float* V0   = ws + OFF_V0;
  float* V1   = ws + OFF_V1;
  unsigned char* VSQ = (unsigned char*)(ws + OFF_VSQ);
  float* H1   = ws + OFF_H1;
  float* H2T  = ws + OFF_H2T;

  // weight prep (conv phase)
  k_mkC1B<<<dim3(256), 128, 0, stream>>>(conv1_w, C1WB);
  k_mkBq<<<dim3(256), 256, 0, stream>>>(pc_w, PCWQ);

  // conv1 + relu (bf16 MFMA)
  k_c1m<<<dim3(1088), 256, 0, stream>>>(x, C1WB, conv1_b, FEAT2);

  // primary caps conv (fp8 MFMA, 16-way K-split) + fused reduce/bias/squash
  k_pc4<<<dim3(41, 16), 256, 0, stream>>>(FEAT2, PCWQ, PCP);
  k_squash2<<<dim3(324), 256, 0, stream>>>(PCP, pc_b, U2);

  // routing pack: W read once -> two fp8 layouts (x64), coalesced
  k_mkW2<<<dim3(8262), 256, 0, stream>>>(W, WQ2, WQ);

  // ---- routing ---- (scales: W x64, cu x16 -> /1024; vq x1024 -> logits /65536)
  hipMemsetAsync(S, 0, 52224 * sizeof(float), stream);
  k_B3<false><<<dim3(102, 8), 256, 0, stream>>>(WQ2, U2, nullptr, S);
  k_R<<<dim3(13), 256, 0, stream>>>(S, 1.0f / (102.0f * 1024.0f), V0, nullptr, VSQ);

  k_A2<<<dim3(648), 128, 0, stream>>>(WQ, U2, VSQ, CT);
  hipMemsetAsync(S, 0, 52224 * sizeof(float), stream);
  k_B3<true><<<dim3(102, 8), 256, 0, stream>>>(WQ2, U2, CT, S);
  k_R<<<dim3(13), 256, 0, stream>>>(S, 1.0f / 1024.0f, V1, V0, VSQ);  // vsq = v0+v1

  k_A2<<<dim3(648), 128, 0, stream>>>(WQ, U2, VSQ, CT);
  hipMemsetAsync(S, 0, 52224 * sizeof(float), stream);
  k_B3<true><<<dim3(102, 8), 256, 0, stream>>>(WQ2, U2, CT, S);
  k_R<<<dim3(13), 256, 0, stream>>>(S, 1.0f / 1024.0f, out, nullptr, nullptr);

  // ---- reconstruction ----
  k_fc1<<<dim3(4, 8), 128, 0, stream>>>(out, targets, fc1_w, fc1_b, H1);
  k_fc2<<<dim3(8, 8), 128, 0, stream>>>(H1, fc2_w, fc2_b, H2T);
  k_fc3a<<<dim3(294, 4), 128, 0, stream>>>(H2T, fc3_w, FC3P);
  k_fc3b<<<dim3(147), 256, 0, stream>>>(FC3P, fc3_b, out);
}

// Round 9
// 641.044 us; speedup vs baseline: 1.3843x; 1.1489x over previous
//
#include <hip/hip_runtime.h>
#include <hip/hip_fp16.h>
#include <math.h>

// ---------------- sizes ----------------
#define B32   32
#define OCLS  102
#define NCAPS 2592

// ---------------- ws map (floats) ----------------
#define OFF_FEAT   0u               // feat2[b][h][co][w36]: 10,027,008
#define OFF_WQ2    0u               // fp8 W pack [o][n][d][i]: 33,867,776 B
#define OFF_C1WT   10027008u        // bf16 conv1 pack: 3*256*128 ush
#define OFF_PCWQ   10119936u        // fp8 pc pack [ci][co][104]B
#define OFF_PCP    15428352u        // 16*32*81*256 = 10,616,832 -> ends 26,045,184
#define OFF_WQ     15428352u        // fp8 W pack [o][n][i][d] (overlays PCP after squash)
#define OFF_U2     26045184u
#define OFF_CT     26708736u        // fp16 c[o][n][b]
#define OFF_FC3P   26045184u        // fc3 partials (overlay U2+CT after routing)
#define OFF_S      30938880u
#define OFF_V0     30991104u
#define OFF_V1     31043328u
#define OFF_VSQ    31095552u
#define OFF_H1     31108608u
#define OFF_H2T    31124992u        // end 31,157,760

typedef __attribute__((ext_vector_type(8))) short short8;
typedef __attribute__((ext_vector_type(4))) float f32x4;
typedef long long i64;

__device__ __forceinline__ unsigned short f2b(float f) {
  union { float f; unsigned u; } v; v.f = f;
  unsigned r = v.u + 0x7fffu + ((v.u >> 16) & 1u);
  return (unsigned short)(r >> 16);
}

// float -> OCP e4m3fn (RNE, flush<2^-6, clamp) -- software fallback
__device__ __forceinline__ unsigned f2q_fast(float x) {
  union { float f; unsigned u; } v; v.f = x;
  unsigned s = (v.u >> 24) & 0x80u;
  unsigned au = v.u & 0x7fffffffu;
  if (au < 0x3c800000u) return s;
  if (au >= 0x43e00000u) return s | 0x7eu;
  unsigned r = au + 0x7ffffu + ((au >> 20) & 1u);
  unsigned e = (r >> 23) - 120u;
  unsigned m = (r >> 20) & 7u;
  return s | (e << 3) | m;
}

// two floats -> packed fp8 pair in low 16 bits (HW cvt when available)
__device__ __forceinline__ unsigned fp8pair(float a, float b) {
#if __has_builtin(__builtin_amdgcn_cvt_pk_fp8_f32)
  return (unsigned)__builtin_amdgcn_cvt_pk_fp8_f32(a, b, 0, false) & 0xffffu;
#else
  return f2q_fast(a) | (f2q_fast(b) << 8);
#endif
}

// ---------------- conv1_w -> bf16 [ci][co][128] ----------------
__global__ void k_mkC1B(const float* __restrict__ conv1_w,
                        unsigned short* __restrict__ C1WB) {
  int co = blockIdx.x;
  int t = threadIdx.x;  // 128
#pragma unroll
  for (int ci = 0; ci < 3; ++ci) {
    float v = (t < 121) ? conv1_w[co * 363 + ci * 121 + t] : 0.f;
    C1WB[(ci * 256 + co) * 128 + t] = f2b(v);
  }
}

// ---------------- pc_w -> fp8 x64 [ci][co][104]B ----------------
__global__ void k_mkBq(const float* __restrict__ pc_w, unsigned char* __restrict__ PCWQ) {
  int co = blockIdx.x;
  for (int e = threadIdx.x; e < 20736; e += 256) {
    int ci = e / 81, tap = e - ci * 81;
    PCWQ[(size_t)ci * 26624 + co * 104 + tap] =
        (unsigned char)f2q_fast(pc_w[(size_t)co * 20736 + e] * 64.f);
  }
  int ci = threadIdx.x;
  for (int tap = 81; tap < 104; ++tap)
    PCWQ[(size_t)ci * 26624 + co * 104 + tap] = 0;
}

// ---------------- W -> fp8 x64, coalesced: Wq2[on][d][i] + Wq[on][i][d] ----------------
__global__ __launch_bounds__(256) void k_mkW2(const float* __restrict__ W,
                                              unsigned char* __restrict__ Wq2,
                                              unsigned char* __restrict__ Wq) {
  __shared__ unsigned char sq[32 * 128];
  int t = threadIdx.x;
  size_t base = (size_t)blockIdx.x * 4096;  // floats / bytes
  const float4* src = (const float4*)(W + base + (size_t)t * 16);
  float4 f0 = src[0], f1 = src[1], f2 = src[2], f3 = src[3];
  float v[16] = {f0.x, f0.y, f0.z, f0.w, f1.x, f1.y, f1.z, f1.w,
                 f2.x, f2.y, f2.z, f2.w, f3.x, f3.y, f3.z, f3.w};
  unsigned words[4];
#pragma unroll
  for (int j = 0; j < 4; ++j)
    words[j] = fp8pair(v[4 * j] * 64.f, v[4 * j + 1] * 64.f) |
               (fp8pair(v[4 * j + 2] * 64.f, v[4 * j + 3] * 64.f) << 16);
  *(uint4*)(Wq2 + base + (size_t)t * 16) =
      make_uint4(words[0], words[1], words[2], words[3]);

  int r = t >> 3, seg = t & 7;
#pragma unroll
  for (int e = 0; e < 16; ++e) {
    unsigned byte = (words[e >> 2] >> ((e & 3) * 8)) & 0xffu;
    int idx = seg * 16 + e, d = idx >> 3, i = idx & 7;
    sq[r * 128 + i * 16 + d] = (unsigned char)byte;
  }
  __syncthreads();
  *(uint4*)(Wq + base + (size_t)t * 16) = ((const uint4*)sq)[t];
}

// ---------------- conv1 via bf16 MFMA implicit-im2col ----------------
__global__ __launch_bounds__(256) void k_c1m(const float* __restrict__ x,
                                             const unsigned short* __restrict__ C1WB,
                                             const float* __restrict__ bias,
                                             float* __restrict__ feat2) {
  __shared__ unsigned short sh[48 * 128 + 256 * 128];
  unsigned short* lA = sh;
  unsigned short* lB = sh + 48 * 128;
  float* obuf = (float*)(sh + 48 * 128);

  int bx = blockIdx.x;
  int b = bx / 34, ho = bx % 34;
  int t = threadIdx.x;
  int lane = t & 63, wv = t >> 6;
  int l15 = lane & 15, lh = lane >> 4;
  int rx = l15 & 7;

  {
    uint4 zz = make_uint4(0, 0, 0, 0);
    uint4* z = (uint4*)lA;
    for (int i = t; i < 48 * 128 / 8; i += 256) z[i] = zz;
  }
  __syncthreads();

  f32x4 acc[3][4];
#pragma unroll
  for (int mf = 0; mf < 3; ++mf)
#pragma unroll
    for (int nf = 0; nf < 4; ++nf) acc[mf][nf] = (f32x4){0.f, 0.f, 0.f, 0.f};

#pragma unroll 1
  for (int ci = 0; ci < 3; ++ci) {
    {
      const uint4* Bsrc = (const uint4*)(C1WB + ci * 32768);
#pragma unroll
      for (int i = 0; i < 16; ++i) {
        int f = i * 256 + t;
        int row = f >> 4, cu = f & 15;
        ((uint4*)lB)[row * 16 + (cu ^ (row & 7))] = Bsrc[f];
      }
    }
    for (int tk = t; tk < 374; tk += 256) {
      int kh = tk / 34, wo = tk - kh * 34;
      const float* src = x + ((size_t)(b * 3 + ci) * 112 + ho * 3 + kh) * 112 + wo * 3;
#pragma unroll
      for (int j = 0; j < 11; ++j) {
        int tap = kh * 11 + j;
        int cu = tap >> 3;
        lA[wo * 128 + (((cu ^ (wo & 7)) << 3) | (tap & 7))] = f2b(src[j]);
      }
    }
    __syncthreads();

#pragma unroll
    for (int s = 0; s < 4; ++s) {
      int cub = ((s * 4 + lh) ^ rx) << 3;
      short8 a0 = *(const short8*)(lA + (0 + l15) * 128 + cub);
      short8 a1 = *(const short8*)(lA + (16 + l15) * 128 + cub);
      short8 a2 = *(const short8*)(lA + (32 + l15) * 128 + cub);
      short8 b0 = *(const short8*)(lB + (wv * 64 + 0 + l15) * 128 + cub);
      short8 b1 = *(const short8*)(lB + (wv * 64 + 16 + l15) * 128 + cub);
      short8 b2 = *(const short8*)(lB + (wv * 64 + 32 + l15) * 128 + cub);
      short8 b3 = *(const short8*)(lB + (wv * 64 + 48 + l15) * 128 + cub);
      acc[0][0] = __builtin_amdgcn_mfma_f32_16x16x32_bf16(a0, b0, acc[0][0], 0, 0, 0);
      acc[0][1] = __builtin_amdgcn_mfma_f32_16x16x32_bf16(a0, b1, acc[0][1], 0, 0, 0);
      acc[0][2] = __builtin_amdgcn_mfma_f32_16x16x32_bf16(a0, b2, acc[0][2], 0, 0, 0);
      acc[0][3] = __builtin_amdgcn_mfma_f32_16x16x32_bf16(a0, b3, acc[0][3], 0, 0, 0);
      acc[1][0] = __builtin_amdgcn_mfma_f32_16x16x32_bf16(a1, b0, acc[1][0], 0, 0, 0);
      acc[1][1] = __builtin_amdgcn_mfma_f32_16x16x32_bf16(a1, b1, acc[1][1], 0, 0, 0);
      acc[1][2] = __builtin_amdgcn_mfma_f32_16x16x32_bf16(a1, b2, acc[1][2], 0, 0, 0);
      acc[1][3] = __builtin_amdgcn_mfma_f32_16x16x32_bf16(a1, b3, acc[1][3], 0, 0, 0);
      acc[2][0] = __builtin_amdgcn_mfma_f32_16x16x32_bf16(a2, b0, acc[2][0], 0, 0, 0);
      acc[2][1] = __builtin_amdgcn_mfma_f32_16x16x32_bf16(a2, b1, acc[2][1], 0, 0, 0);
      acc[2][2] = __builtin_amdgcn_mfma_f32_16x16x32_bf16(a2, b2, acc[2][2], 0, 0, 0);
      acc[2][3] = __builtin_amdgcn_mfma_f32_16x16x32_bf16(a2, b3, acc[2][3], 0, 0, 0);
    }
    __syncthreads();
  }

  float bv[4];
#pragma unroll
  for (int nf = 0; nf < 4; ++nf) bv[nf] = bias[wv * 64 + nf * 16 + l15];
#pragma unroll
  for (int mf = 0; mf < 3; ++mf)
#pragma unroll
    for (int nf = 0; nf < 4; ++nf)
#pragma unroll
      for (int r = 0; r < 4; ++r) {
        int wo = mf * 16 + lh * 4 + r;
        if (wo < 36)
          obuf[(wv * 64 + nf * 16 + l15) * 36 + wo] = fmaxf(acc[mf][nf][r] + bv[nf], 0.f);
      }
  __syncthreads();
  float4* dst = (float4*)(feat2 + (size_t)bx * 9216);
  const float4* srcb = (const float4*)obuf;
#pragma unroll
  for (int i = 0; i < 9; ++i) dst[i * 256 + t] = srcb[i * 256 + t];
}

// ---------------- pc conv gather (fp8, HW cvt pairs) ----------------
__device__ __forceinline__ void pc_gather8(const float* __restrict__ feat2,
                                           unsigned char* __restrict__ dstbuf,
                                           int mb, int ci, int t) {
  for (int task = t; task < 576; task += 256) {
    int m = task / 9, kh = task - m * 9;
    int gm = mb * 64 + m;
    if (gm < 2592) {
      int b = gm / 81, p = gm - b * 81;
      int ho = p / 9, wo = p - ho * 9;
      const float* src = feat2 + ((size_t)(b * 34 + ho * 3 + kh) * 256 + ci) * 36 + wo * 3;
      unsigned char* dst = dstbuf + m * 104 + kh * 9;
      unsigned p01 = fp8pair(src[0], src[1]);
      unsigned p23 = fp8pair(src[2], src[3]);
      unsigned p45 = fp8pair(src[4], src[5]);
      unsigned p67 = fp8pair(src[6], src[7]);
      unsigned p8  = fp8pair(src[8], 0.f);
      dst[0] = p01; dst[1] = p01 >> 8;
      dst[2] = p23; dst[3] = p23 >> 8;
      dst[4] = p45; dst[5] = p45 >> 8;
      dst[6] = p67; dst[7] = p67 >> 8;
      dst[8] = p8;
    }
  }
}

// ---------------- primary caps conv: fp8 MFMA, kc=16, B-in-regs, A dbuf ----------------
__global__ __launch_bounds__(256, 3) void k_pc4(const float* __restrict__ feat2,
                                                const unsigned char* __restrict__ PCWQ,
                                                float* __restrict__ pcp) {
  __shared__ unsigned char lA[2][64 * 104];

  int mb = blockIdx.x, kc = blockIdx.y;  // (41, 16)
  int t = threadIdx.x;
  int lane = t & 63, wv = t >> 6;
  int l15 = lane & 15, lh = lane >> 4;

  {
    uint4 zz = make_uint4(0, 0, 0, 0);
    uint4* z = (uint4*)lA;
    for (int i = t; i < 2 * 64 * 104 / 16; i += 256) z[i] = zz;
  }
  __syncthreads();
  pc_gather8(feat2, lA[0], mb, kc * 16, t);
  __syncthreads();

  f32x4 acc[4][4];
#pragma unroll
  for (int mf = 0; mf < 4; ++mf)
#pragma unroll
    for (int nf = 0; nf < 4; ++nf) acc[mf][nf] = (f32x4){0.f, 0.f, 0.f, 0.f};

#pragma unroll 1
  for (int cil = 0; cil < 16; ++cil) {
    int ci = kc * 16 + cil;
    int cur = cil & 1;

    i64 bfr[4][3];
    const unsigned char* Bbase = PCWQ + (size_t)ci * 26624 + (wv * 64 + l15) * 104 + lh * 8;
#pragma unroll
    for (int nf = 0; nf < 4; ++nf)
#pragma unroll
      for (int s = 0; s < 3; ++s)
        bfr[nf][s] = *(const i64*)(Bbase + nf * 16 * 104 + s * 32);

    if (cil < 15) pc_gather8(feat2, lA[cur ^ 1], mb, ci + 1, t);

    const unsigned char* arow = lA[cur] + l15 * 104 + lh * 8;
#pragma unroll
    for (int s = 0; s < 3; ++s) {
      i64 a0 = *(const i64*)(arow + s * 32);
      i64 a1 = *(const i64*)(arow + 16 * 104 + s * 32);
      i64 a2 = *(const i64*)(arow + 32 * 104 + s * 32);
      i64 a3 = *(const i64*)(arow + 48 * 104 + s * 32);
      acc[0][0] = __builtin_amdgcn_mfma_f32_16x16x32_fp8_fp8(a0, bfr[0][s], acc[0][0], 0, 0, 0);
      acc[0][1] = __builtin_amdgcn_mfma_f32_16x16x32_fp8_fp8(a0, bfr[1][s], acc[0][1], 0, 0, 0);
      acc[0][2] = __builtin_amdgcn_mfma_f32_16x16x32_fp8_fp8(a0, bfr[2][s], acc[0][2], 0, 0, 0);
      acc[0][3] = __builtin_amdgcn_mfma_f32_16x16x32_fp8_fp8(a0, bfr[3][s], acc[0][3], 0, 0, 0);
      acc[1][0] = __builtin_amdgcn_mfma_f32_16x16x32_fp8_fp8(a1, bfr[0][s], acc[1][0], 0, 0, 0);
      acc[1][1] = __builtin_amdgcn_mfma_f32_16x16x32_fp8_fp8(a1, bfr[1][s], acc[1][1], 0, 0, 0);
      acc[1][2] = __builtin_amdgcn_mfma_f32_16x16x32_fp8_fp8(a1, bfr[2][s], acc[1][2], 0, 0, 0);
      acc[1][3] = __builtin_amdgcn_mfma_f32_16x16x32_fp8_fp8(a1, bfr[3][s], acc[1][3], 0, 0, 0);
      acc[2][0] = __builtin_amdgcn_mfma_f32_16x16x32_fp8_fp8(a2, bfr[0][s], acc[2][0], 0, 0, 0);
      acc[2][1] = __builtin_amdgcn_mfma_f32_16x16x32_fp8_fp8(a2, bfr[1][s], acc[2][1], 0, 0, 0);
      acc[2][2] = __builtin_amdgcn_mfma_f32_16x16x32_fp8_fp8(a2, bfr[2][s], acc[2][2], 0, 0, 0);
      acc[2][3] = __builtin_amdgcn_mfma_f32_16x16x32_fp8_fp8(a2, bfr[3][s], acc[2][3], 0, 0, 0);
      acc[3][0] = __builtin_amdgcn_mfma_f32_16x16x32_fp8_fp8(a3, bfr[0][s], acc[3][0], 0, 0, 0);
      acc[3][1] = __builtin_amdgcn_mfma_f32_16x16x32_fp8_fp8(a3, bfr[1][s], acc[3][1], 0, 0, 0);
      acc[3][2] = __builtin_amdgcn_mfma_f32_16x16x32_fp8_fp8(a3, bfr[2][s], acc[3][2], 0, 0, 0);
      acc[3][3] = __builtin_amdgcn_mfma_f32_16x16x32_fp8_fp8(a3, bfr[3][s], acc[3][3], 0, 0, 0);
    }
    __syncthreads();
  }

#pragma unroll
  for (int mf = 0; mf < 4; ++mf) {
    int gm = mb * 64 + mf * 16 + lh * 4;
    if (gm < 2592) {
      float* dst = pcp + (size_t)kc * 663552 + (size_t)gm * 256 + wv * 64 + l15;
#pragma unroll
      for (int nf = 0; nf < 4; ++nf)
#pragma unroll
        for (int r = 0; r < 4; ++r)
          dst[(size_t)r * 256 + nf * 16] = acc[mf][nf][r];
    }
  }
}

// ---------------- fused transpose-reduce-squash: pcp(16 slices) -> u2 ----------------
// block = (b, cog); LDS tile[81][65] (pitch 65 breaks bank aliasing).
// Phase 1: coalesced 256B-run reads of 16 slices, reduce+bias into tile.
// Phase 2: 64co*81p = 5184 = 648 whole capsules/block; gather 8 elems from LDS,
// squash, write u2 as 2 contiguous float4 per capsule (coalesced).
__global__ __launch_bounds__(256) void k_rs(const float* __restrict__ pcp,
                                            const float* __restrict__ pcb,
                                            float* __restrict__ u2) {
  __shared__ float tile[81 * 65];
  int b = blockIdx.x;    // 32
  int cog = blockIdx.y;  // 4
  int c0 = cog * 64;
  int t = threadIdx.x;

  for (int e = t; e < 5184; e += 256) {
    int p = e >> 6, col = e & 63;
    const float* base = pcp + (size_t)(b * 81 + p) * 256 + c0 + col;
    float s = 0.f;
#pragma unroll
    for (int c = 0; c < 16; ++c) s += base[(size_t)c * 663552];
    tile[p * 65 + col] = pcb[c0 + col] + s * 0.015625f;  // /64 (W x64)
  }
  __syncthreads();

  for (int cap = t; cap < 648; cap += 256) {
    float v[8];
    float sq = 0.f;
#pragma unroll
    for (int i = 0; i < 8; ++i) {
      int g = cap * 8 + i;
      int col = g / 81, p = g - col * 81;
      v[i] = tile[p * 65 + col];
      sq += v[i] * v[i];
    }
    float sc = (sq / (1.f + sq)) / sqrtf(sq + 1e-8f);
    int n = cog * 648 + cap;
    float4* dst = (float4*)(u2 + ((size_t)b * 2592 + n) * 8);
    dst[0] = make_float4(v[0] * sc, v[1] * sc, v[2] * sc, v[3] * sc);
    dst[1] = make_float4(v[4] * sc, v[5] * sc, v[6] * sc, v[7] * sc);
  }
}

// ---------------- routing kernel A (fp8 MFMA): logits + softmax -> cT ----------------
__global__ __launch_bounds__(128) void k_A2(const unsigned char* __restrict__ Wq,
                                            const float* __restrict__ u2,
                                            const unsigned char* __restrict__ vq,
                                            __half* __restrict__ cT) {
  __shared__ __half Eld[102 * 2 * 2 * 32];
  int nb = blockIdx.x;  // 648
  int t = threadIdx.x, wv = t >> 6, lane = t & 63;
  int l15 = lane & 15, g = lane >> 4;
  int n0 = nb * 4 + 2 * wv;
  int nl = g >> 1, ih = (g & 1) * 4;

  float4 u0 = *(const float4*)(u2 + (((size_t)l15 * 2592 + n0 + nl) * 8 + ih));
  float4 u1 = *(const float4*)(u2 + (((size_t)(l15 + 16) * 2592 + n0 + nl) * 8 + ih));

  int nlA = l15 >> 3, iA = l15 & 7;
  const unsigned char* Ap = Wq + (((size_t)(n0 + nlA)) * 8 + iA) * 16 + (g & 1) * 8;
  const unsigned char* B0p = vq + (size_t)l15 * 16 + (g & 1) * 8;
  bool act = (g < 2);

  float den0 = 0.f, den1 = 0.f;
#pragma unroll 2
  for (int o = 0; o < 102; ++o) {
    i64 a = 0, b0 = 0, b1 = 0;
    if (act) {
      a  = *(const i64*)(Ap + (size_t)o * 331776);
      b0 = *(const i64*)(B0p + (size_t)o * 512);
      b1 = *(const i64*)(B0p + (size_t)o * 512 + 256);
    }
    f32x4 d0 = {0.f, 0.f, 0.f, 0.f}, d1 = {0.f, 0.f, 0.f, 0.f};
    d0 = __builtin_amdgcn_mfma_f32_16x16x32_fp8_fp8(a, b0, d0, 0, 0, 0);
    d1 = __builtin_amdgcn_mfma_f32_16x16x32_fp8_fp8(a, b1, d1, 0, 0, 0);
    float p0 = d0[0] * u0.x + d0[1] * u0.y + d0[2] * u0.z + d0[3] * u0.w;
    float p1 = d1[0] * u1.x + d1[1] * u1.y + d1[2] * u1.z + d1[3] * u1.w;
    p0 += __shfl_xor(p0, 16);
    p1 += __shfl_xor(p1, 16);
    p0 *= 1.52587890625e-05f;  // / (64 * 1024)
    p1 *= 1.52587890625e-05f;
    float e0 = __expf(p0), e1 = __expf(p1);
    den0 += e0; den1 += e1;
    if ((g & 1) == 0) {
      int base = (o * 2 + wv) * 64 + (g >> 1) * 16 + l15;
      Eld[base] = __float2half(e0);
      Eld[base + 32] = __float2half(e1);
    }
  }
  float r0 = 1.0f / den0, r1 = 1.0f / den1;
  if ((g & 1) == 0) {
    for (int o = 0; o < 102; ++o) {
      int base = (o * 2 + wv) * 64 + (g >> 1) * 16 + l15;
      float c0 = __half2float(Eld[base]) * r0;
      float c1 = __half2float(Eld[base + 32]) * r1;
      __half* dst = cT + ((size_t)o * 2592 + n0 + (g >> 1)) * 32 + l15;
      dst[0] = __float2half(c0);
      dst[16] = __float2half(c1);
    }
  }
}

// ---------------- routing kernel B (fp8 MFMA): s = sum c*xhat ----------------
__device__ __forceinline__ i64 cu_pack8(float c, float4 a, float4 b) {
  union { unsigned u[2]; i64 v; } r;
  r.u[0] = fp8pair(c * a.x, c * a.y) | (fp8pair(c * a.z, c * a.w) << 16);
  r.u[1] = fp8pair(c * b.x, c * b.y) | (fp8pair(c * b.z, c * b.w) << 16);
  return r.v;
}

template <bool HASC>
__global__ __launch_bounds__(256) void k_B3(const unsigned char* __restrict__ Wq2,
                                            const float* __restrict__ u2,
                                            const __half* __restrict__ cT,
                                            float* __restrict__ s) {
  int o = blockIdx.x, kc = blockIdx.y;
  int t = threadIdx.x, lane = t & 63, wv = t >> 6;
  int l15 = lane & 15, h = lane >> 4;

  f32x4 acc0 = {0.f, 0.f, 0.f, 0.f}, acc1 = {0.f, 0.f, 0.f, 0.f};

#pragma unroll 1
  for (int st = wv; st < 81; st += 4) {
    int n = kc * 324 + st * 4 + h;
    i64 aq = *(const i64*)(Wq2 + (((size_t)o * 2592 + n) * 16 + l15) * 8);

    const float4* u0p = (const float4*)(u2 + ((size_t)l15 * 2592 + n) * 8);
    float4 u0a = u0p[0], u0b = u0p[1];
    const float4* u1p = (const float4*)(u2 + ((size_t)(l15 + 16) * 2592 + n) * 8);
    float4 u1a = u1p[0], u1b = u1p[1];

    float c0 = 16.0f, c1 = 16.0f;
    if (HASC) {
      const __half* cp = cT + ((size_t)o * 2592 + n) * 32;
      c0 = 16.0f * __half2float(cp[l15]);
      c1 = 16.0f * __half2float(cp[l15 + 16]);
    }
    i64 b0 = cu_pack8(c0, u0a, u0b);
    i64 b1 = cu_pack8(c1, u1a, u1b);

    acc0 = __builtin_amdgcn_mfma_f32_16x16x32_fp8_fp8(aq, b0, acc0, 0, 0, 0);
    acc1 = __builtin_amdgcn_mfma_f32_16x16x32_fp8_fp8(aq, b1, acc1, 0, 0, 0);
  }

#pragma unroll
  for (int r = 0; r < 4; ++r) {
    atomicAdd(s + ((size_t)l15 * 102 + o) * 16 + h * 4 + r, acc0[r]);
    atomicAdd(s + ((size_t)(l15 + 16) * 102 + o) * 16 + h * 4 + r, acc1[r]);
  }
}

// ---------------- squash v (dim 16); optional fp8 vsum (x1024) ----------------
__global__ void k_R(const float* __restrict__ s, float scale,
                    float* __restrict__ vout, const float* __restrict__ addin,
                    unsigned char* __restrict__ vsq) {
  int t = blockIdx.x * 256 + threadIdx.x;
  if (t >= 3264) return;
  const float* sp = s + t * 16;
  float r[16];
  float sq = 0.f;
#pragma unroll
  for (int d = 0; d < 16; ++d) {
    r[d] = sp[d] * scale;
    sq += r[d] * r[d];
  }
  float sc = (sq / (1.f + sq)) / sqrtf(sq + 1e-8f);
  float vv[16];
#pragma unroll
  for (int d = 0; d < 16; ++d) {
    vv[d] = r[d] * sc;
    vout[t * 16 + d] = vv[d];
  }
  if (vsq) {
    int b = t / 102, o = t - b * 102;
    float w[16];
#pragma unroll
    for (int d = 0; d < 16; ++d)
      w[d] = (addin ? (addin[t * 16 + d] + vv[d]) : vv[d]) * 1024.f;
    unsigned words[4];
#pragma unroll
    for (int q = 0; q < 4; ++q)
      words[q] = fp8pair(w[4 * q], w[4 * q + 1]) | (fp8pair(w[4 * q + 2], w[4 * q + 3]) << 16);
    *(uint4*)(vsq + ((size_t)o * 32 + b) * 16) =
        make_uint4(words[0], words[1], words[2], words[3]);
  }
}

// ---------------- fc chain ----------------
__global__ void k_fc1(const float* __restrict__ v2, const int* __restrict__ tgt,
                      const float* __restrict__ w1, const float* __restrict__ b1,
                      float* __restrict__ h1) {
  int j = blockIdx.x * 128 + threadIdx.x;
  int bq = blockIdx.y;
#pragma unroll
  for (int bi = 0; bi < 4; ++bi) {
    int b = bq * 4 + bi;
    int tb = tgt[b];
    float acc = b1[j];
    const float* vv = v2 + (b * 102 + tb) * 16;
    const float* wr = w1 + (tb * 16) * 512 + j;
#pragma unroll
    for (int d = 0; d < 16; ++d) acc += vv[d] * wr[d * 512];
    h1[b * 512 + j] = fmaxf(acc, 0.f);
  }
}

__global__ void k_fc2(const float* __restrict__ h1, const float* __restrict__ w2,
                      const float* __restrict__ b2, float* __restrict__ h2T) {
  int j = blockIdx.x * 128 + threadIdx.x;
  int bq = blockIdx.y;
  float acc[4];
#pragma unroll
  for (int bi = 0; bi < 4; ++bi) acc[bi] = b2[j];
  for (int k = 0; k < 512; ++k) {
    float wv = w2[k * 1024 + j];
#pragma unroll
    for (int bi = 0; bi < 4; ++bi) acc[bi] += h1[(bq * 4 + bi) * 512 + k] * wv;
  }
  float4 o;
  o.x = fmaxf(acc[0], 0.f); o.y = fmaxf(acc[1], 0.f);
  o.z = fmaxf(acc[2], 0.f); o.w = fmaxf(acc[3], 0.f);
  *(float4*)(h2T + j * 32 + bq * 4) = o;
}

__global__ void k_fc3a(const float* __restrict__ h2T, const float* __restrict__ w3,
                       float* __restrict__ p) {
  int j = blockIdx.x * 128 + threadIdx.x;
  int ky = blockIdx.y;
  float acc[32];
#pragma unroll
  for (int i = 0; i < 32; ++i) acc[i] = 0.f;
  int k0 = ky * 256;
  for (int k = k0; k < k0 + 256; ++k) {
    float wv = w3[(size_t)k * 37632 + j];
    const float4* hp = (const float4*)(h2T + k * 32);
#pragma unroll
    for (int q = 0; q < 8; ++q) {
      float4 h = hp[q];
      acc[q * 4 + 0] += h.x * wv; acc[q * 4 + 1] += h.y * wv;
      acc[q * 4 + 2] += h.z * wv; acc[q * 4 + 3] += h.w * wv;
    }
  }
#pragma unroll
  for (int i = 0; i < 32; ++i)
    p[((size_t)ky * 32 + i) * 37632 + j] = acc[i];
}

__global__ void k_fc3b(const float* __restrict__ p, const float* __restrict__ b3,
                       float* __restrict__ out) {
  int j = blockIdx.x * 256 + threadIdx.x;
  float bv = b3[j];
#pragma unroll 1
  for (int b = 0; b < 32; ++b) {
    float s = bv + p[(size_t)b * 37632 + j] + p[(size_t)(32 + b) * 37632 + j] +
              p[(size_t)(64 + b) * 37632 + j] + p[(size_t)(96 + b) * 37632 + j];
    out[52224 + (size_t)b * 37632 + j] = 1.0f / (1.0f + __expf(-s));
  }
}

// ---------------- host ----------------
extern "C" void kernel_launch(void* const* d_in, const int* in_sizes, int n_in,
                              void* d_out, int out_size, void* d_ws, size_t ws_size,
                              hipStream_t stream) {
  const float* x       = (const float*)d_in[0];
  const int*   targets = (const int*)d_in[1];
  const float* conv1_w = (const float*)d_in[2];
  const float* conv1_b = (const float*)d_in[3];
  const float* pc_w    = (const float*)d_in[4];
  const float* pc_b    = (const float*)d_in[5];
  const float* W       = (const float*)d_in[6];
  const float* fc1_w   = (const float*)d_in[7];
  const float* fc1_b   = (const float*)d_in[8];
  const float* fc2_w   = (const float*)d_in[9];
  const float* fc2_b   = (const float*)d_in[10];
  const float* fc3_w   = (const float*)d_in[11];
  const float* fc3_b   = (const float*)d_in[12];
  float* out = (float*)d_out;
  float* ws = (float*)d_ws;

  float* FEAT2 = ws + OFF_FEAT;
  unsigned short* C1WB = (unsigned short*)(ws + OFF_C1WT);
  unsigned char* PCWQ = (unsigned char*)(ws + OFF_PCWQ);
  float* PCP  = ws + OFF_PCP;
  float* U2   = ws + OFF_U2;
  unsigned char* WQ2 = (unsigned char*)(ws + OFF_WQ2);  // overlays FEAT2 after k_pc4
  unsigned char* WQ  = (unsigned char*)(ws + OFF_WQ);   // overlays PCP after k_rs
  __half* CT  = (__half*)(ws + OFF_CT);
  float* FC3P = ws + OFF_FC3P;
  float* S    = ws + OFF_S;
  float* V0   = ws + OFF_V0;
  float* V1   = ws + OFF_V1;
  unsigned char* VSQ = (unsigned char*)(ws + OFF_VSQ);
  float* H1   = ws + OFF_H1;
  float* H2T  = ws + OFF_H2T;

  // weight prep (conv phase)
  k_mkC1B<<<dim3(256), 128, 0, stream>>>(conv1_w, C1WB);
  k_mkBq<<<dim3(256), 256, 0, stream>>>(pc_w, PCWQ);

  // conv1 + relu (bf16 MFMA)
  k_c1m<<<dim3(1088), 256, 0, stream>>>(x, C1WB, conv1_b, FEAT2);

  // primary caps conv (fp8 MFMA, 16-way K-split) + fused transpose/reduce/squash
  k_pc4<<<dim3(41, 16), 256, 0, stream>>>(FEAT2, PCWQ, PCP);
  k_rs<<<dim3(32, 4), 256, 0, stream>>>(PCP, pc_b, U2);

  // routing pack: W read once -> two fp8 layouts (x64), coalesced
  k_mkW2<<<dim3(8262), 256, 0, stream>>>(W, WQ2, WQ);

  // ---- routing ---- (scales: W x64, cu x16 -> /1024; vq x1024 -> logits /65536)
  hipMemsetAsync(S, 0, 52224 * sizeof(float), stream);
  k_B3<false><<<dim3(102, 8), 256, 0, stream>>>(WQ2, U2, nullptr, S);
  k_R<<<dim3(13), 256, 0, stream>>>(S, 1.0f / (102.0f * 1024.0f), V0, nullptr, VSQ);

  k_A2<<<dim3(648), 128, 0, stream>>>(WQ, U2, VSQ, CT);
  hipMemsetAsync(S, 0, 52224 * sizeof(float), stream);
  k_B3<true><<<dim3(102, 8), 256, 0, stream>>>(WQ2, U2, CT, S);
  k_R<<<dim3(13), 256, 0, stream>>>(S, 1.0f / 1024.0f, V1, V0, VSQ);  // vsq = v0+v1

  k_A2<<<dim3(648), 128, 0, stream>>>(WQ, U2, VSQ, CT);
  hipMemsetAsync(S, 0, 52224 * sizeof(float), stream);
  k_B3<true><<<dim3(102, 8), 256, 0, stream>>>(WQ2, U2, CT, S);
  k_R<<<dim3(13), 256, 0, stream>>>(S, 1.0f / 1024.0f, out, nullptr, nullptr);

  // ---- reconstruction ----
  k_fc1<<<dim3(4, 8), 128, 0, stream>>>(out, targets, fc1_w, fc1_b, H1);
  k_fc2<<<dim3(8, 8), 128, 0, stream>>>(H1, fc2_w, fc2_b, H2T);
  k_fc3a<<<dim3(294, 4), 128, 0, stream>>>(H2T, fc3_w, FC3P);
  k_fc3b<<<dim3(147), 256, 0, stream>>>(FC3P, fc3_b, out);
}

// Round 10
// 636.042 us; speedup vs baseline: 1.3952x; 1.0079x over previous
//
#include <hip/hip_runtime.h>
#include <hip/hip_fp16.h>
#include <math.h>

// ---------------- sizes ----------------
#define B32   32
#define OCLS  102
#define NCAPS 2592

// ---------------- ws map (floats) ----------------
#define OFF_FEAT   0u               // feat2[b][h][co][w36]: 10,027,008
#define OFF_WQ2    0u               // fp8 W pack [o][n][d][i]: 33,867,776 B
#define OFF_C1WT   10027008u        // bf16 conv1 pack: 3*256*128 ush
#define OFF_PCWQ   10119936u        // fp8 pc pack [ci][co][104]B
#define OFF_PCP    15428352u        // fp16 partials: 32*663552 halfs = 10,616,832 fl
#define OFF_WQ     15428352u        // fp8 W pack [o][n][i][d] (overlays PCP after k_rs)
#define OFF_U2     26045184u
#define OFF_CT     26708736u        // fp16 c[o][n][b]
#define OFF_FC3P   26045184u        // fc3 partials (overlay U2+CT after routing)
#define OFF_S      30938880u
#define OFF_V0     30991104u
#define OFF_V1     31043328u
#define OFF_VSQ    31095552u
#define OFF_H1     31108608u
#define OFF_H2T    31124992u        // end 31,157,760

typedef __attribute__((ext_vector_type(8))) short short8;
typedef __attribute__((ext_vector_type(4))) float f32x4;
typedef long long i64;

__device__ __forceinline__ unsigned short f2b(float f) {
  union { float f; unsigned u; } v; v.f = f;
  unsigned r = v.u + 0x7fffu + ((v.u >> 16) & 1u);
  return (unsigned short)(r >> 16);
}

// float -> OCP e4m3fn (RNE, flush<2^-6, clamp) -- software fallback
__device__ __forceinline__ unsigned f2q_fast(float x) {
  union { float f; unsigned u; } v; v.f = x;
  unsigned s = (v.u >> 24) & 0x80u;
  unsigned au = v.u & 0x7fffffffu;
  if (au < 0x3c800000u) return s;
  if (au >= 0x43e00000u) return s | 0x7eu;
  unsigned r = au + 0x7ffffu + ((au >> 20) & 1u);
  unsigned e = (r >> 23) - 120u;
  unsigned m = (r >> 20) & 7u;
  return s | (e << 3) | m;
}

// two floats -> packed fp8 pair in low 16 bits (HW cvt when available)
__device__ __forceinline__ unsigned fp8pair(float a, float b) {
#if __has_builtin(__builtin_amdgcn_cvt_pk_fp8_f32)
  return (unsigned)__builtin_amdgcn_cvt_pk_fp8_f32(a, b, 0, false) & 0xffffu;
#else
  return f2q_fast(a) | (f2q_fast(b) << 8);
#endif
}

// ---------------- conv1_w -> bf16 [ci][co][128] ----------------
__global__ void k_mkC1B(const float* __restrict__ conv1_w,
                        unsigned short* __restrict__ C1WB) {
  int co = blockIdx.x;
  int t = threadIdx.x;  // 128
#pragma unroll
  for (int ci = 0; ci < 3; ++ci) {
    float v = (t < 121) ? conv1_w[co * 363 + ci * 121 + t] : 0.f;
    C1WB[(ci * 256 + co) * 128 + t] = f2b(v);
  }
}

// ---------------- pc_w -> fp8 x64 [ci][co][104]B ----------------
__global__ void k_mkBq(const float* __restrict__ pc_w, unsigned char* __restrict__ PCWQ) {
  int co = blockIdx.x;
  for (int e = threadIdx.x; e < 20736; e += 256) {
    int ci = e / 81, tap = e - ci * 81;
    PCWQ[(size_t)ci * 26624 + co * 104 + tap] =
        (unsigned char)f2q_fast(pc_w[(size_t)co * 20736 + e] * 64.f);
  }
  int ci = threadIdx.x;
  for (int tap = 81; tap < 104; ++tap)
    PCWQ[(size_t)ci * 26624 + co * 104 + tap] = 0;
}

// ---------------- W -> fp8 x64, coalesced: Wq2[on][d][i] + Wq[on][i][d] ----------------
__global__ __launch_bounds__(256) void k_mkW2(const float* __restrict__ W,
                                              unsigned char* __restrict__ Wq2,
                                              unsigned char* __restrict__ Wq) {
  __shared__ unsigned char sq[32 * 128];
  int t = threadIdx.x;
  size_t base = (size_t)blockIdx.x * 4096;  // floats / bytes
  const float4* src = (const float4*)(W + base + (size_t)t * 16);
  float4 f0 = src[0], f1 = src[1], f2 = src[2], f3 = src[3];
  float v[16] = {f0.x, f0.y, f0.z, f0.w, f1.x, f1.y, f1.z, f1.w,
                 f2.x, f2.y, f2.z, f2.w, f3.x, f3.y, f3.z, f3.w};
  unsigned words[4];
#pragma unroll
  for (int j = 0; j < 4; ++j)
    words[j] = fp8pair(v[4 * j] * 64.f, v[4 * j + 1] * 64.f) |
               (fp8pair(v[4 * j + 2] * 64.f, v[4 * j + 3] * 64.f) << 16);
  *(uint4*)(Wq2 + base + (size_t)t * 16) =
      make_uint4(words[0], words[1], words[2], words[3]);

  int r = t >> 3, seg = t & 7;
#pragma unroll
  for (int e = 0; e < 16; ++e) {
    unsigned byte = (words[e >> 2] >> ((e & 3) * 8)) & 0xffu;
    int idx = seg * 16 + e, d = idx >> 3, i = idx & 7;
    sq[r * 128 + i * 16 + d] = (unsigned char)byte;
  }
  __syncthreads();
  *(uint4*)(Wq + base + (size_t)t * 16) = ((const uint4*)sq)[t];
}

// ---------------- conv1 via bf16 MFMA, co-split x2 ----------------
// grid (1088, 2): block = (b,ho, co-half). LDS: lA 48x128 (12KB) + lB 128x128 (32KB).
__global__ __launch_bounds__(256) void k_c1m(const float* __restrict__ x,
                                             const unsigned short* __restrict__ C1WB,
                                             const float* __restrict__ bias,
                                             float* __restrict__ feat2) {
  __shared__ unsigned short sh[48 * 128 + 128 * 128];
  unsigned short* lA = sh;
  unsigned short* lB = sh + 48 * 128;
  float* obuf = (float*)(sh + 48 * 128);  // 18432B < 32768B, reused in epilogue

  int bx = blockIdx.x;
  int hf = blockIdx.y;  // co half
  int b = bx / 34, ho = bx % 34;
  int t = threadIdx.x;
  int lane = t & 63, wv = t >> 6;
  int l15 = lane & 15, lh = lane >> 4;
  int rx = l15 & 7;

  {
    uint4 zz = make_uint4(0, 0, 0, 0);
    uint4* z = (uint4*)lA;
    for (int i = t; i < 48 * 128 / 8; i += 256) z[i] = zz;
  }
  __syncthreads();

  f32x4 acc[3][2];
#pragma unroll
  for (int mf = 0; mf < 3; ++mf)
#pragma unroll
    for (int nf = 0; nf < 2; ++nf) acc[mf][nf] = (f32x4){0.f, 0.f, 0.f, 0.f};

#pragma unroll 1
  for (int ci = 0; ci < 3; ++ci) {
    {
      const uint4* Bsrc = (const uint4*)(C1WB + ci * 32768 + hf * 16384);
#pragma unroll
      for (int i = 0; i < 8; ++i) {
        int f = i * 256 + t;
        int row = f >> 4, cu = f & 15;
        ((uint4*)lB)[row * 16 + (cu ^ (row & 7))] = Bsrc[f];
      }
    }
    for (int tk = t; tk < 374; tk += 256) {
      int kh = tk / 34, wo = tk - kh * 34;
      const float* src = x + ((size_t)(b * 3 + ci) * 112 + ho * 3 + kh) * 112 + wo * 3;
#pragma unroll
      for (int j = 0; j < 11; ++j) {
        int tap = kh * 11 + j;
        int cu = tap >> 3;
        lA[wo * 128 + (((cu ^ (wo & 7)) << 3) | (tap & 7))] = f2b(src[j]);
      }
    }
    __syncthreads();

#pragma unroll
    for (int s = 0; s < 4; ++s) {
      int cub = ((s * 4 + lh) ^ rx) << 3;
      short8 a0 = *(const short8*)(lA + (0 + l15) * 128 + cub);
      short8 a1 = *(const short8*)(lA + (16 + l15) * 128 + cub);
      short8 a2 = *(const short8*)(lA + (32 + l15) * 128 + cub);
      short8 b0 = *(const short8*)(lB + (wv * 32 + 0 + l15) * 128 + cub);
      short8 b1 = *(const short8*)(lB + (wv * 32 + 16 + l15) * 128 + cub);
      acc[0][0] = __builtin_amdgcn_mfma_f32_16x16x32_bf16(a0, b0, acc[0][0], 0, 0, 0);
      acc[0][1] = __builtin_amdgcn_mfma_f32_16x16x32_bf16(a0, b1, acc[0][1], 0, 0, 0);
      acc[1][0] = __builtin_amdgcn_mfma_f32_16x16x32_bf16(a1, b0, acc[1][0], 0, 0, 0);
      acc[1][1] = __builtin_amdgcn_mfma_f32_16x16x32_bf16(a1, b1, acc[1][1], 0, 0, 0);
      acc[2][0] = __builtin_amdgcn_mfma_f32_16x16x32_bf16(a2, b0, acc[2][0], 0, 0, 0);
      acc[2][1] = __builtin_amdgcn_mfma_f32_16x16x32_bf16(a2, b1, acc[2][1], 0, 0, 0);
    }
    __syncthreads();
  }

  float bv[2];
#pragma unroll
  for (int nf = 0; nf < 2; ++nf) bv[nf] = bias[hf * 128 + wv * 32 + nf * 16 + l15];
#pragma unroll
  for (int mf = 0; mf < 3; ++mf)
#pragma unroll
    for (int nf = 0; nf < 2; ++nf)
#pragma unroll
      for (int r = 0; r < 4; ++r) {
        int wo = mf * 16 + lh * 4 + r;
        if (wo < 36)
          obuf[(wv * 32 + nf * 16 + l15) * 36 + wo] = fmaxf(acc[mf][nf][r] + bv[nf], 0.f);
      }
  __syncthreads();
  float4* dst = (float4*)(feat2 + (size_t)bx * 9216 + hf * 4608);
  const float4* srcb = (const float4*)obuf;
  for (int i = t; i < 1152; i += 256) dst[i] = srcb[i];
}

// ---------------- pc conv gather (fp8, HW cvt pairs) ----------------
__device__ __forceinline__ void pc_gather8(const float* __restrict__ feat2,
                                           unsigned char* __restrict__ dstbuf,
                                           int mb, int ci, int t) {
  for (int task = t; task < 576; task += 256) {
    int m = task / 9, kh = task - m * 9;
    int gm = mb * 64 + m;
    if (gm < 2592) {
      int b = gm / 81, p = gm - b * 81;
      int ho = p / 9, wo = p - ho * 9;
      const float* src = feat2 + ((size_t)(b * 34 + ho * 3 + kh) * 256 + ci) * 36 + wo * 3;
      unsigned char* dst = dstbuf + m * 104 + kh * 9;
      unsigned p01 = fp8pair(src[0], src[1]);
      unsigned p23 = fp8pair(src[2], src[3]);
      unsigned p45 = fp8pair(src[4], src[5]);
      unsigned p67 = fp8pair(src[6], src[7]);
      unsigned p8  = fp8pair(src[8], 0.f);
      dst[0] = p01; dst[1] = p01 >> 8;
      dst[2] = p23; dst[3] = p23 >> 8;
      dst[4] = p45; dst[5] = p45 >> 8;
      dst[6] = p67; dst[7] = p67 >> 8;
      dst[8] = p8;
    }
  }
}

// ---------------- primary caps conv: fp8 MFMA, kc=32, fp16 partials ----------------
__global__ __launch_bounds__(256, 3) void k_pc4(const float* __restrict__ feat2,
                                                const unsigned char* __restrict__ PCWQ,
                                                __half* __restrict__ pcp) {
  __shared__ unsigned char lA[2][64 * 104];

  int mb = blockIdx.x, kc = blockIdx.y;  // (41, 32)
  int t = threadIdx.x;
  int lane = t & 63, wv = t >> 6;
  int l15 = lane & 15, lh = lane >> 4;

  {
    uint4 zz = make_uint4(0, 0, 0, 0);
    uint4* z = (uint4*)lA;
    for (int i = t; i < 2 * 64 * 104 / 16; i += 256) z[i] = zz;
  }
  __syncthreads();
  pc_gather8(feat2, lA[0], mb, kc * 8, t);
  __syncthreads();

  f32x4 acc[4][4];
#pragma unroll
  for (int mf = 0; mf < 4; ++mf)
#pragma unroll
    for (int nf = 0; nf < 4; ++nf) acc[mf][nf] = (f32x4){0.f, 0.f, 0.f, 0.f};

#pragma unroll 1
  for (int cil = 0; cil < 8; ++cil) {
    int ci = kc * 8 + cil;
    int cur = cil & 1;

    i64 bfr[4][3];
    const unsigned char* Bbase = PCWQ + (size_t)ci * 26624 + (wv * 64 + l15) * 104 + lh * 8;
#pragma unroll
    for (int nf = 0; nf < 4; ++nf)
#pragma unroll
      for (int s = 0; s < 3; ++s)
        bfr[nf][s] = *(const i64*)(Bbase + nf * 16 * 104 + s * 32);

    if (cil < 7) pc_gather8(feat2, lA[cur ^ 1], mb, ci + 1, t);

    const unsigned char* arow = lA[cur] + l15 * 104 + lh * 8;
#pragma unroll
    for (int s = 0; s < 3; ++s) {
      i64 a0 = *(const i64*)(arow + s * 32);
      i64 a1 = *(const i64*)(arow + 16 * 104 + s * 32);
      i64 a2 = *(const i64*)(arow + 32 * 104 + s * 32);
      i64 a3 = *(const i64*)(arow + 48 * 104 + s * 32);
      acc[0][0] = __builtin_amdgcn_mfma_f32_16x16x32_fp8_fp8(a0, bfr[0][s], acc[0][0], 0, 0, 0);
      acc[0][1] = __builtin_amdgcn_mfma_f32_16x16x32_fp8_fp8(a0, bfr[1][s], acc[0][1], 0, 0, 0);
      acc[0][2] = __builtin_amdgcn_mfma_f32_16x16x32_fp8_fp8(a0, bfr[2][s], acc[0][2], 0, 0, 0);
      acc[0][3] = __builtin_amdgcn_mfma_f32_16x16x32_fp8_fp8(a0, bfr[3][s], acc[0][3], 0, 0, 0);
      acc[1][0] = __builtin_amdgcn_mfma_f32_16x16x32_fp8_fp8(a1, bfr[0][s], acc[1][0], 0, 0, 0);
      acc[1][1] = __builtin_amdgcn_mfma_f32_16x16x32_fp8_fp8(a1, bfr[1][s], acc[1][1], 0, 0, 0);
      acc[1][2] = __builtin_amdgcn_mfma_f32_16x16x32_fp8_fp8(a1, bfr[2][s], acc[1][2], 0, 0, 0);
      acc[1][3] = __builtin_amdgcn_mfma_f32_16x16x32_fp8_fp8(a1, bfr[3][s], acc[1][3], 0, 0, 0);
      acc[2][0] = __builtin_amdgcn_mfma_f32_16x16x32_fp8_fp8(a2, bfr[0][s], acc[2][0], 0, 0, 0);
      acc[2][1] = __builtin_amdgcn_mfma_f32_16x16x32_fp8_fp8(a2, bfr[1][s], acc[2][1], 0, 0, 0);
      acc[2][2] = __builtin_amdgcn_mfma_f32_16x16x32_fp8_fp8(a2, bfr[2][s], acc[2][2], 0, 0, 0);
      acc[2][3] = __builtin_amdgcn_mfma_f32_16x16x32_fp8_fp8(a2, bfr[3][s], acc[2][3], 0, 0, 0);
      acc[3][0] = __builtin_amdgcn_mfma_f32_16x16x32_fp8_fp8(a3, bfr[0][s], acc[3][0], 0, 0, 0);
      acc[3][1] = __builtin_amdgcn_mfma_f32_16x16x32_fp8_fp8(a3, bfr[1][s], acc[3][1], 0, 0, 0);
      acc[3][2] = __builtin_amdgcn_mfma_f32_16x16x32_fp8_fp8(a3, bfr[2][s], acc[3][2], 0, 0, 0);
      acc[3][3] = __builtin_amdgcn_mfma_f32_16x16x32_fp8_fp8(a3, bfr[3][s], acc[3][3], 0, 0, 0);
    }
    __syncthreads();
  }

#pragma unroll
  for (int mf = 0; mf < 4; ++mf) {
    int gm = mb * 64 + mf * 16 + lh * 4;
    if (gm < 2592) {
      __half* dst = pcp + (size_t)kc * 663552 + (size_t)gm * 256 + wv * 64 + l15;
#pragma unroll
      for (int nf = 0; nf < 4; ++nf)
#pragma unroll
        for (int r = 0; r < 4; ++r)
          dst[(size_t)r * 256 + nf * 16] = __float2half(acc[mf][nf][r]);
    }
  }
}

// ---------------- fused transpose-reduce-squash: pcp(32 fp16 slices) -> u2 ----------------
// grid (32,16): block = (b, 16-co group); 16*81=1296 elems = 162 whole capsules.
__global__ __launch_bounds__(256) void k_rs(const __half* __restrict__ pcp,
                                            const float* __restrict__ pcb,
                                            float* __restrict__ u2) {
  __shared__ float tile[81 * 17];
  int b = blockIdx.x;    // 32
  int cog = blockIdx.y;  // 16
  int c0 = cog * 16;
  int t = threadIdx.x;

  for (int e = t; e < 1296; e += 256) {
    int p = e >> 4, col = e & 15;
    const __half* base = pcp + (size_t)(b * 81 + p) * 256 + c0 + col;
    float s = 0.f;
#pragma unroll
    for (int c = 0; c < 32; ++c) s += __half2float(base[(size_t)c * 663552]);
    tile[p * 17 + col] = pcb[c0 + col] + s * 0.015625f;  // /64 (W x64)
  }
  __syncthreads();

  if (t < 162) {
    float v[8];
    float sq = 0.f;
#pragma unroll
    for (int i = 0; i < 8; ++i) {
      int g = t * 8 + i;
      int col = g / 81, p = g - col * 81;
      v[i] = tile[p * 17 + col];
      sq += v[i] * v[i];
    }
    float sc = (sq / (1.f + sq)) / sqrtf(sq + 1e-8f);
    int n = cog * 162 + t;
    float4* dst = (float4*)(u2 + ((size_t)b * 2592 + n) * 8);
    dst[0] = make_float4(v[0] * sc, v[1] * sc, v[2] * sc, v[3] * sc);
    dst[1] = make_float4(v[4] * sc, v[5] * sc, v[6] * sc, v[7] * sc);
  }
}

// ---------------- routing kernel A (fp8 MFMA): logits + softmax -> cT ----------------
__global__ __launch_bounds__(128) void k_A2(const unsigned char* __restrict__ Wq,
                                            const float* __restrict__ u2,
                                            const unsigned char* __restrict__ vq,
                                            __half* __restrict__ cT) {
  __shared__ __half Eld[102 * 2 * 2 * 32];
  int nb = blockIdx.x;  // 648
  int t = threadIdx.x, wv = t >> 6, lane = t & 63;
  int l15 = lane & 15, g = lane >> 4;
  int n0 = nb * 4 + 2 * wv;
  int nl = g >> 1, ih = (g & 1) * 4;

  float4 u0 = *(const float4*)(u2 + (((size_t)l15 * 2592 + n0 + nl) * 8 + ih));
  float4 u1 = *(const float4*)(u2 + (((size_t)(l15 + 16) * 2592 + n0 + nl) * 8 + ih));

  int nlA = l15 >> 3, iA = l15 & 7;
  const unsigned char* Ap = Wq + (((size_t)(n0 + nlA)) * 8 + iA) * 16 + (g & 1) * 8;
  const unsigned char* B0p = vq + (size_t)l15 * 16 + (g & 1) * 8;
  bool act = (g < 2);

  float den0 = 0.f, den1 = 0.f;
#pragma unroll 2
  for (int o = 0; o < 102; ++o) {
    i64 a = 0, b0 = 0, b1 = 0;
    if (act) {
      a  = *(const i64*)(Ap + (size_t)o * 331776);
      b0 = *(const i64*)(B0p + (size_t)o * 512);
      b1 = *(const i64*)(B0p + (size_t)o * 512 + 256);
    }
    f32x4 d0 = {0.f, 0.f, 0.f, 0.f}, d1 = {0.f, 0.f, 0.f, 0.f};
    d0 = __builtin_amdgcn_mfma_f32_16x16x32_fp8_fp8(a, b0, d0, 0, 0, 0);
    d1 = __builtin_amdgcn_mfma_f32_16x16x32_fp8_fp8(a, b1, d1, 0, 0, 0);
    float p0 = d0[0] * u0.x + d0[1] * u0.y + d0[2] * u0.z + d0[3] * u0.w;
    float p1 = d1[0] * u1.x + d1[1] * u1.y + d1[2] * u1.z + d1[3] * u1.w;
    p0 += __shfl_xor(p0, 16);
    p1 += __shfl_xor(p1, 16);
    p0 *= 1.52587890625e-05f;  // / (64 * 1024)
    p1 *= 1.52587890625e-05f;
    float e0 = __expf(p0), e1 = __expf(p1);
    den0 += e0; den1 += e1;
    if ((g & 1) == 0) {
      int base = (o * 2 + wv) * 64 + (g >> 1) * 16 + l15;
      Eld[base] = __float2half(e0);
      Eld[base + 32] = __float2half(e1);
    }
  }
  float r0 = 1.0f / den0, r1 = 1.0f / den1;
  if ((g & 1) == 0) {
    for (int o = 0; o < 102; ++o) {
      int base = (o * 2 + wv) * 64 + (g >> 1) * 16 + l15;
      float c0 = __half2float(Eld[base]) * r0;
      float c1 = __half2float(Eld[base + 32]) * r1;
      __half* dst = cT + ((size_t)o * 2592 + n0 + (g >> 1)) * 32 + l15;
      dst[0] = __float2half(c0);
      dst[16] = __float2half(c1);
    }
  }
}

// ---------------- routing kernel B (fp8 MFMA): s = sum c*xhat ----------------
__device__ __forceinline__ i64 cu_pack8(float c, float4 a, float4 b) {
  union { unsigned u[2]; i64 v; } r;
  r.u[0] = fp8pair(c * a.x, c * a.y) | (fp8pair(c * a.z, c * a.w) << 16);
  r.u[1] = fp8pair(c * b.x, c * b.y) | (fp8pair(c * b.z, c * b.w) << 16);
  return r.v;
}

template <bool HASC>
__global__ __launch_bounds__(256) void k_B3(const unsigned char* __restrict__ Wq2,
                                            const float* __restrict__ u2,
                                            const __half* __restrict__ cT,
                                            float* __restrict__ s) {
  int o = blockIdx.x, kc = blockIdx.y;  // (102, 12)
  int t = threadIdx.x, lane = t & 63, wv = t >> 6;
  int l15 = lane & 15, h = lane >> 4;

  f32x4 acc0 = {0.f, 0.f, 0.f, 0.f}, acc1 = {0.f, 0.f, 0.f, 0.f};

#pragma unroll 1
  for (int st = wv; st < 54; st += 4) {
    int n = kc * 216 + st * 4 + h;
    i64 aq = *(const i64*)(Wq2 + (((size_t)o * 2592 + n) * 16 + l15) * 8);

    const float4* u0p = (const float4*)(u2 + ((size_t)l15 * 2592 + n) * 8);
    float4 u0a = u0p[0], u0b = u0p[1];
    const float4* u1p = (const float4*)(u2 + ((size_t)(l15 + 16) * 2592 + n) * 8);
    float4 u1a = u1p[0], u1b = u1p[1];

    float c0 = 16.0f, c1 = 16.0f;
    if (HASC) {
      const __half* cp = cT + ((size_t)o * 2592 + n) * 32;
      c0 = 16.0f * __half2float(cp[l15]);
      c1 = 16.0f * __half2float(cp[l15 + 16]);
    }
    i64 b0 = cu_pack8(c0, u0a, u0b);
    i64 b1 = cu_pack8(c1, u1a, u1b);

    acc0 = __builtin_amdgcn_mfma_f32_16x16x32_fp8_fp8(aq, b0, acc0, 0, 0, 0);
    acc1 = __builtin_amdgcn_mfma_f32_16x16x32_fp8_fp8(aq, b1, acc1, 0, 0, 0);
  }

#pragma unroll
  for (int r = 0; r < 4; ++r) {
    atomicAdd(s + ((size_t)l15 * 102 + o) * 16 + h * 4 + r, acc0[r]);
    atomicAdd(s + ((size_t)(l15 + 16) * 102 + o) * 16 + h * 4 + r, acc1[r]);
  }
}

// ---------------- squash v; optional fp8 vsum (x1024); optional S re-zero ----------------
__global__ void k_R(const float* __restrict__ s, float scale,
                    float* __restrict__ vout, const float* __restrict__ addin,
                    unsigned char* __restrict__ vsq, float* __restrict__ szero) {
  int t = blockIdx.x * 256 + threadIdx.x;
  if (t >= 3264) return;
  const float* sp = s + t * 16;
  float r[16];
  float sq = 0.f;
#pragma unroll
  for (int d = 0; d < 16; ++d) {
    r[d] = sp[d] * scale;
    sq += r[d] * r[d];
  }
  if (szero) {
#pragma unroll
    for (int d = 0; d < 16; ++d) szero[t * 16 + d] = 0.f;
  }
  float sc = (sq / (1.f + sq)) / sqrtf(sq + 1e-8f);
  float vv[16];
#pragma unroll
  for (int d = 0; d < 16; ++d) {
    vv[d] = r[d] * sc;
    vout[t * 16 + d] = vv[d];
  }
  if (vsq) {
    int b = t / 102, o = t - b * 102;
    float w[16];
#pragma unroll
    for (int d = 0; d < 16; ++d)
      w[d] = (addin ? (addin[t * 16 + d] + vv[d]) : vv[d]) * 1024.f;
    unsigned words[4];
#pragma unroll
    for (int q = 0; q < 4; ++q)
      words[q] = fp8pair(w[4 * q], w[4 * q + 1]) | (fp8pair(w[4 * q + 2], w[4 * q + 3]) << 16);
    *(uint4*)(vsq + ((size_t)o * 32 + b) * 16) =
        make_uint4(words[0], words[1], words[2], words[3]);
  }
}

// ---------------- fc chain ----------------
__global__ void k_fc1(const float* __restrict__ v2, const int* __restrict__ tgt,
                      const float* __restrict__ w1, const float* __restrict__ b1,
                      float* __restrict__ h1) {
  int j = blockIdx.x * 128 + threadIdx.x;
  int bq = blockIdx.y;
#pragma unroll
  for (int bi = 0; bi < 4; ++bi) {
    int b = bq * 4 + bi;
    int tb = tgt[b];
    float acc = b1[j];
    const float* vv = v2 + (b * 102 + tb) * 16;
    const float* wr = w1 + (tb * 16) * 512 + j;
#pragma unroll
    for (int d = 0; d < 16; ++d) acc += vv[d] * wr[d * 512];
    h1[b * 512 + j] = fmaxf(acc, 0.f);
  }
}

__global__ void k_fc2(const float* __restrict__ h1, const float* __restrict__ w2,
                      const float* __restrict__ b2, float* __restrict__ h2T) {
  int j = blockIdx.x * 128 + threadIdx.x;
  int bq = blockIdx.y;
  float acc[4];
#pragma unroll
  for (int bi = 0; bi < 4; ++bi) acc[bi] = b2[j];
  for (int k = 0; k < 512; ++k) {
    float wv = w2[k * 1024 + j];
#pragma unroll
    for (int bi = 0; bi < 4; ++bi) acc[bi] += h1[(bq * 4 + bi) * 512 + k] * wv;
  }
  float4 o;
  o.x = fmaxf(acc[0], 0.f); o.y = fmaxf(acc[1], 0.f);
  o.z = fmaxf(acc[2], 0.f); o.w = fmaxf(acc[3], 0.f);
  *(float4*)(h2T + j * 32 + bq * 4) = o;
}

__global__ void k_fc3a(const float* __restrict__ h2T, const float* __restrict__ w3,
                       float* __restrict__ p) {
  int j = blockIdx.x * 128 + threadIdx.x;
  int ky = blockIdx.y;
  float acc[32];
#pragma unroll
  for (int i = 0; i < 32; ++i) acc[i] = 0.f;
  int k0 = ky * 256;
  for (int k = k0; k < k0 + 256; ++k) {
    float wv = w3[(size_t)k * 37632 + j];
    const float4* hp = (const float4*)(h2T + k * 32);
#pragma unroll
    for (int q = 0; q < 8; ++q) {
      float4 h = hp[q];
      acc[q * 4 + 0] += h.x * wv; acc[q * 4 + 1] += h.y * wv;
      acc[q * 4 + 2] += h.z * wv; acc[q * 4 + 3] += h.w * wv;
    }
  }
#pragma unroll
  for (int i = 0; i < 32; ++i)
    p[((size_t)ky * 32 + i) * 37632 + j] = acc[i];
}

__global__ void k_fc3b(const float* __restrict__ p, const float* __restrict__ b3,
                       float* __restrict__ out) {
  int j = blockIdx.x * 256 + threadIdx.x;
  float bv = b3[j];
#pragma unroll 1
  for (int b = 0; b < 32; ++b) {
    float s = bv + p[(size_t)b * 37632 + j] + p[(size_t)(32 + b) * 37632 + j] +
              p[(size_t)(64 + b) * 37632 + j] + p[(size_t)(96 + b) * 37632 + j];
    out[52224 + (size_t)b * 37632 + j] = 1.0f / (1.0f + __expf(-s));
  }
}

// ---------------- host ----------------
extern "C" void kernel_launch(void* const* d_in, const int* in_sizes, int n_in,
                              void* d_out, int out_size, void* d_ws, size_t ws_size,
                              hipStream_t stream) {
  const float* x       = (const float*)d_in[0];
  const int*   targets = (const int*)d_in[1];
  const float* conv1_w = (const float*)d_in[2];
  const float* conv1_b = (const float*)d_in[3];
  const float* pc_w    = (const float*)d_in[4];
  const float* pc_b    = (const float*)d_in[5];
  const float* W       = (const float*)d_in[6];
  const float* fc1_w   = (const float*)d_in[7];
  const float* fc1_b   = (const float*)d_in[8];
  const float* fc2_w   = (const float*)d_in[9];
  const float* fc2_b   = (const float*)d_in[10];
  const float* fc3_w   = (const float*)d_in[11];
  const float* fc3_b   = (const float*)d_in[12];
  float* out = (float*)d_out;
  float* ws = (float*)d_ws;

  float* FEAT2 = ws + OFF_FEAT;
  unsigned short* C1WB = (unsigned short*)(ws + OFF_C1WT);
  unsigned char* PCWQ = (unsigned char*)(ws + OFF_PCWQ);
  __half* PCP = (__half*)(ws + OFF_PCP);
  float* U2   = ws + OFF_U2;
  unsigned char* WQ2 = (unsigned char*)(ws + OFF_WQ2);  // overlays FEAT2 after k_pc4
  unsigned char* WQ  = (unsigned char*)(ws + OFF_WQ);   // overlays PCP after k_rs
  __half* CT  = (__half*)(ws + OFF_CT);
  float* FC3P = ws + OFF_FC3P;
  float* S    = ws + OFF_S;
  float* V0   = ws + OFF_V0;
  float* V1   = ws + OFF_V1;
  unsigned char* VSQ = (unsigned char*)(ws + OFF_VSQ);
  float* H1   = ws + OFF_H1;
  float* H2T  = ws + OFF_H2T;

  // weight prep (conv phase)
  k_mkC1B<<<dim3(256), 128, 0, stream>>>(conv1_w, C1WB);
  k_mkBq<<<dim3(256), 256, 0, stream>>>(pc_w, PCWQ);

  // conv1 + relu (bf16 MFMA, co-split)
  k_c1m<<<dim3(1088, 2), 256, 0, stream>>>(x, C1WB, conv1_b, FEAT2);

  // primary caps conv (fp8 MFMA, 32-way K-split, fp16 partials) + fused reduce/squash
  k_pc4<<<dim3(41, 32), 256, 0, stream>>>(FEAT2, PCWQ, PCP);
  k_rs<<<dim3(32, 16), 256, 0, stream>>>(PCP, pc_b, U2);

  // routing pack: W read once -> two fp8 layouts (x64), coalesced
  k_mkW2<<<dim3(8262), 256, 0, stream>>>(W, WQ2, WQ);

  // ---- routing ---- (scales: W x64, cu x16 -> /1024; vq x1024 -> logits /65536)
  hipMemsetAsync(S, 0, 52224 * sizeof(float), stream);
  k_B3<false><<<dim3(102, 12), 256, 0, stream>>>(WQ2, U2, nullptr, S);
  k_R<<<dim3(13), 256, 0, stream>>>(S, 1.0f / (102.0f * 1024.0f), V0, nullptr, VSQ, S);

  k_A2<<<dim3(648), 128, 0, stream>>>(WQ, U2, VSQ, CT);
  k_B3<true><<<dim3(102, 12), 256, 0, stream>>>(WQ2, U2, CT, S);
  k_R<<<dim3(13), 256, 0, stream>>>(S, 1.0f / 1024.0f, V1, V0, VSQ, S);  // vsq = v0+v1

  k_A2<<<dim3(648), 128, 0, stream>>>(WQ, U2, VSQ, CT);
  k_B3<true><<<dim3(102, 12), 256, 0, stream>>>(WQ2, U2, CT, S);
  k_R<<<dim3(13), 256, 0, stream>>>(S, 1.0f / 1024.0f, out, nullptr, nullptr, nullptr);

  // ---- reconstruction ----
  k_fc1<<<dim3(4, 8), 128, 0, stream>>>(out, targets, fc1_w, fc1_b, H1);
  k_fc2<<<dim3(8, 8), 128, 0, stream>>>(H1, fc2_w, fc2_b, H2T);
  k_fc3a<<<dim3(294, 4), 128, 0, stream>>>(H2T, fc3_w, FC3P);
  k_fc3b<<<dim3(147), 256, 0, stream>>>(FC3P, fc3_b, out);
}

// Round 11
// 549.392 us; speedup vs baseline: 1.6152x; 1.1577x over previous
//
#include <hip/hip_runtime.h>
#include <hip/hip_fp16.h>
#include <math.h>

// ---------------- sizes ----------------
#define B32   32
#define OCLS  102
#define NCAPS 2592

// ---------------- ws map (floats) -- ws is 616 MB (154M floats); flat, no overlays ----
#define OFF_FEAT   0u               // feat2[b][h][co][w36]: 10,027,008
#define OFF_C1WT   10027008u        // bf16 conv1 pack: 49,152
#define OFF_PCWQ   10076160u        // fp8 pc pack: 1,703,936
#define OFF_PCP    11780096u        // fp16 partials 16 slices: 5,308,416
#define OFF_WQ2    17088512u        // fp8 W pack [o][n][d][i]: 8,466,944
#define OFF_WQ     25555456u        // fp8 W pack [o][n][i][d]: 8,466,944
#define OFF_U2     34022400u        // 663,552
#define OFF_CT     34685952u        // fp16 E[o][n][b]: 4,230,144
#define OFF_DEN    38916096u        // f32 den[n][b]: 82,944
#define OFF_S      38999040u        // 52,224
#define OFF_V0     39051264u
#define OFF_V1     39103488u
#define OFF_VSQ    39155712u        // fp8 vsum x1024
#define OFF_H1     39168768u
#define OFF_H2T    39185152u
#define OFF_FC3P   39217920u        // 4,816,896 -> end 44,034,816 (176MB < 616MB)

typedef __attribute__((ext_vector_type(8))) short short8;
typedef __attribute__((ext_vector_type(4))) float f32x4;
typedef long long i64;

__device__ __forceinline__ unsigned short f2b(float f) {
  union { float f; unsigned u; } v; v.f = f;
  unsigned r = v.u + 0x7fffu + ((v.u >> 16) & 1u);
  return (unsigned short)(r >> 16);
}

// float -> OCP e4m3fn (RNE, flush<2^-6, clamp) -- software fallback
__device__ __forceinline__ unsigned f2q_fast(float x) {
  union { float f; unsigned u; } v; v.f = x;
  unsigned s = (v.u >> 24) & 0x80u;
  unsigned au = v.u & 0x7fffffffu;
  if (au < 0x3c800000u) return s;
  if (au >= 0x43e00000u) return s | 0x7eu;
  unsigned r = au + 0x7ffffu + ((au >> 20) & 1u);
  unsigned e = (r >> 23) - 120u;
  unsigned m = (r >> 20) & 7u;
  return s | (e << 3) | m;
}

__device__ __forceinline__ unsigned fp8pair(float a, float b) {
#if __has_builtin(__builtin_amdgcn_cvt_pk_fp8_f32)
  return (unsigned)__builtin_amdgcn_cvt_pk_fp8_f32(a, b, 0, false) & 0xffffu;
#else
  return f2q_fast(a) | (f2q_fast(b) << 8);
#endif
}

__device__ __forceinline__ float rcpf(float x) {
#if __has_builtin(__builtin_amdgcn_rcpf)
  return __builtin_amdgcn_rcpf(x);
#else
  return 1.0f / x;
#endif
}

// ---------------- merged weight-pack kernel ----------------
// blocks [0,256): conv1_w -> bf16 C1WB[ci][co][128]
// blocks [256,512): pc_w -> fp8 x64 PCWQ[ci][co][104]
// blocks [512,8774): W -> fp8 x64 Wq2[on][d][i] + Wq[on][i][d] (coalesced + LDS transpose)
__global__ __launch_bounds__(256) void k_pack(const float* __restrict__ conv1_w,
                                              const float* __restrict__ pc_w,
                                              const float* __restrict__ W,
                                              unsigned short* __restrict__ C1WB,
                                              unsigned char* __restrict__ PCWQ,
                                              unsigned char* __restrict__ Wq2,
                                              unsigned char* __restrict__ Wq) {
  __shared__ unsigned char sq[32 * 128];
  int bb = blockIdx.x;
  int t = threadIdx.x;
  if (bb < 256) {
    if (t < 128) {
#pragma unroll
      for (int ci = 0; ci < 3; ++ci) {
        float v = (t < 121) ? conv1_w[bb * 363 + ci * 121 + t] : 0.f;
        C1WB[(ci * 256 + bb) * 128 + t] = f2b(v);
      }
    }
  } else if (bb < 512) {
    int co = bb - 256;
    for (int e = t; e < 20736; e += 256) {
      int ci = e / 81, tap = e - ci * 81;
      PCWQ[(size_t)ci * 26624 + co * 104 + tap] =
          (unsigned char)f2q_fast(pc_w[(size_t)co * 20736 + e] * 64.f);
    }
    for (int tap = 81; tap < 104; ++tap)
      PCWQ[(size_t)t * 26624 + co * 104 + tap] = 0;
  } else {
    size_t base = (size_t)(bb - 512) * 4096;  // floats / bytes
    const float4* src = (const float4*)(W + base + (size_t)t * 16);
    float4 f0 = src[0], f1 = src[1], f2 = src[2], f3 = src[3];
    float v[16] = {f0.x, f0.y, f0.z, f0.w, f1.x, f1.y, f1.z, f1.w,
                   f2.x, f2.y, f2.z, f2.w, f3.x, f3.y, f3.z, f3.w};
    unsigned words[4];
#pragma unroll
    for (int j = 0; j < 4; ++j)
      words[j] = fp8pair(v[4 * j] * 64.f, v[4 * j + 1] * 64.f) |
                 (fp8pair(v[4 * j + 2] * 64.f, v[4 * j + 3] * 64.f) << 16);
    *(uint4*)(Wq2 + base + (size_t)t * 16) =
        make_uint4(words[0], words[1], words[2], words[3]);
    int r = t >> 3, seg = t & 7;
#pragma unroll
    for (int e = 0; e < 16; ++e) {
      unsigned byte = (words[e >> 2] >> ((e & 3) * 8)) & 0xffu;
      int idx = seg * 16 + e, d = idx >> 3, i = idx & 7;
      sq[r * 128 + i * 16 + d] = (unsigned char)byte;
    }
    __syncthreads();
    *(uint4*)(Wq + base + (size_t)t * 16) = ((const uint4*)sq)[t];
  }
}

// ---------------- conv1 via bf16 MFMA, co-split x2 ----------------
__global__ __launch_bounds__(256) void k_c1m(const float* __restrict__ x,
                                             const unsigned short* __restrict__ C1WB,
                                             const float* __restrict__ bias,
                                             float* __restrict__ feat2) {
  __shared__ unsigned short sh[48 * 128 + 128 * 128];
  unsigned short* lA = sh;
  unsigned short* lB = sh + 48 * 128;
  float* obuf = (float*)(sh + 48 * 128);

  int bx = blockIdx.x;
  int hf = blockIdx.y;  // co half
  int b = bx / 34, ho = bx % 34;
  int t = threadIdx.x;
  int lane = t & 63, wv = t >> 6;
  int l15 = lane & 15, lh = lane >> 4;
  int rx = l15 & 7;

  {
    uint4 zz = make_uint4(0, 0, 0, 0);
    uint4* z = (uint4*)lA;
    for (int i = t; i < 48 * 128 / 8; i += 256) z[i] = zz;
  }
  __syncthreads();

  f32x4 acc[3][2];
#pragma unroll
  for (int mf = 0; mf < 3; ++mf)
#pragma unroll
    for (int nf = 0; nf < 2; ++nf) acc[mf][nf] = (f32x4){0.f, 0.f, 0.f, 0.f};

#pragma unroll 1
  for (int ci = 0; ci < 3; ++ci) {
    {
      const uint4* Bsrc = (const uint4*)(C1WB + ci * 32768 + hf * 16384);
#pragma unroll
      for (int i = 0; i < 8; ++i) {
        int f = i * 256 + t;
        int row = f >> 4, cu = f & 15;
        ((uint4*)lB)[row * 16 + (cu ^ (row & 7))] = Bsrc[f];
      }
    }
    for (int tk = t; tk < 374; tk += 256) {
      int kh = tk / 34, wo = tk - kh * 34;
      const float* src = x + ((size_t)(b * 3 + ci) * 112 + ho * 3 + kh) * 112 + wo * 3;
#pragma unroll
      for (int j = 0; j < 11; ++j) {
        int tap = kh * 11 + j;
        int cu = tap >> 3;
        lA[wo * 128 + (((cu ^ (wo & 7)) << 3) | (tap & 7))] = f2b(src[j]);
      }
    }
    __syncthreads();

#pragma unroll
    for (int s = 0; s < 4; ++s) {
      int cub = ((s * 4 + lh) ^ rx) << 3;
      short8 a0 = *(const short8*)(lA + (0 + l15) * 128 + cub);
      short8 a1 = *(const short8*)(lA + (16 + l15) * 128 + cub);
      short8 a2 = *(const short8*)(lA + (32 + l15) * 128 + cub);
      short8 b0 = *(const short8*)(lB + (wv * 32 + 0 + l15) * 128 + cub);
      short8 b1 = *(const short8*)(lB + (wv * 32 + 16 + l15) * 128 + cub);
      acc[0][0] = __builtin_amdgcn_mfma_f32_16x16x32_bf16(a0, b0, acc[0][0], 0, 0, 0);
      acc[0][1] = __builtin_amdgcn_mfma_f32_16x16x32_bf16(a0, b1, acc[0][1], 0, 0, 0);
      acc[1][0] = __builtin_amdgcn_mfma_f32_16x16x32_bf16(a1, b0, acc[1][0], 0, 0, 0);
      acc[1][1] = __builtin_amdgcn_mfma_f32_16x16x32_bf16(a1, b1, acc[1][1], 0, 0, 0);
      acc[2][0] = __builtin_amdgcn_mfma_f32_16x16x32_bf16(a2, b0, acc[2][0], 0, 0, 0);
      acc[2][1] = __builtin_amdgcn_mfma_f32_16x16x32_bf16(a2, b1, acc[2][1], 0, 0, 0);
    }
    __syncthreads();
  }

  float bv[2];
#pragma unroll
  for (int nf = 0; nf < 2; ++nf) bv[nf] = bias[hf * 128 + wv * 32 + nf * 16 + l15];
#pragma unroll
  for (int mf = 0; mf < 3; ++mf)
#pragma unroll
    for (int nf = 0; nf < 2; ++nf)
#pragma unroll
      for (int r = 0; r < 4; ++r) {
        int wo = mf * 16 + lh * 4 + r;
        if (wo < 36)
          obuf[(wv * 32 + nf * 16 + l15) * 36 + wo] = fmaxf(acc[mf][nf][r] + bv[nf], 0.f);
      }
  __syncthreads();
  float4* dst = (float4*)(feat2 + (size_t)bx * 9216 + hf * 4608);
  const float4* srcb = (const float4*)obuf;
  for (int i = t; i < 1152; i += 256) dst[i] = srcb[i];
}

// ---------------- pc conv gather (fp8, HW cvt pairs) ----------------
__device__ __forceinline__ void pc_gather8(const float* __restrict__ feat2,
                                           unsigned char* __restrict__ dstbuf,
                                           int mb, int ci, int t) {
  for (int task = t; task < 576; task += 256) {
    int m = task / 9, kh = task - m * 9;
    int gm = mb * 64 + m;
    if (gm < 2592) {
      int b = gm / 81, p = gm - b * 81;
      int ho = p / 9, wo = p - ho * 9;
      const float* src = feat2 + ((size_t)(b * 34 + ho * 3 + kh) * 256 + ci) * 36 + wo * 3;
      unsigned char* dst = dstbuf + m * 104 + kh * 9;
      unsigned p01 = fp8pair(src[0], src[1]);
      unsigned p23 = fp8pair(src[2], src[3]);
      unsigned p45 = fp8pair(src[4], src[5]);
      unsigned p67 = fp8pair(src[6], src[7]);
      unsigned p8  = fp8pair(src[8], 0.f);
      dst[0] = p01; dst[1] = p01 >> 8;
      dst[2] = p23; dst[3] = p23 >> 8;
      dst[4] = p45; dst[5] = p45 >> 8;
      dst[6] = p67; dst[7] = p67 >> 8;
      dst[8] = p8;
    }
  }
}

// ---------------- primary caps conv: fp8 MFMA, kc=16, fp16 partials ----------------
__global__ __launch_bounds__(256, 3) void k_pc4(const float* __restrict__ feat2,
                                                const unsigned char* __restrict__ PCWQ,
                                                __half* __restrict__ pcp) {
  __shared__ unsigned char lA[2][64 * 104];

  int mb = blockIdx.x, kc = blockIdx.y;  // (41, 16)
  int t = threadIdx.x;
  int lane = t & 63, wv = t >> 6;
  int l15 = lane & 15, lh = lane >> 4;

  {
    uint4 zz = make_uint4(0, 0, 0, 0);
    uint4* z = (uint4*)lA;
    for (int i = t; i < 2 * 64 * 104 / 16; i += 256) z[i] = zz;
  }
  __syncthreads();
  pc_gather8(feat2, lA[0], mb, kc * 16, t);
  __syncthreads();

  f32x4 acc[4][4];
#pragma unroll
  for (int mf = 0; mf < 4; ++mf)
#pragma unroll
    for (int nf = 0; nf < 4; ++nf) acc[mf][nf] = (f32x4){0.f, 0.f, 0.f, 0.f};

#pragma unroll 1
  for (int cil = 0; cil < 16; ++cil) {
    int ci = kc * 16 + cil;
    int cur = cil & 1;

    i64 bfr[4][3];
    const unsigned char* Bbase = PCWQ + (size_t)ci * 26624 + (wv * 64 + l15) * 104 + lh * 8;
#pragma unroll
    for (int nf = 0; nf < 4; ++nf)
#pragma unroll
      for (int s = 0; s < 3; ++s)
        bfr[nf][s] = *(const i64*)(Bbase + nf * 16 * 104 + s * 32);

    if (cil < 15) pc_gather8(feat2, lA[cur ^ 1], mb, ci + 1, t);

    const unsigned char* arow = lA[cur] + l15 * 104 + lh * 8;
#pragma unroll
    for (int s = 0; s < 3; ++s) {
      i64 a0 = *(const i64*)(arow + s * 32);
      i64 a1 = *(const i64*)(arow + 16 * 104 + s * 32);
      i64 a2 = *(const i64*)(arow + 32 * 104 + s * 32);
      i64 a3 = *(const i64*)(arow + 48 * 104 + s * 32);
      acc[0][0] = __builtin_amdgcn_mfma_f32_16x16x32_fp8_fp8(a0, bfr[0][s], acc[0][0], 0, 0, 0);
      acc[0][1] = __builtin_amdgcn_mfma_f32_16x16x32_fp8_fp8(a0, bfr[1][s], acc[0][1], 0, 0, 0);
      acc[0][2] = __builtin_amdgcn_mfma_f32_16x16x32_fp8_fp8(a0, bfr[2][s], acc[0][2], 0, 0, 0);
      acc[0][3] = __builtin_amdgcn_mfma_f32_16x16x32_fp8_fp8(a0, bfr[3][s], acc[0][3], 0, 0, 0);
      acc[1][0] = __builtin_amdgcn_mfma_f32_16x16x32_fp8_fp8(a1, bfr[0][s], acc[1][0], 0, 0, 0);
      acc[1][1] = __builtin_amdgcn_mfma_f32_16x16x32_fp8_fp8(a1, bfr[1][s], acc[1][1], 0, 0, 0);
      acc[1][2] = __builtin_amdgcn_mfma_f32_16x16x32_fp8_fp8(a1, bfr[2][s], acc[1][2], 0, 0, 0);
      acc[1][3] = __builtin_amdgcn_mfma_f32_16x16x32_fp8_fp8(a1, bfr[3][s], acc[1][3], 0, 0, 0);
      acc[2][0] = __builtin_amdgcn_mfma_f32_16x16x32_fp8_fp8(a2, bfr[0][s], acc[2][0], 0, 0, 0);
      acc[2][1] = __builtin_amdgcn_mfma_f32_16x16x32_fp8_fp8(a2, bfr[1][s], acc[2][1], 0, 0, 0);
      acc[2][2] = __builtin_amdgcn_mfma_f32_16x16x32_fp8_fp8(a2, bfr[2][s], acc[2][2], 0, 0, 0);
      acc[2][3] = __builtin_amdgcn_mfma_f32_16x16x32_fp8_fp8(a2, bfr[3][s], acc[2][3], 0, 0, 0);
      acc[3][0] = __builtin_amdgcn_mfma_f32_16x16x32_fp8_fp8(a3, bfr[0][s], acc[3][0], 0, 0, 0);
      acc[3][1] = __builtin_amdgcn_mfma_f32_16x16x32_fp8_fp8(a3, bfr[1][s], acc[3][1], 0, 0, 0);
      acc[3][2] = __builtin_amdgcn_mfma_f32_16x16x32_fp8_fp8(a3, bfr[2][s], acc[3][2], 0, 0, 0);
      acc[3][3] = __builtin_amdgcn_mfma_f32_16x16x32_fp8_fp8(a3, bfr[3][s], acc[3][3], 0, 0, 0);
    }
    __syncthreads();
  }

#pragma unroll
  for (int mf = 0; mf < 4; ++mf) {
    int gm = mb * 64 + mf * 16 + lh * 4;
    if (gm < 2592) {
      __half* dst = pcp + (size_t)kc * 663552 + (size_t)gm * 256 + wv * 64 + l15;
#pragma unroll
      for (int nf = 0; nf < 4; ++nf)
#pragma unroll
        for (int r = 0; r < 4; ++r)
          dst[(size_t)r * 256 + nf * 16] = __float2half(acc[mf][nf][r]);
    }
  }
}

// ---------------- fused transpose-reduce-squash: pcp(16 fp16 slices) -> u2 ----------------
__global__ __launch_bounds__(256) void k_rs(const __half* __restrict__ pcp,
                                            const float* __restrict__ pcb,
                                            float* __restrict__ u2) {
  __shared__ float tile[81 * 17];
  int b = blockIdx.x;    // 32
  int cog = blockIdx.y;  // 16
  int c0 = cog * 16;
  int t = threadIdx.x;

  for (int e = t; e < 1296; e += 256) {
    int p = e >> 4, col = e & 15;
    const __half* base = pcp + (size_t)(b * 81 + p) * 256 + c0 + col;
    float s = 0.f;
#pragma unroll
    for (int c = 0; c < 16; ++c) s += __half2float(base[(size_t)c * 663552]);
    tile[p * 17 + col] = pcb[c0 + col] + s * 0.015625f;  // /64 (W x64)
  }
  __syncthreads();

  if (t < 162) {
    float v[8];
    float sq = 0.f;
#pragma unroll
    for (int i = 0; i < 8; ++i) {
      int g = t * 8 + i;
      int col = g / 81, p = g - col * 81;
      v[i] = tile[p * 17 + col];
      sq += v[i] * v[i];
    }
    float sc = (sq / (1.f + sq)) / sqrtf(sq + 1e-8f);
    int n = cog * 162 + t;
    float4* dst = (float4*)(u2 + ((size_t)b * 2592 + n) * 8);
    dst[0] = make_float4(v[0] * sc, v[1] * sc, v[2] * sc, v[3] * sc);
    dst[1] = make_float4(v[4] * sc, v[5] * sc, v[6] * sc, v[7] * sc);
  }
}

// ---------------- routing kernel A3 (fp8 MFMA, o-split x3): E + partial den ----------------
// grid (648, 3): block owns 4 n's x 34 o's. Writes UNNORMALIZED E to cT and
// atomic-adds its denominator partial into den[n][b] (zeroed by preceding k_R).
__global__ __launch_bounds__(128) void k_A3(const unsigned char* __restrict__ Wq,
                                            const float* __restrict__ u2,
                                            const unsigned char* __restrict__ vq,
                                            __half* __restrict__ cT,
                                            float* __restrict__ den) {
  int nb = blockIdx.x;   // 648
  int ch = blockIdx.y;   // 3
  int o0 = ch * 34;
  int t = threadIdx.x, wv = t >> 6, lane = t & 63;
  int l15 = lane & 15, g = lane >> 4;
  int n0 = nb * 4 + 2 * wv;
  int nl = g >> 1, ih = (g & 1) * 4;

  float4 u0 = *(const float4*)(u2 + (((size_t)l15 * 2592 + n0 + nl) * 8 + ih));
  float4 u1 = *(const float4*)(u2 + (((size_t)(l15 + 16) * 2592 + n0 + nl) * 8 + ih));

  int nlA = l15 >> 3, iA = l15 & 7;
  const unsigned char* Ap = Wq + (((size_t)(n0 + nlA)) * 8 + iA) * 16 + (g & 1) * 8 +
                            (size_t)o0 * 331776;
  const unsigned char* B0p = vq + (size_t)l15 * 16 + (g & 1) * 8 + (size_t)o0 * 512;
  bool act = (g < 2);

  float den0 = 0.f, den1 = 0.f;
#pragma unroll 2
  for (int oo = 0; oo < 34; ++oo) {
    i64 a = 0, b0 = 0, b1 = 0;
    if (act) {
      a  = *(const i64*)(Ap + (size_t)oo * 331776);
      b0 = *(const i64*)(B0p + (size_t)oo * 512);
      b1 = *(const i64*)(B0p + (size_t)oo * 512 + 256);
    }
    f32x4 d0 = {0.f, 0.f, 0.f, 0.f}, d1 = {0.f, 0.f, 0.f, 0.f};
    d0 = __builtin_amdgcn_mfma_f32_16x16x32_fp8_fp8(a, b0, d0, 0, 0, 0);
    d1 = __builtin_amdgcn_mfma_f32_16x16x32_fp8_fp8(a, b1, d1, 0, 0, 0);
    float p0 = d0[0] * u0.x + d0[1] * u0.y + d0[2] * u0.z + d0[3] * u0.w;
    float p1 = d1[0] * u1.x + d1[1] * u1.y + d1[2] * u1.z + d1[3] * u1.w;
    p0 += __shfl_xor(p0, 16);
    p1 += __shfl_xor(p1, 16);
    p0 *= 1.52587890625e-05f;  // / (64 * 1024)
    p1 *= 1.52587890625e-05f;
    float e0 = __expf(p0), e1 = __expf(p1);
    den0 += e0; den1 += e1;
    if ((g & 1) == 0) {
      __half* dst = cT + ((size_t)(o0 + oo) * 2592 + n0 + nl) * 32 + l15;
      dst[0]  = __float2half(e0);
      dst[16] = __float2half(e1);
    }
  }
  if ((g & 1) == 0) {
    atomicAdd(den + (n0 + nl) * 32 + l15, den0);
    atomicAdd(den + (n0 + nl) * 32 + l15 + 16, den1);
  }
}

// ---------------- routing kernel B (fp8 MFMA): s = sum (E/den)*xhat ----------------
__device__ __forceinline__ i64 cu_pack8(float c, float4 a, float4 b) {
  union { unsigned u[2]; i64 v; } r;
  r.u[0] = fp8pair(c * a.x, c * a.y) | (fp8pair(c * a.z, c * a.w) << 16);
  r.u[1] = fp8pair(c * b.x, c * b.y) | (fp8pair(c * b.z, c * b.w) << 16);
  return r.v;
}

template <bool HASC>
__global__ __launch_bounds__(256) void k_B3(const unsigned char* __restrict__ Wq2,
                                            const float* __restrict__ u2,
                                            const __half* __restrict__ cT,
                                            const float* __restrict__ den,
                                            float* __restrict__ s) {
  int o = blockIdx.x, kc = blockIdx.y;  // (102, 12)
  int t = threadIdx.x, lane = t & 63, wv = t >> 6;
  int l15 = lane & 15, h = lane >> 4;

  f32x4 acc0 = {0.f, 0.f, 0.f, 0.f}, acc1 = {0.f, 0.f, 0.f, 0.f};

#pragma unroll 1
  for (int st = wv; st < 54; st += 4) {
    int n = kc * 216 + st * 4 + h;
    i64 aq = *(const i64*)(Wq2 + (((size_t)o * 2592 + n) * 16 + l15) * 8);

    const float4* u0p = (const float4*)(u2 + ((size_t)l15 * 2592 + n) * 8);
    float4 u0a = u0p[0], u0b = u0p[1];
    const float4* u1p = (const float4*)(u2 + ((size_t)(l15 + 16) * 2592 + n) * 8);
    float4 u1a = u1p[0], u1b = u1p[1];

    float c0 = 16.0f, c1 = 16.0f;
    if (HASC) {
      const __half* cp = cT + ((size_t)o * 2592 + n) * 32;
      float i0 = rcpf(den[n * 32 + l15]);
      float i1 = rcpf(den[n * 32 + l15 + 16]);
      c0 = 16.0f * __half2float(cp[l15]) * i0;
      c1 = 16.0f * __half2float(cp[l15 + 16]) * i1;
    }
    i64 b0 = cu_pack8(c0, u0a, u0b);
    i64 b1 = cu_pack8(c1, u1a, u1b);

    acc0 = __builtin_amdgcn_mfma_f32_16x16x32_fp8_fp8(aq, b0, acc0, 0, 0, 0);
    acc1 = __builtin_amdgcn_mfma_f32_16x16x32_fp8_fp8(aq, b1, acc1, 0, 0, 0);
  }

#pragma unroll
  for (int r = 0; r < 4; ++r) {
    atomicAdd(s + ((size_t)l15 * 102 + o) * 16 + h * 4 + r, acc0[r]);
    atomicAdd(s + ((size_t)(l15 + 16) * 102 + o) * 16 + h * 4 + r, acc1[r]);
  }
}

// ---------------- squash v; optional fp8 vsum; optional S re-zero + den zero ----------------
__global__ void k_R(const float* __restrict__ s, float scale,
                    float* __restrict__ vout, const float* __restrict__ addin,
                    unsigned char* __restrict__ vsq, float* __restrict__ szero,
                    float* __restrict__ dzero) {
  int t = blockIdx.x * 256 + threadIdx.x;  // grid 13*256 = 3328
  if (dzero) {
    for (int i = t; i < 82944; i += 3328) dzero[i] = 0.f;
  }
  if (t >= 3264) return;
  const float* sp = s + t * 16;
  float r[16];
  float sq = 0.f;
#pragma unroll
  for (int d = 0; d < 16; ++d) {
    r[d] = sp[d] * scale;
    sq += r[d] * r[d];
  }
  if (szero) {
#pragma unroll
    for (int d = 0; d < 16; ++d) szero[t * 16 + d] = 0.f;
  }
  float sc = (sq / (1.f + sq)) / sqrtf(sq + 1e-8f);
  float vv[16];
#pragma unroll
  for (int d = 0; d < 16; ++d) {
    vv[d] = r[d] * sc;
    vout[t * 16 + d] = vv[d];
  }
  if (vsq) {
    int b = t / 102, o = t - b * 102;
    float w[16];
#pragma unroll
    for (int d = 0; d < 16; ++d)
      w[d] = (addin ? (addin[t * 16 + d] + vv[d]) : vv[d]) * 1024.f;
    unsigned words[4];
#pragma unroll
    for (int q = 0; q < 4; ++q)
      words[q] = fp8pair(w[4 * q], w[4 * q + 1]) | (fp8pair(w[4 * q + 2], w[4 * q + 3]) << 16);
    *(uint4*)(vsq + ((size_t)o * 32 + b) * 16) =
        make_uint4(words[0], words[1], words[2], words[3]);
  }
}

// ---------------- fc chain ----------------
__global__ void k_fc1(const float* __restrict__ v2, const int* __restrict__ tgt,
                      const float* __restrict__ w1, const float* __restrict__ b1,
                      float* __restrict__ h1) {
  int j = blockIdx.x * 128 + threadIdx.x;
  int bq = blockIdx.y;
#pragma unroll
  for (int bi = 0; bi < 4; ++bi) {
    int b = bq * 4 + bi;
    int tb = tgt[b];
    float acc = b1[j];
    const float* vv = v2 + (b * 102 + tb) * 16;
    const float* wr = w1 + (tb * 16) * 512 + j;
#pragma unroll
    for (int d = 0; d < 16; ++d) acc += vv[d] * wr[d * 512];
    h1[b * 512 + j] = fmaxf(acc, 0.f);
  }
}

__global__ void k_fc2(const float* __restrict__ h1, const float* __restrict__ w2,
                      const float* __restrict__ b2, float* __restrict__ h2T) {
  int j = blockIdx.x * 128 + threadIdx.x;
  int bq = blockIdx.y;
  float acc[4];
#pragma unroll
  for (int bi = 0; bi < 4; ++bi) acc[bi] = b2[j];
  for (int k = 0; k < 512; ++k) {
    float wv = w2[k * 1024 + j];
#pragma unroll
    for (int bi = 0; bi < 4; ++bi) acc[bi] += h1[(bq * 4 + bi) * 512 + k] * wv;
  }
  float4 o;
  o.x = fmaxf(acc[0], 0.f); o.y = fmaxf(acc[1], 0.f);
  o.z = fmaxf(acc[2], 0.f); o.w = fmaxf(acc[3], 0.f);
  *(float4*)(h2T + j * 32 + bq * 4) = o;
}

__global__ void k_fc3a(const float* __restrict__ h2T, const float* __restrict__ w3,
                       float* __restrict__ p) {
  int j = blockIdx.x * 128 + threadIdx.x;
  int ky = blockIdx.y;
  float acc[32];
#pragma unroll
  for (int i = 0; i < 32; ++i) acc[i] = 0.f;
  int k0 = ky * 256;
  for (int k = k0; k < k0 + 256; ++k) {
    float wv = w3[(size_t)k * 37632 + j];
    const float4* hp = (const float4*)(h2T + k * 32);
#pragma unroll
    for (int q = 0; q < 8; ++q) {
      float4 h = hp[q];
      acc[q * 4 + 0] += h.x * wv; acc[q * 4 + 1] += h.y * wv;
      acc[q * 4 + 2] += h.z * wv; acc[q * 4 + 3] += h.w * wv;
    }
  }
#pragma unroll
  for (int i = 0; i < 32; ++i)
    p[((size_t)ky * 32 + i) * 37632 + j] = acc[i];
}

__global__ void k_fc3b(const float* __restrict__ p, const float* __restrict__ b3,
                       float* __restrict__ out) {
  int j = blockIdx.x * 256 + threadIdx.x;
  float bv = b3[j];
#pragma unroll 1
  for (int b = 0; b < 32; ++b) {
    float s = bv + p[(size_t)b * 37632 + j] + p[(size_t)(32 + b) * 37632 + j] +
              p[(size_t)(64 + b) * 37632 + j] + p[(size_t)(96 + b) * 37632 + j];
    out[52224 + (size_t)b * 37632 + j] = 1.0f / (1.0f + __expf(-s));
  }
}

// ---------------- host ----------------
extern "C" void kernel_launch(void* const* d_in, const int* in_sizes, int n_in,
                              void* d_out, int out_size, void* d_ws, size_t ws_size,
                              hipStream_t stream) {
  const float* x       = (const float*)d_in[0];
  const int*   targets = (const int*)d_in[1];
  const float* conv1_w = (const float*)d_in[2];
  const float* conv1_b = (const float*)d_in[3];
  const float* pc_w    = (const float*)d_in[4];
  const float* pc_b    = (const float*)d_in[5];
  const float* W       = (const float*)d_in[6];
  const float* fc1_w   = (const float*)d_in[7];
  const float* fc1_b   = (const float*)d_in[8];
  const float* fc2_w   = (const float*)d_in[9];
  const float* fc2_b   = (const float*)d_in[10];
  const float* fc3_w   = (const float*)d_in[11];
  const float* fc3_b   = (const float*)d_in[12];
  float* out = (float*)d_out;
  float* ws = (float*)d_ws;

  float* FEAT2 = ws + OFF_FEAT;
  unsigned short* C1WB = (unsigned short*)(ws + OFF_C1WT);
  unsigned char* PCWQ = (unsigned char*)(ws + OFF_PCWQ);
  __half* PCP = (__half*)(ws + OFF_PCP);
  unsigned char* WQ2 = (unsigned char*)(ws + OFF_WQ2);
  unsigned char* WQ  = (unsigned char*)(ws + OFF_WQ);
  float* U2   = ws + OFF_U2;
  __half* CT  = (__half*)(ws + OFF_CT);
  float* DEN  = ws + OFF_DEN;
  float* S    = ws + OFF_S;
  float* V0   = ws + OFF_V0;
  float* V1   = ws + OFF_V1;
  unsigned char* VSQ = (unsigned char*)(ws + OFF_VSQ);
  float* H1   = ws + OFF_H1;
  float* H2T  = ws + OFF_H2T;
  float* FC3P = ws + OFF_FC3P;

  // all weight packs in one launch
  k_pack<<<dim3(8774), 256, 0, stream>>>(conv1_w, pc_w, W, C1WB, PCWQ, WQ2, WQ);

  // conv1 + relu (bf16 MFMA, co-split)
  k_c1m<<<dim3(1088, 2), 256, 0, stream>>>(x, C1WB, conv1_b, FEAT2);

  // primary caps conv (fp8 MFMA, 16-way K-split, fp16 partials) + fused reduce/squash
  k_pc4<<<dim3(41, 16), 256, 0, stream>>>(FEAT2, PCWQ, PCP);
  k_rs<<<dim3(32, 16), 256, 0, stream>>>(PCP, pc_b, U2);

  // ---- routing ---- (scales: W x64, cu x16 -> /1024; vq x1024 -> logits /65536)
  hipMemsetAsync(S, 0, 52224 * sizeof(float), stream);
  k_B3<false><<<dim3(102, 12), 256, 0, stream>>>(WQ2, U2, nullptr, nullptr, S);
  k_R<<<dim3(13), 256, 0, stream>>>(S, 1.0f / (102.0f * 1024.0f), V0, nullptr, VSQ, S, DEN);

  k_A3<<<dim3(648, 3), 128, 0, stream>>>(WQ, U2, VSQ, CT, DEN);
  k_B3<true><<<dim3(102, 12), 256, 0, stream>>>(WQ2, U2, CT, DEN, S);
  k_R<<<dim3(13), 256, 0, stream>>>(S, 1.0f / 1024.0f, V1, V0, VSQ, S, DEN);  // vsq = v0+v1

  k_A3<<<dim3(648, 3), 128, 0, stream>>>(WQ, U2, VSQ, CT, DEN);
  k_B3<true><<<dim3(102, 12), 256, 0, stream>>>(WQ2, U2, CT, DEN, S);
  k_R<<<dim3(13), 256, 0, stream>>>(S, 1.0f / 1024.0f, out, nullptr, nullptr, nullptr, nullptr);

  // ---- reconstruction ----
  k_fc1<<<dim3(4, 8), 128, 0, stream>>>(out, targets, fc1_w, fc1_b, H1);
  k_fc2<<<dim3(8, 8), 128, 0, stream>>>(H1, fc2_w, fc2_b, H2T);
  k_fc3a<<<dim3(294, 4), 128, 0, stream>>>(H2T, fc3_w, FC3P);
  k_fc3b<<<dim3(147), 256, 0, stream>>>(FC3P, fc3_b, out);
}

// Round 12
// 545.364 us; speedup vs baseline: 1.6271x; 1.0074x over previous
//
#include <hip/hip_runtime.h>
#include <hip/hip_fp16.h>
#include <math.h>

// ---------------- sizes ----------------
#define B32   32
#define OCLS  102
#define NCAPS 2592

// ---------------- ws map (floats) -- ws is 616 MB; flat, no overlays ----
#define OFF_FEAT   0u               // feat2[b][h][co][w36]: 10,027,008
#define OFF_C1WT   10027008u        // bf16 conv1 pack: 49,152
#define OFF_PCWQ   10076160u        // fp8 pc pack: 1,703,936
#define OFF_PCP    11780096u        // fp16 partials 16 slices: 5,308,416
#define OFF_WQ2    17088512u        // fp8 W pack [o][n][d][i]: 8,466,944
#define OFF_WQ     25555456u        // fp8 W pack [o][n][i][d]: 8,466,944
#define OFF_U2     34022400u        // 663,552
#define OFF_CT     34685952u        // fp16 E[o][n][b]: 4,230,144
#define OFF_DEN    38916096u        // f32 den[n][b]: 82,944
#define OFF_S      38999040u        // 52,224
#define OFF_V0     39051264u
#define OFF_V1     39103488u
#define OFF_VSQ    39155712u        // fp8 vsum x1024
#define OFF_H2T    39185152u
#define OFF_FC3P   39217920u        // 4,816,896 -> end 44,034,816 (176MB < 616MB)

typedef __attribute__((ext_vector_type(8))) short short8;
typedef __attribute__((ext_vector_type(4))) float f32x4;
typedef long long i64;

__device__ __forceinline__ unsigned short f2b(float f) {
  union { float f; unsigned u; } v; v.f = f;
  unsigned r = v.u + 0x7fffu + ((v.u >> 16) & 1u);
  return (unsigned short)(r >> 16);
}

// float -> OCP e4m3fn (RNE, flush<2^-6, clamp) -- software fallback
__device__ __forceinline__ unsigned f2q_fast(float x) {
  union { float f; unsigned u; } v; v.f = x;
  unsigned s = (v.u >> 24) & 0x80u;
  unsigned au = v.u & 0x7fffffffu;
  if (au < 0x3c800000u) return s;
  if (au >= 0x43e00000u) return s | 0x7eu;
  unsigned r = au + 0x7ffffu + ((au >> 20) & 1u);
  unsigned e = (r >> 23) - 120u;
  unsigned m = (r >> 20) & 7u;
  return s | (e << 3) | m;
}

__device__ __forceinline__ unsigned fp8pair(float a, float b) {
#if __has_builtin(__builtin_amdgcn_cvt_pk_fp8_f32)
  return (unsigned)__builtin_amdgcn_cvt_pk_fp8_f32(a, b, 0, false) & 0xffffu;
#else
  return f2q_fast(a) | (f2q_fast(b) << 8);
#endif
}

__device__ __forceinline__ float rcpf(float x) {
#if __has_builtin(__builtin_amdgcn_rcpf)
  return __builtin_amdgcn_rcpf(x);
#else
  return 1.0f / x;
#endif
}

// ---------------- merged weight-pack kernel ----------------
// [0,256): conv1_w -> bf16 C1WB   [256,512): pc_w -> fp8 PCWQ
// [512,4643): W -> fp8 Wq2 + Wq (2 rows/thread, liveness-pinned loads)
// [4643,4694): zero S
__global__ __launch_bounds__(256) void k_pack(const float* __restrict__ conv1_w,
                                              const float* __restrict__ pc_w,
                                              const float* __restrict__ W,
                                              unsigned short* __restrict__ C1WB,
                                              unsigned char* __restrict__ PCWQ,
                                              unsigned char* __restrict__ Wq2,
                                              unsigned char* __restrict__ Wq,
                                              float* __restrict__ S) {
  __shared__ unsigned char sq[64 * 128];
  int bb = blockIdx.x;
  int t = threadIdx.x;
  if (bb < 256) {
    if (t < 128) {
#pragma unroll
      for (int ci = 0; ci < 3; ++ci) {
        float v = (t < 121) ? conv1_w[bb * 363 + ci * 121 + t] : 0.f;
        C1WB[(ci * 256 + bb) * 128 + t] = f2b(v);
      }
    }
  } else if (bb < 512) {
    int co = bb - 256;
    for (int e = t; e < 20736; e += 256) {
      int ci = e / 81, tap = e - ci * 81;
      PCWQ[(size_t)ci * 26624 + co * 104 + tap] =
          (unsigned char)f2q_fast(pc_w[(size_t)co * 20736 + e] * 64.f);
    }
    for (int tap = 81; tap < 104; ++tap)
      PCWQ[(size_t)t * 26624 + co * 104 + tap] = 0;
  } else if (bb < 4643) {
    size_t base = (size_t)(bb - 512) * 8192;  // 64 rows of 128 floats
    int g = t >> 3, seg = t & 7;
    int r0 = 2 * g, r1 = 2 * g + 1;
    const f32x4* s0 = (const f32x4*)(W + base + r0 * 128 + seg * 16);
    const f32x4* s1 = (const f32x4*)(W + base + r1 * 128 + seg * 16);
    f32x4 a0 = s0[0], a1 = s0[1], a2 = s0[2], a3 = s0[3];
    f32x4 c0 = s1[0], c1 = s1[1], c2 = s1[2], c3 = s1[3];
    // pin all 8 vectors live -> compiler cannot serialize the loads
    asm volatile("" :: "v"(a0), "v"(a1), "v"(a2), "v"(a3),
                       "v"(c0), "v"(c1), "v"(c2), "v"(c3));
    unsigned w0[4], w1[4];
    f32x4 va[4] = {a0, a1, a2, a3}, vc[4] = {c0, c1, c2, c3};
#pragma unroll
    for (int j = 0; j < 4; ++j) {
      w0[j] = fp8pair(va[j][0] * 64.f, va[j][1] * 64.f) |
              (fp8pair(va[j][2] * 64.f, va[j][3] * 64.f) << 16);
      w1[j] = fp8pair(vc[j][0] * 64.f, vc[j][1] * 64.f) |
              (fp8pair(vc[j][2] * 64.f, vc[j][3] * 64.f) << 16);
    }
    *(uint4*)(Wq2 + base + r0 * 128 + seg * 16) = make_uint4(w0[0], w0[1], w0[2], w0[3]);
    *(uint4*)(Wq2 + base + r1 * 128 + seg * 16) = make_uint4(w1[0], w1[1], w1[2], w1[3]);
#pragma unroll
    for (int e = 0; e < 16; ++e) {
      int idx = seg * 16 + e, d = idx >> 3, i = idx & 7;
      sq[r0 * 128 + i * 16 + d] = (unsigned char)((w0[e >> 2] >> ((e & 3) * 8)) & 0xffu);
      sq[r1 * 128 + i * 16 + d] = (unsigned char)((w1[e >> 2] >> ((e & 3) * 8)) & 0xffu);
    }
    __syncthreads();
    *(uint4*)(Wq + base + (size_t)t * 16) = ((const uint4*)sq)[t];
    *(uint4*)(Wq + base + 4096 + (size_t)t * 16) = ((const uint4*)sq)[256 + t];
  } else {
    int idx = (bb - 4643) * 1024 + t * 4;  // 51*1024 = 52224
    *(float4*)(S + idx) = make_float4(0.f, 0.f, 0.f, 0.f);
  }
}

// ---------------- conv1 via bf16 MFMA, co-split x2 ----------------
__global__ __launch_bounds__(256) void k_c1m(const float* __restrict__ x,
                                             const unsigned short* __restrict__ C1WB,
                                             const float* __restrict__ bias,
                                             float* __restrict__ feat2) {
  __shared__ unsigned short sh[48 * 128 + 128 * 128];
  unsigned short* lA = sh;
  unsigned short* lB = sh + 48 * 128;
  float* obuf = (float*)(sh + 48 * 128);

  int bx = blockIdx.x;
  int hf = blockIdx.y;  // co half
  int b = bx / 34, ho = bx % 34;
  int t = threadIdx.x;
  int lane = t & 63, wv = t >> 6;
  int l15 = lane & 15, lh = lane >> 4;
  int rx = l15 & 7;

  {
    uint4 zz = make_uint4(0, 0, 0, 0);
    uint4* z = (uint4*)lA;
    for (int i = t; i < 48 * 128 / 8; i += 256) z[i] = zz;
  }
  __syncthreads();

  f32x4 acc[3][2];
#pragma unroll
  for (int mf = 0; mf < 3; ++mf)
#pragma unroll
    for (int nf = 0; nf < 2; ++nf) acc[mf][nf] = (f32x4){0.f, 0.f, 0.f, 0.f};

#pragma unroll 1
  for (int ci = 0; ci < 3; ++ci) {
    {
      const uint4* Bsrc = (const uint4*)(C1WB + ci * 32768 + hf * 16384);
#pragma unroll
      for (int i = 0; i < 8; ++i) {
        int f = i * 256 + t;
        int row = f >> 4, cu = f & 15;
        ((uint4*)lB)[row * 16 + (cu ^ (row & 7))] = Bsrc[f];
      }
    }
    for (int tk = t; tk < 374; tk += 256) {
      int kh = tk / 34, wo = tk - kh * 34;
      const float* src = x + ((size_t)(b * 3 + ci) * 112 + ho * 3 + kh) * 112 + wo * 3;
#pragma unroll
      for (int j = 0; j < 11; ++j) {
        int tap = kh * 11 + j;
        int cu = tap >> 3;
        lA[wo * 128 + (((cu ^ (wo & 7)) << 3) | (tap & 7))] = f2b(src[j]);
      }
    }
    __syncthreads();

#pragma unroll
    for (int s = 0; s < 4; ++s) {
      int cub = ((s * 4 + lh) ^ rx) << 3;
      short8 a0 = *(const short8*)(lA + (0 + l15) * 128 + cub);
      short8 a1 = *(const short8*)(lA + (16 + l15) * 128 + cub);
      short8 a2 = *(const short8*)(lA + (32 + l15) * 128 + cub);
      short8 b0 = *(const short8*)(lB + (wv * 32 + 0 + l15) * 128 + cub);
      short8 b1 = *(const short8*)(lB + (wv * 32 + 16 + l15) * 128 + cub);
      acc[0][0] = __builtin_amdgcn_mfma_f32_16x16x32_bf16(a0, b0, acc[0][0], 0, 0, 0);
      acc[0][1] = __builtin_amdgcn_mfma_f32_16x16x32_bf16(a0, b1, acc[0][1], 0, 0, 0);
      acc[1][0] = __builtin_amdgcn_mfma_f32_16x16x32_bf16(a1, b0, acc[1][0], 0, 0, 0);
      acc[1][1] = __builtin_amdgcn_mfma_f32_16x16x32_bf16(a1, b1, acc[1][1], 0, 0, 0);
      acc[2][0] = __builtin_amdgcn_mfma_f32_16x16x32_bf16(a2, b0, acc[2][0], 0, 0, 0);
      acc[2][1] = __builtin_amdgcn_mfma_f32_16x16x32_bf16(a2, b1, acc[2][1], 0, 0, 0);
    }
    __syncthreads();
  }

  float bv[2];
#pragma unroll
  for (int nf = 0; nf < 2; ++nf) bv[nf] = bias[hf * 128 + wv * 32 + nf * 16 + l15];
#pragma unroll
  for (int mf = 0; mf < 3; ++mf)
#pragma unroll
    for (int nf = 0; nf < 2; ++nf)
#pragma unroll
      for (int r = 0; r < 4; ++r) {
        int wo = mf * 16 + lh * 4 + r;
        if (wo < 36)
          obuf[(wv * 32 + nf * 16 + l15) * 36 + wo] = fmaxf(acc[mf][nf][r] + bv[nf], 0.f);
      }
  __syncthreads();
  float4* dst = (float4*)(feat2 + (size_t)bx * 9216 + hf * 4608);
  const float4* srcb = (const float4*)obuf;
  for (int i = t; i < 1152; i += 256) dst[i] = srcb[i];
}

// ---------------- pc conv gather (fp8, HW cvt pairs) ----------------
__device__ __forceinline__ void pc_gather8(const float* __restrict__ feat2,
                                           unsigned char* __restrict__ dstbuf,
                                           int mb, int ci, int t) {
  for (int task = t; task < 576; task += 256) {
    int m = task / 9, kh = task - m * 9;
    int gm = mb * 64 + m;
    if (gm < 2592) {
      int b = gm / 81, p = gm - b * 81;
      int ho = p / 9, wo = p - ho * 9;
      const float* src = feat2 + ((size_t)(b * 34 + ho * 3 + kh) * 256 + ci) * 36 + wo * 3;
      unsigned char* dst = dstbuf + m * 104 + kh * 9;
      unsigned p01 = fp8pair(src[0], src[1]);
      unsigned p23 = fp8pair(src[2], src[3]);
      unsigned p45 = fp8pair(src[4], src[5]);
      unsigned p67 = fp8pair(src[6], src[7]);
      unsigned p8  = fp8pair(src[8], 0.f);
      dst[0] = p01; dst[1] = p01 >> 8;
      dst[2] = p23; dst[3] = p23 >> 8;
      dst[4] = p45; dst[5] = p45 >> 8;
      dst[6] = p67; dst[7] = p67 >> 8;
      dst[8] = p8;
    }
  }
}

// ---------------- primary caps conv: fp8 MFMA, kc=16, fp16 partials ----------------
__global__ __launch_bounds__(256, 3) void k_pc4(const float* __restrict__ feat2,
                                                const unsigned char* __restrict__ PCWQ,
                                                __half* __restrict__ pcp) {
  __shared__ unsigned char lA[2][64 * 104];

  int mb = blockIdx.x, kc = blockIdx.y;  // (41, 16)
  int t = threadIdx.x;
  int lane = t & 63, wv = t >> 6;
  int l15 = lane & 15, lh = lane >> 4;

  {
    uint4 zz = make_uint4(0, 0, 0, 0);
    uint4* z = (uint4*)lA;
    for (int i = t; i < 2 * 64 * 104 / 16; i += 256) z[i] = zz;
  }
  __syncthreads();
  pc_gather8(feat2, lA[0], mb, kc * 16, t);
  __syncthreads();

  f32x4 acc[4][4];
#pragma unroll
  for (int mf = 0; mf < 4; ++mf)
#pragma unroll
    for (int nf = 0; nf < 4; ++nf) acc[mf][nf] = (f32x4){0.f, 0.f, 0.f, 0.f};

#pragma unroll 1
  for (int cil = 0; cil < 16; ++cil) {
    int ci = kc * 16 + cil;
    int cur = cil & 1;

    i64 bfr[4][3];
    const unsigned char* Bbase = PCWQ + (size_t)ci * 26624 + (wv * 64 + l15) * 104 + lh * 8;
#pragma unroll
    for (int nf = 0; nf < 4; ++nf)
#pragma unroll
      for (int s = 0; s < 3; ++s)
        bfr[nf][s] = *(const i64*)(Bbase + nf * 16 * 104 + s * 32);

    if (cil < 15) pc_gather8(feat2, lA[cur ^ 1], mb, ci + 1, t);

    const unsigned char* arow = lA[cur] + l15 * 104 + lh * 8;
#pragma unroll
    for (int s = 0; s < 3; ++s) {
      i64 a0 = *(const i64*)(arow + s * 32);
      i64 a1 = *(const i64*)(arow + 16 * 104 + s * 32);
      i64 a2 = *(const i64*)(arow + 32 * 104 + s * 32);
      i64 a3 = *(const i64*)(arow + 48 * 104 + s * 32);
      acc[0][0] = __builtin_amdgcn_mfma_f32_16x16x32_fp8_fp8(a0, bfr[0][s], acc[0][0], 0, 0, 0);
      acc[0][1] = __builtin_amdgcn_mfma_f32_16x16x32_fp8_fp8(a0, bfr[1][s], acc[0][1], 0, 0, 0);
      acc[0][2] = __builtin_amdgcn_mfma_f32_16x16x32_fp8_fp8(a0, bfr[2][s], acc[0][2], 0, 0, 0);
      acc[0][3] = __builtin_amdgcn_mfma_f32_16x16x32_fp8_fp8(a0, bfr[3][s], acc[0][3], 0, 0, 0);
      acc[1][0] = __builtin_amdgcn_mfma_f32_16x16x32_fp8_fp8(a1, bfr[0][s], acc[1][0], 0, 0, 0);
      acc[1][1] = __builtin_amdgcn_mfma_f32_16x16x32_fp8_fp8(a1, bfr[1][s], acc[1][1], 0, 0, 0);
      acc[1][2] = __builtin_amdgcn_mfma_f32_16x16x32_fp8_fp8(a1, bfr[2][s], acc[1][2], 0, 0, 0);
      acc[1][3] = __builtin_amdgcn_mfma_f32_16x16x32_fp8_fp8(a1, bfr[3][s], acc[1][3], 0, 0, 0);
      acc[2][0] = __builtin_amdgcn_mfma_f32_16x16x32_fp8_fp8(a2, bfr[0][s], acc[2][0], 0, 0, 0);
      acc[2][1] = __builtin_amdgcn_mfma_f32_16x16x32_fp8_fp8(a2, bfr[1][s], acc[2][1], 0, 0, 0);
      acc[2][2] = __builtin_amdgcn_mfma_f32_16x16x32_fp8_fp8(a2, bfr[2][s], acc[2][2], 0, 0, 0);
      acc[2][3] = __builtin_amdgcn_mfma_f32_16x16x32_fp8_fp8(a2, bfr[3][s], acc[2][3], 0, 0, 0);
      acc[3][0] = __builtin_amdgcn_mfma_f32_16x16x32_fp8_fp8(a3, bfr[0][s], acc[3][0], 0, 0, 0);
      acc[3][1] = __builtin_amdgcn_mfma_f32_16x16x32_fp8_fp8(a3, bfr[1][s], acc[3][1], 0, 0, 0);
      acc[3][2] = __builtin_amdgcn_mfma_f32_16x16x32_fp8_fp8(a3, bfr[2][s], acc[3][2], 0, 0, 0);
      acc[3][3] = __builtin_amdgcn_mfma_f32_16x16x32_fp8_fp8(a3, bfr[3][s], acc[3][3], 0, 0, 0);
    }
    __syncthreads();
  }

#pragma unroll
  for (int mf = 0; mf < 4; ++mf) {
    int gm = mb * 64 + mf * 16 + lh * 4;
    if (gm < 2592) {
      __half* dst = pcp + (size_t)kc * 663552 + (size_t)gm * 256 + wv * 64 + l15;
#pragma unroll
      for (int nf = 0; nf < 4; ++nf)
#pragma unroll
        for (int r = 0; r < 4; ++r)
          dst[(size_t)r * 256 + nf * 16] = __float2half(acc[mf][nf][r]);
    }
  }
}

// ---------------- fused transpose-reduce-squash: pcp(16 fp16 slices) -> u2 ----------------
__global__ __launch_bounds__(256) void k_rs(const __half* __restrict__ pcp,
                                            const float* __restrict__ pcb,
                                            float* __restrict__ u2) {
  __shared__ float tile[81 * 17];
  int b = blockIdx.x;    // 32
  int cog = blockIdx.y;  // 16
  int c0 = cog * 16;
  int t = threadIdx.x;

  for (int e = t; e < 1296; e += 256) {
    int p = e >> 4, col = e & 15;
    const __half* base = pcp + (size_t)(b * 81 + p) * 256 + c0 + col;
    float s = 0.f;
#pragma unroll
    for (int c = 0; c < 16; ++c) s += __half2float(base[(size_t)c * 663552]);
    tile[p * 17 + col] = pcb[c0 + col] + s * 0.015625f;  // /64 (W x64)
  }
  __syncthreads();

  if (t < 162) {
    float v[8];
    float sq = 0.f;
#pragma unroll
    for (int i = 0; i < 8; ++i) {
      int g = t * 8 + i;
      int col = g / 81, p = g - col * 81;
      v[i] = tile[p * 17 + col];
      sq += v[i] * v[i];
    }
    float sc = (sq / (1.f + sq)) / sqrtf(sq + 1e-8f);
    int n = cog * 162 + t;
    float4* dst = (float4*)(u2 + ((size_t)b * 2592 + n) * 8);
    dst[0] = make_float4(v[0] * sc, v[1] * sc, v[2] * sc, v[3] * sc);
    dst[1] = make_float4(v[4] * sc, v[5] * sc, v[6] * sc, v[7] * sc);
  }
}

// ---------------- routing kernel A3 (fp8 MFMA, o-split x3): E + partial den ----------------
__global__ __launch_bounds__(128) void k_A3(const unsigned char* __restrict__ Wq,
                                            const float* __restrict__ u2,
                                            const unsigned char* __restrict__ vq,
                                            __half* __restrict__ cT,
                                            float* __restrict__ den) {
  int nb = blockIdx.x;   // 648
  int ch = blockIdx.y;   // 3
  int o0 = ch * 34;
  int t = threadIdx.x, wv = t >> 6, lane = t & 63;
  int l15 = lane & 15, g = lane >> 4;
  int n0 = nb * 4 + 2 * wv;
  int nl = g >> 1, ih = (g & 1) * 4;

  float4 u0 = *(const float4*)(u2 + (((size_t)l15 * 2592 + n0 + nl) * 8 + ih));
  float4 u1 = *(const float4*)(u2 + (((size_t)(l15 + 16) * 2592 + n0 + nl) * 8 + ih));

  int nlA = l15 >> 3, iA = l15 & 7;
  const unsigned char* Ap = Wq + (((size_t)(n0 + nlA)) * 8 + iA) * 16 + (g & 1) * 8 +
                            (size_t)o0 * 331776;
  const unsigned char* B0p = vq + (size_t)l15 * 16 + (g & 1) * 8 + (size_t)o0 * 512;
  bool act = (g < 2);

  float den0 = 0.f, den1 = 0.f;
#pragma unroll 2
  for (int oo = 0; oo < 34; ++oo) {
    i64 a = 0, b0 = 0, b1 = 0;
    if (act) {
      a  = *(const i64*)(Ap + (size_t)oo * 331776);
      b0 = *(const i64*)(B0p + (size_t)oo * 512);
      b1 = *(const i64*)(B0p + (size_t)oo * 512 + 256);
    }
    f32x4 d0 = {0.f, 0.f, 0.f, 0.f}, d1 = {0.f, 0.f, 0.f, 0.f};
    d0 = __builtin_amdgcn_mfma_f32_16x16x32_fp8_fp8(a, b0, d0, 0, 0, 0);
    d1 = __builtin_amdgcn_mfma_f32_16x16x32_fp8_fp8(a, b1, d1, 0, 0, 0);
    float p0 = d0[0] * u0.x + d0[1] * u0.y + d0[2] * u0.z + d0[3] * u0.w;
    float p1 = d1[0] * u1.x + d1[1] * u1.y + d1[2] * u1.z + d1[3] * u1.w;
    p0 += __shfl_xor(p0, 16);
    p1 += __shfl_xor(p1, 16);
    p0 *= 1.52587890625e-05f;  // / (64 * 1024)
    p1 *= 1.52587890625e-05f;
    float e0 = __expf(p0), e1 = __expf(p1);
    den0 += e0; den1 += e1;
    if ((g & 1) == 0) {
      __half* dst = cT + ((size_t)(o0 + oo) * 2592 + n0 + nl) * 32 + l15;
      dst[0]  = __float2half(e0);
      dst[16] = __float2half(e1);
    }
  }
  if ((g & 1) == 0) {
    atomicAdd(den + (n0 + nl) * 32 + l15, den0);
    atomicAdd(den + (n0 + nl) * 32 + l15 + 16, den1);
  }
}

// ---------------- routing kernel B (fp8 MFMA): s = sum (E/den)*xhat ----------------
__device__ __forceinline__ i64 cu_pack8(float c, float4 a, float4 b) {
  union { unsigned u[2]; i64 v; } r;
  r.u[0] = fp8pair(c * a.x, c * a.y) | (fp8pair(c * a.z, c * a.w) << 16);
  r.u[1] = fp8pair(c * b.x, c * b.y) | (fp8pair(c * b.z, c * b.w) << 16);
  return r.v;
}

template <bool HASC>
__global__ __launch_bounds__(256) void k_B3(const unsigned char* __restrict__ Wq2,
                                            const float* __restrict__ u2,
                                            const __half* __restrict__ cT,
                                            const float* __restrict__ den,
                                            float* __restrict__ s) {
  int o = blockIdx.x, kc = blockIdx.y;  // (102, 12)
  int t = threadIdx.x, lane = t & 63, wv = t >> 6;
  int l15 = lane & 15, h = lane >> 4;

  f32x4 acc0 = {0.f, 0.f, 0.f, 0.f}, acc1 = {0.f, 0.f, 0.f, 0.f};

#pragma unroll 1
  for (int st = wv; st < 54; st += 4) {
    int n = kc * 216 + st * 4 + h;
    i64 aq = *(const i64*)(Wq2 + (((size_t)o * 2592 + n) * 16 + l15) * 8);

    const float4* u0p = (const float4*)(u2 + ((size_t)l15 * 2592 + n) * 8);
    float4 u0a = u0p[0], u0b = u0p[1];
    const float4* u1p = (const float4*)(u2 + ((size_t)(l15 + 16) * 2592 + n) * 8);
    float4 u1a = u1p[0], u1b = u1p[1];

    float c0 = 16.0f, c1 = 16.0f;
    if (HASC) {
      const __half* cp = cT + ((size_t)o * 2592 + n) * 32;
      float i0 = rcpf(den[n * 32 + l15]);
      float i1 = rcpf(den[n * 32 + l15 + 16]);
      c0 = 16.0f * __half2float(cp[l15]) * i0;
      c1 = 16.0f * __half2float(cp[l15 + 16]) * i1;
    }
    i64 b0 = cu_pack8(c0, u0a, u0b);
    i64 b1 = cu_pack8(c1, u1a, u1b);

    acc0 = __builtin_amdgcn_mfma_f32_16x16x32_fp8_fp8(aq, b0, acc0, 0, 0, 0);
    acc1 = __builtin_amdgcn_mfma_f32_16x16x32_fp8_fp8(aq, b1, acc1, 0, 0, 0);
  }

#pragma unroll
  for (int r = 0; r < 4; ++r) {
    atomicAdd(s + ((size_t)l15 * 102 + o) * 16 + h * 4 + r, acc0[r]);
    atomicAdd(s + ((size_t)(l15 + 16) * 102 + o) * 16 + h * 4 + r, acc1[r]);
  }
}

// ---------------- squash v; optional fp8 vsum; optional S re-zero + den zero ----------------
__global__ void k_R(const float* __restrict__ s, float scale,
                    float* __restrict__ vout, const float* __restrict__ addin,
                    unsigned char* __restrict__ vsq, float* __restrict__ szero,
                    float* __restrict__ dzero) {
  int t = blockIdx.x * 256 + threadIdx.x;  // grid 13*256 = 3328
  if (dzero) {
    for (int i = t; i < 82944; i += 3328) dzero[i] = 0.f;
  }
  if (t >= 3264) return;
  const float* sp = s + t * 16;
  float r[16];
  float sq = 0.f;
#pragma unroll
  for (int d = 0; d < 16; ++d) {
    r[d] = sp[d] * scale;
    sq += r[d] * r[d];
  }
  if (szero) {
#pragma unroll
    for (int d = 0; d < 16; ++d) szero[t * 16 + d] = 0.f;
  }
  float sc = (sq / (1.f + sq)) / sqrtf(sq + 1e-8f);
  float vv[16];
#pragma unroll
  for (int d = 0; d < 16; ++d) {
    vv[d] = r[d] * sc;
    vout[t * 16 + d] = vv[d];
  }
  if (vsq) {
    int b = t / 102, o = t - b * 102;
    float w[16];
#pragma unroll
    for (int d = 0; d < 16; ++d)
      w[d] = (addin ? (addin[t * 16 + d] + vv[d]) : vv[d]) * 1024.f;
    unsigned words[4];
#pragma unroll
    for (int q = 0; q < 4; ++q)
      words[q] = fp8pair(w[4 * q], w[4 * q + 1]) | (fp8pair(w[4 * q + 2], w[4 * q + 3]) << 16);
    *(uint4*)(vsq + ((size_t)o * 32 + b) * 16) =
        make_uint4(words[0], words[1], words[2], words[3]);
  }
}

// ---------------- fused fc1+fc2: block = bq (4 batch items), h1 in LDS ----------------
__global__ __launch_bounds__(512) void k_fc12(const float* __restrict__ v2,
                                              const int* __restrict__ tgt,
                                              const float* __restrict__ w1,
                                              const float* __restrict__ b1,
                                              const float* __restrict__ w2,
                                              const float* __restrict__ b2,
                                              float* __restrict__ h2T) {
  __shared__ float h1s[4][512];
  int bq = blockIdx.x;  // 8
  int t = threadIdx.x;  // 512
#pragma unroll
  for (int bi = 0; bi < 4; ++bi) {
    int b = bq * 4 + bi;
    int tb = tgt[b];
    float acc = b1[t];
    const float* vv = v2 + (b * 102 + tb) * 16;
    const float* wr = w1 + (tb * 16) * 512 + t;
#pragma unroll
    for (int d = 0; d < 16; ++d) acc += vv[d] * wr[d * 512];
    h1s[bi][t] = fmaxf(acc, 0.f);
  }
  __syncthreads();
  float a0[4], a1[4];
#pragma unroll
  for (int bi = 0; bi < 4; ++bi) { a0[bi] = b2[t]; a1[bi] = b2[t + 512]; }
  for (int k = 0; k < 512; ++k) {
    float w0 = w2[k * 1024 + t], w1v = w2[k * 1024 + t + 512];
#pragma unroll
    for (int bi = 0; bi < 4; ++bi) {
      float h = h1s[bi][k];
      a0[bi] += h * w0;
      a1[bi] += h * w1v;
    }
  }
  float4 o0, o1;
  o0.x = fmaxf(a0[0], 0.f); o0.y = fmaxf(a0[1], 0.f);
  o0.z = fmaxf(a0[2], 0.f); o0.w = fmaxf(a0[3], 0.f);
  o1.x = fmaxf(a1[0], 0.f); o1.y = fmaxf(a1[1], 0.f);
  o1.z = fmaxf(a1[2], 0.f); o1.w = fmaxf(a1[3], 0.f);
  *(float4*)(h2T + t * 32 + bq * 4) = o0;
  *(float4*)(h2T + (t + 512) * 32 + bq * 4) = o1;
}

__global__ void k_fc3a(const float* __restrict__ h2T, const float* __restrict__ w3,
                       float* __restrict__ p) {
  int j = blockIdx.x * 128 + threadIdx.x;
  int ky = blockIdx.y;
  float acc[32];
#pragma unroll
  for (int i = 0; i < 32; ++i) acc[i] = 0.f;
  int k0 = ky * 256;
  for (int k = k0; k < k0 + 256; ++k) {
    float wv = w3[(size_t)k * 37632 + j];
    const float4* hp = (const float4*)(h2T + k * 32);
#pragma unroll
    for (int q = 0; q < 8; ++q) {
      float4 h = hp[q];
      acc[q * 4 + 0] += h.x * wv; acc[q * 4 + 1] += h.y * wv;
      acc[q * 4 + 2] += h.z * wv; acc[q * 4 + 3] += h.w * wv;
    }
  }
#pragma unroll
  for (int i = 0; i < 32; ++i)
    p[((size_t)ky * 32 + i) * 37632 + j] = acc[i];
}

__global__ void k_fc3b(const float* __restrict__ p, const float* __restrict__ b3,
                       float* __restrict__ out) {
  int j = blockIdx.x * 256 + threadIdx.x;
  float bv = b3[j];
#pragma unroll 1
  for (int b = 0; b < 32; ++b) {
    float s = bv + p[(size_t)b * 37632 + j] + p[(size_t)(32 + b) * 37632 + j] +
              p[(size_t)(64 + b) * 37632 + j] + p[(size_t)(96 + b) * 37632 + j];
    out[52224 + (size_t)b * 37632 + j] = 1.0f / (1.0f + __expf(-s));
  }
}

// ---------------- host ----------------
extern "C" void kernel_launch(void* const* d_in, const int* in_sizes, int n_in,
                              void* d_out, int out_size, void* d_ws, size_t ws_size,
                              hipStream_t stream) {
  const float* x       = (const float*)d_in[0];
  const int*   targets = (const int*)d_in[1];
  const float* conv1_w = (const float*)d_in[2];
  const float* conv1_b = (const float*)d_in[3];
  const float* pc_w    = (const float*)d_in[4];
  const float* pc_b    = (const float*)d_in[5];
  const float* W       = (const float*)d_in[6];
  const float* fc1_w   = (const float*)d_in[7];
  const float* fc1_b   = (const float*)d_in[8];
  const float* fc2_w   = (const float*)d_in[9];
  const float* fc2_b   = (const float*)d_in[10];
  const float* fc3_w   = (const float*)d_in[11];
  const float* fc3_b   = (const float*)d_in[12];
  float* out = (float*)d_out;
  float* ws = (float*)d_ws;

  float* FEAT2 = ws + OFF_FEAT;
  unsigned short* C1WB = (unsigned short*)(ws + OFF_C1WT);
  unsigned char* PCWQ = (unsigned char*)(ws + OFF_PCWQ);
  __half* PCP = (__half*)(ws + OFF_PCP);
  unsigned char* WQ2 = (unsigned char*)(ws + OFF_WQ2);
  unsigned char* WQ  = (unsigned char*)(ws + OFF_WQ);
  float* U2   = ws + OFF_U2;
  __half* CT  = (__half*)(ws + OFF_CT);
  float* DEN  = ws + OFF_DEN;
  float* S    = ws + OFF_S;
  float* V0   = ws + OFF_V0;
  float* V1   = ws + OFF_V1;
  unsigned char* VSQ = (unsigned char*)(ws + OFF_VSQ);
  float* H2T  = ws + OFF_H2T;
  float* FC3P = ws + OFF_FC3P;

  // all weight packs + initial S zero in one launch
  k_pack<<<dim3(4694), 256, 0, stream>>>(conv1_w, pc_w, W, C1WB, PCWQ, WQ2, WQ, S);

  // conv1 + relu (bf16 MFMA, co-split)
  k_c1m<<<dim3(1088, 2), 256, 0, stream>>>(x, C1WB, conv1_b, FEAT2);

  // primary caps conv + fused reduce/squash
  k_pc4<<<dim3(41, 16), 256, 0, stream>>>(FEAT2, PCWQ, PCP);
  k_rs<<<dim3(32, 16), 256, 0, stream>>>(PCP, pc_b, U2);

  // ---- routing ---- (scales: W x64, cu x16 -> /1024; vq x1024 -> logits /65536)
  k_B3<false><<<dim3(102, 12), 256, 0, stream>>>(WQ2, U2, nullptr, nullptr, S);
  k_R<<<dim3(13), 256, 0, stream>>>(S, 1.0f / (102.0f * 1024.0f), V0, nullptr, VSQ, S, DEN);

  k_A3<<<dim3(648, 3), 128, 0, stream>>>(WQ, U2, VSQ, CT, DEN);
  k_B3<true><<<dim3(102, 12), 256, 0, stream>>>(WQ2, U2, CT, DEN, S);
  k_R<<<dim3(13), 256, 0, stream>>>(S, 1.0f / 1024.0f, V1, V0, VSQ, S, DEN);  // vsq = v0+v1

  k_A3<<<dim3(648, 3), 128, 0, stream>>>(WQ, U2, VSQ, CT, DEN);
  k_B3<true><<<dim3(102, 12), 256, 0, stream>>>(WQ2, U2, CT, DEN, S);
  k_R<<<dim3(13), 256, 0, stream>>>(S, 1.0f / 1024.0f, out, nullptr, nullptr, nullptr, nullptr);

  // ---- reconstruction ----
  k_fc12<<<dim3(8), 512, 0, stream>>>(out, targets, fc1_w, fc1_b, fc2_w, fc2_b, H2T);
  k_fc3a<<<dim3(294, 4), 128, 0, stream>>>(H2T, fc3_w, FC3P);
  k_fc3b<<<dim3(147), 256, 0, stream>>>(FC3P, fc3_b, out);
}